// Round 10
// baseline (545.560 us; speedup 1.0000x reference)
//
#include <hip/hip_runtime.h>
#include <hip/hip_bf16.h>
#include <math.h>

namespace {

constexpr int SEQ    = 64;
constexpr int DINNER = 1024;
constexpr int DFF    = 16;
constexpr int DTRANK = 32;
constexpr int WXPD_STRIDE = 1056 * 1024;   // rows 0..31 = BC weights, 32..1055 = W_delta

typedef __attribute__((ext_vector_type(8))) short short8;
typedef __attribute__((ext_vector_type(4))) float f32x4;
typedef __attribute__((address_space(3))) unsigned int lds_u32_t;
typedef __attribute__((address_space(1))) unsigned int glb_u32_t;

__device__ __forceinline__ float sigm(float x) { return 1.f / (1.f + __expf(-x)); }
__device__ __forceinline__ short f2b(float v) {
    __hip_bfloat16 h = __float2bfloat16(v);
    return *(short*)&h;
}
__device__ __forceinline__ float b2f(short s) {
    union { unsigned u; float f; } c; c.u = ((unsigned)(unsigned short)s) << 16; return c.f;
}
__device__ __forceinline__ float softp(float v) {
    return fmaxf(v, 0.f) + log1pf(__expf(-fabsf(v)));
}

// ====== bf16 MFMA GEMM core, 64x64 tile, 2-phase pipelined (R8, verified) ======
__device__ __forceinline__ void gemm_core64(
    f32x4 (&acc)[2][2],
    const short* __restrict__ A, int lda,
    const short* __restrict__ W, int ldw,
    int Kd, short* As, short* Bs, int m0, int n0)
{
    constexpr int SZ = 64 * 32;
    const int tid = threadIdx.x, wave = tid >> 6, lane = tid & 63;
    const int wm = wave >> 1, wn = wave & 1;
    const int l15 = lane & 15, kg = lane >> 4;

    const int p = wave * 64 + lane;   // 16B chunk: row p>>2, slot p&3
    const short* srcA = A + (size_t)(m0 + (p >> 2)) * lda + (p & 3) * 8;
    const short* srcB = W + (size_t)(n0 + (p >> 2)) * ldw + (p & 3) * 8;
    const int ob = (wave * 64) * 8;   // wave-uniform LDS base (shorts)

    const int nt = Kd >> 5;
    __builtin_amdgcn_global_load_lds((const glb_u32_t*)srcA, (lds_u32_t*)(As + ob), 16, 0, 0);
    __builtin_amdgcn_global_load_lds((const glb_u32_t*)srcB, (lds_u32_t*)(Bs + ob), 16, 0, 0);

    for (int t = 0; t < nt; t++) {
        __syncthreads();   // drains stage for buf[t&1] + prior ds_reads
        if (t + 1 < nt) {
            const int k0 = (t + 1) * 32;
            const int s = ((t + 1) & 1) * SZ;
            __builtin_amdgcn_global_load_lds((const glb_u32_t*)(srcA + k0), (lds_u32_t*)(As + s + ob), 16, 0, 0);
            __builtin_amdgcn_global_load_lds((const glb_u32_t*)(srcB + k0), (lds_u32_t*)(Bs + s + ob), 16, 0, 0);
        }
        const short* Ab = As + (t & 1) * SZ;
        const short* Bb = Bs + (t & 1) * SZ;
        short8 af[2], bfr[2];
#pragma unroll
        for (int mi = 0; mi < 2; mi++)
            af[mi] = *(const short8*)(Ab + (wm * 32 + mi * 16 + l15) * 32 + kg * 8);
#pragma unroll
        for (int ni = 0; ni < 2; ni++)
            bfr[ni] = *(const short8*)(Bb + (wn * 32 + ni * 16 + l15) * 32 + kg * 8);
#pragma unroll
        for (int mi = 0; mi < 2; mi++)
#pragma unroll
            for (int ni = 0; ni < 2; ni++)
                acc[mi][ni] = __builtin_amdgcn_mfma_f32_16x16x32_bf16(af[mi], bfr[ni], acc[mi][ni], 0, 0, 0);
    }
}
// C/D frag [m89]: col = n0 + wn*32 + ni*16 + (lane&15);
//                 row = m0 + wm*32 + mi*16 + (lane>>4)*4 + j

// ================= prep: conversions (+gamma fold), W_delta (LDS-tiled), zeroing ======
__global__ __launch_bounds__(256) void prep_k(
    const float* __restrict__ lin1_w, const float* __restrict__ gate_w,
    const float* __restrict__ lin2_w, const float* __restrict__ in_proj_w,
    const float* __restrict__ out_proj_w, const float* __restrict__ proj_w,
    const float* __restrict__ x_proj_w, const float* __restrict__ dt_proj_w,
    const float* __restrict__ inputs, const float* __restrict__ blk_norm_w,
    const float* __restrict__ post_norm_w,
    short* __restrict__ wlin1gb, short* __restrict__ wlin2b, short* __restrict__ winpb,
    short* __restrict__ woutpb, short* __restrict__ wprojb, short* __restrict__ wxpdb,
    short* __restrict__ inputsb, float* __restrict__ preds, float* __restrict__ ss)
{
    __shared__ float xs[32][256];   // 32 KB, used only by blk<256 (W_delta)
    const int blk = blockIdx.x, tid = threadIdx.x;
    if (blk < 256) {
        // W_delta = dt_w(1024x32) @ xp_w[:32](32x1024); 16 n-rows per block,
        // xp_w chunks LDS-staged once per block (cuts 512MB L2 reads -> 32MB).
        const int l = blk >> 6;            // layer
        const int r0 = (blk & 63) * 16;    // first of 16 n-rows
        const int wave = tid >> 6, lane = tid & 63;
        const float* xpw = x_proj_w + (size_t)l * 65536;
        for (int rep = 0; rep < 4; rep++) {
            for (int i = tid; i < 2048; i += 256) {   // 2048 float4 = 32x256
                const int r = i >> 6, c = (i & 63) * 4;
                *(float4*)&xs[r][c] = *(const float4*)(xpw + r * 1024 + rep * 256 + c);
            }
            __syncthreads();
#pragma unroll
            for (int rr = 0; rr < 4; rr++) {
                const int row = r0 + wave * 4 + rr;
                const float* dtw = dt_proj_w + (size_t)l * 32768 + row * 32;
                float4 acc = make_float4(0.f, 0.f, 0.f, 0.f);
                for (int r = 0; r < 32; r++) {
                    const float s = dtw[r];
                    const float4 xv = *(const float4*)&xs[r][lane * 4];
                    acc.x = fmaf(s, xv.x, acc.x); acc.y = fmaf(s, xv.y, acc.y);
                    acc.z = fmaf(s, xv.z, acc.z); acc.w = fmaf(s, xv.w, acc.w);
                }
                union { short sh[4]; uint2 u; } pk;
                pk.sh[0] = f2b(acc.x); pk.sh[1] = f2b(acc.y);
                pk.sh[2] = f2b(acc.z); pk.sh[3] = f2b(acc.w);
                *(uint2*)(wxpdb + (size_t)l * WXPD_STRIDE + (size_t)(32 + row) * 1024
                          + rep * 256 + lane * 4) = pk.u;
            }
            __syncthreads();
        }
    } else if (blk < 288) {
        // BC weights: xp_w rows 32..63 -> wxpdb rows 0..31 (bf16)
#pragma unroll
        for (int rep = 0; rep < 4; rep++) {
            const int idx = (blk - 256) * 4096 + rep * 1024 + tid * 4;   // < 131072
            const int l = idx >> 15, off = idx & 32767;
            const float4 v = *(const float4*)(x_proj_w + (size_t)l * 65536 + 32768 + off);
            union { short sh[4]; uint2 u; } pk;
            pk.sh[0] = f2b(v.x); pk.sh[1] = f2b(v.y); pk.sh[2] = f2b(v.z); pk.sh[3] = f2b(v.w);
            *(uint2*)(wxpdb + (size_t)l * WXPD_STRIDE + off) = pk.u;
        }
    } else if (blk < 1248) {
        constexpr int pre[8] = {0, 128, 256, 512, 4608, 6656, 7680, 7936};
        for (int vb = blk - 288; vb < 7936; vb += 960) {
            int s = 0;
#pragma unroll
            for (int i = 1; i < 7; i++) s += (vb >= pre[i]);
            const int e = (vb - pre[s]) * 1024 + tid * 4;
            const float* src; short* dst;
            bool hasG = false; const float* gp = nullptr;
            if      (s == 0) { src = lin1_w + e;     dst = wlin1gb + e; }
            else if (s == 1) { src = gate_w + e;     dst = wlin1gb + 131072 + e; }
            else if (s == 2) { src = lin2_w + e;     dst = wlin2b + e; }
            else if (s == 3) { src = in_proj_w + e;  dst = winpb + e;
                               hasG = true; gp = blk_norm_w + (e >> 20) * 512 + (e & 511); }
            else if (s == 4) { src = out_proj_w + e; dst = woutpb + e; }
            else if (s == 5) { src = proj_w + e;     dst = wprojb + e;
                               hasG = true; gp = post_norm_w + (e & 511); }
            else             { src = inputs + e;     dst = inputsb + e; }
            float4 v = *(const float4*)src;
            if (hasG) {
                const float4 gv = *(const float4*)gp;
                v.x *= gv.x; v.y *= gv.y; v.z *= gv.z; v.w *= gv.w;
            }
            union { short sh[4]; uint2 u; } pk;
            pk.sh[0] = f2b(v.x); pk.sh[1] = f2b(v.y); pk.sh[2] = f2b(v.z); pk.sh[3] = f2b(v.w);
            *(uint2*)dst = pk.u;
        }
    } else {
        const int i = (blk - 1248) * 256 + tid;   // < 8192
        if (i < 4096) preds[i] = 0.f;
        else ss[1024 + (i - 4096)] = 0.f;          // zero ss slots 1..4
    }
}

// ================= spatial: lin1|gate merged (N=1024) =================
__global__ __launch_bounds__(256) void lin1gate_k(
    const short* __restrict__ A, const short* __restrict__ W,
    const float* __restrict__ b1, const float* __restrict__ b2,
    short* __restrict__ h1b, float* __restrict__ g)
{
    __shared__ short As[2 * 64 * 32];
    __shared__ short Bs[2 * 64 * 32];
    f32x4 acc[2][2] = {};
    const int m0 = blockIdx.y * 64, n0 = blockIdx.x * 64;
    gemm_core64(acc, A, 256, W, 256, 256, As, Bs, m0, n0);
    const int lane = threadIdx.x & 63, wave = threadIdx.x >> 6;
    const int wm = wave >> 1, wn = wave & 1, l15 = lane & 15, kg = lane >> 4;
#pragma unroll
    for (int ni = 0; ni < 2; ni++) {
        const int col = n0 + wn * 32 + ni * 16 + l15;
        const bool isG = col >= 512;
        const float b = isG ? b2[col - 512] : b1[col];
#pragma unroll
        for (int mi = 0; mi < 2; mi++)
#pragma unroll
            for (int j = 0; j < 4; j++) {
                const int row = m0 + wm * 32 + mi * 16 + kg * 4 + j;
                const float v = acc[mi][ni][j] + b;
                if (isG) g[(size_t)row * 512 + (col - 512)] = sigm(v);
                else     h1b[(size_t)row * 512 + col] = f2b(0.5f * v * (1.f + erff(v * 0.70710678f)));
            }
    }
}

// ================= lin2: x = (h1 @ W^T + b) * g =================
__global__ __launch_bounds__(256) void lin2_k(
    const short* __restrict__ A, const short* __restrict__ W,
    const float* __restrict__ bias, const float* __restrict__ g, float* __restrict__ x)
{
    __shared__ short As[2 * 64 * 32];
    __shared__ short Bs[2 * 64 * 32];
    f32x4 acc[2][2] = {};
    const int m0 = blockIdx.y * 64, n0 = blockIdx.x * 64;
    gemm_core64(acc, A, 512, W, 512, 512, As, Bs, m0, n0);
    const int lane = threadIdx.x & 63, wave = threadIdx.x >> 6;
    const int wm = wave >> 1, wn = wave & 1, l15 = lane & 15, kg = lane >> 4;
#pragma unroll
    for (int ni = 0; ni < 2; ni++) {
        const int col = n0 + wn * 32 + ni * 16 + l15;
        const float b = bias[col];
#pragma unroll
        for (int mi = 0; mi < 2; mi++)
#pragma unroll
            for (int j = 0; j < 4; j++) {
                const int row = m0 + wm * 32 + mi * 16 + kg * 4 + j;
                x[(size_t)row * 512 + col] = (acc[mi][ni][j] + b) * g[(size_t)row * 512 + col];
            }
    }
}

// ================= spatial rmsnorm: h fp32 + hb bf16 + ss[0] =================
__global__ __launch_bounds__(256) void rms_sp_k(
    const float* __restrict__ x, const float* __restrict__ w,
    float* __restrict__ h, short* __restrict__ hb, float* __restrict__ ss0)
{
    const int lane = threadIdx.x & 63;
    const int rowId = blockIdx.x * 4 + (threadIdx.x >> 6);
    const float* ip = x + (size_t)rowId * 512 + lane * 8;
    const float4 v1 = *(const float4*)ip;
    const float4 v2 = *(const float4*)(ip + 4);
    float sq = v1.x * v1.x + v1.y * v1.y + v1.z * v1.z + v1.w * v1.w
             + v2.x * v2.x + v2.y * v2.y + v2.z * v2.z + v2.w * v2.w;
#pragma unroll
    for (int off = 32; off > 0; off >>= 1) sq += __shfl_xor(sq, off, 64);
    const float rs = rsqrtf(sq * (1.f / 512.f) + 1e-5f);
    const float4 w1 = *(const float4*)(w + lane * 8);
    const float4 w2 = *(const float4*)(w + lane * 8 + 4);
    const float o[8] = { v1.x * rs * w1.x, v1.y * rs * w1.y, v1.z * rs * w1.z, v1.w * rs * w1.w,
                         v2.x * rs * w2.x, v2.y * rs * w2.y, v2.z * rs * w2.z, v2.w * rs * w2.w };
    float* op = h + (size_t)rowId * 512 + lane * 8;
    *(float4*)op       = make_float4(o[0], o[1], o[2], o[3]);
    *(float4*)(op + 4) = make_float4(o[4], o[5], o[6], o[7]);
    short8 pk;
#pragma unroll
    for (int i = 0; i < 8; i++) pk[i] = f2b(o[i]);
    *(short8*)(hb + (size_t)rowId * 512 + lane * 8) = pk;
    float s2 = 0.f;
#pragma unroll
    for (int i = 0; i < 8; i++) s2 = fmaf(o[i], o[i], s2);
#pragma unroll
    for (int off = 32; off > 0; off >>= 1) s2 += __shfl_xor(s2, off, 64);
    if (lane == 0) ss0[rowId] = s2;
}

// ================= in_proj + fused depthwise conv + silu (64x64 tile) =================
union ConvU {
    struct { short As[2 * 64 * 32]; short Bs[2 * 64 * 32]; } gm;   // 16 KB (GEMM)
    float cbuf[67][68];                                             // 18.2 KB (conv)
};

__global__ __launch_bounds__(256) void inprojconv_k(
    const short* __restrict__ A, const short* __restrict__ W,
    const float* __restrict__ ss_in, const float* __restrict__ cw,
    const float* __restrict__ cb, short* __restrict__ xcb, short* __restrict__ srb)
{
    __shared__ ConvU u;
    f32x4 acc[2][2] = {};
    const int m0 = blockIdx.y * 64, n0 = blockIdx.x * 64;
    gemm_core64(acc, A, 512, W, 512, 512, u.gm.As, u.gm.Bs, m0, n0);
    const int tid = threadIdx.x;
    const int lane = tid & 63, wave = tid >> 6;
    const int wm = wave >> 1, wn = wave & 1, l15 = lane & 15, kg = lane >> 4;

#pragma unroll
    for (int mi = 0; mi < 2; mi++)
#pragma unroll
        for (int j = 0; j < 4; j++) {
            const int row = m0 + wm * 32 + mi * 16 + kg * 4 + j;
            const float r = rsqrtf(ss_in[row] * (1.f / 512.f) + 1e-5f);
#pragma unroll
            for (int ni = 0; ni < 2; ni++) acc[mi][ni][j] *= r;
        }

    if (n0 < 1024) {
        const int ccol = tid & 63;
        const int rg = tid >> 6;           // 0..3
        const int d = n0 + ccol;
        const float4 w4 = *(const float4*)(cw + d * 4);
        const float bia = cb[d];

        __syncthreads();   // gemm LDS reads done
#pragma unroll
        for (int mi = 0; mi < 2; mi++)
#pragma unroll
            for (int ni = 0; ni < 2; ni++)
#pragma unroll
                for (int j = 0; j < 4; j++)
                    u.cbuf[3 + wm * 32 + mi * 16 + kg * 4 + j][wn * 32 + ni * 16 + l15] = acc[mi][ni][j];
        for (int i = tid; i < 3 * 68; i += 256) u.cbuf[i / 68][i % 68] = 0.f;
        __syncthreads();
#pragma unroll 4
        for (int k = 0; k < 16; k++) {
            const int row = rg + 4 * k;    // 0..63
            float v = bia + w4.x * u.cbuf[row][ccol] + w4.y * u.cbuf[row + 1][ccol]
                          + w4.z * u.cbuf[row + 2][ccol] + w4.w * u.cbuf[row + 3][ccol];
            v = v * sigm(v);
            xcb[(size_t)(m0 + row) * 1024 + d] = f2b(v);
        }
    } else {
#pragma unroll
        for (int ni = 0; ni < 2; ni++) {
            const int scol = n0 - 1024 + wn * 32 + ni * 16 + l15;
#pragma unroll
            for (int mi = 0; mi < 2; mi++)
#pragma unroll
                for (int j = 0; j < 4; j++) {
                    const int row = m0 + wm * 32 + mi * 16 + kg * 4 + j;
                    const float v = acc[mi][ni][j];
                    srb[(size_t)row * 1024 + scol] = f2b(v * sigm(v));
                }
        }
    }
}

// ================= fused x_proj/dt + scan, ONE GEMM pass =================
// W layout (wxpdb): rows 0..31 = BC weights (xp_w rows 32..63), rows 32..1055 = W_delta.
// Per block (dg,b): one K=1024 pass computes delta tile (64 cols, Wd) AND BC tile
// (32 cols) with A staged once. Then softplus(delta)+BC -> LDS -> 64-thread scan.
union XsU {
    struct { short As[2 * 64 * 32]; short Wd[2 * 64 * 32]; short BC[2 * 32 * 32]; } gm; // 20 KB
    struct { float dlt[64][68]; float BC[64][32]; } sc;                                  // 25.6 KB
};

__global__ __launch_bounds__(256) void xpdscan_k(
    const short* __restrict__ A /*xcb*/, const short* __restrict__ W /*wxpdb layer*/,
    const float* __restrict__ dtb, const float* __restrict__ Alog,
    const float* __restrict__ Dp, const short* __restrict__ srb, short* __restrict__ yb)
{
    __shared__ XsU u;
    const int dg = blockIdx.x, b = blockIdx.y;
    const int m0 = b * 64;
    const int tid = threadIdx.x;
    const int lane = tid & 63, wave = tid >> 6;
    const int wm = wave >> 1, wn = wave & 1, l15 = lane & 15, kg = lane >> 4;

    constexpr int SZA = 64 * 32, SZBC = 32 * 32;
    const int p = wave * 64 + lane;   // chunk id
    const short* srcA  = A + (size_t)(m0 + (p >> 2)) * 1024 + (p & 3) * 8;
    const short* srcWd = W + (size_t)(32 + dg * 64 + (p >> 2)) * 1024 + (p & 3) * 8;
    const short* srcBC = W + (size_t)(p >> 2) * 1024 + (p & 3) * 8;   // valid for p<128 (waves 0,1)
    const int ob = (wave * 64) * 8;

    f32x4 accd[2][2] = {};
    f32x4 accx[2] = {};

    __builtin_amdgcn_global_load_lds((const glb_u32_t*)srcA,  (lds_u32_t*)(u.gm.As + ob), 16, 0, 0);
    __builtin_amdgcn_global_load_lds((const glb_u32_t*)srcWd, (lds_u32_t*)(u.gm.Wd + ob), 16, 0, 0);
    if (wave < 2)
        __builtin_amdgcn_global_load_lds((const glb_u32_t*)srcBC, (lds_u32_t*)(u.gm.BC + ob), 16, 0, 0);

    for (int t = 0; t < 32; t++) {
        __syncthreads();
        if (t + 1 < 32) {
            const int k0 = (t + 1) * 32;
            const int sA = ((t + 1) & 1) * SZA, sBC = ((t + 1) & 1) * SZBC;
            __builtin_amdgcn_global_load_lds((const glb_u32_t*)(srcA + k0),  (lds_u32_t*)(u.gm.As + sA + ob), 16, 0, 0);
            __builtin_amdgcn_global_load_lds((const glb_u32_t*)(srcWd + k0), (lds_u32_t*)(u.gm.Wd + sA + ob), 16, 0, 0);
            if (wave < 2)
                __builtin_amdgcn_global_load_lds((const glb_u32_t*)(srcBC + k0), (lds_u32_t*)(u.gm.BC + sBC + ob), 16, 0, 0);
        }
        const short* Ab  = u.gm.As + (t & 1) * SZA;
        const short* Wdb = u.gm.Wd + (t & 1) * SZA;
        const short* BCb = u.gm.BC + (t & 1) * SZBC;
        short8 af[2], wf[2], bcf;
#pragma unroll
        for (int mi = 0; mi < 2; mi++)
            af[mi] = *(const short8*)(Ab + (wm * 32 + mi * 16 + l15) * 32 + kg * 8);
#pragma unroll
        for (int ni = 0; ni < 2; ni++)
            wf[ni] = *(const short8*)(Wdb + (wn * 32 + ni * 16 + l15) * 32 + kg * 8);
        bcf = *(const short8*)(BCb + (wn * 16 + l15) * 32 + kg * 8);
#pragma unroll
        for (int mi = 0; mi < 2; mi++) {
#pragma unroll
            for (int ni = 0; ni < 2; ni++)
                accd[mi][ni] = __builtin_amdgcn_mfma_f32_16x16x32_bf16(af[mi], wf[ni], accd[mi][ni], 0, 0, 0);
            accx[mi] = __builtin_amdgcn_mfma_f32_16x16x32_bf16(af[mi], bcf, accx[mi], 0, 0, 0);
        }
    }

    __syncthreads();   // gemm LDS reads done before repurposing union
    // delta -> LDS with softplus; tile col dl = local d 0..63
#pragma unroll
    for (int ni = 0; ni < 2; ni++) {
        const int dl = wn * 32 + ni * 16 + l15;
        const float bb = dtb[dg * 64 + dl];
#pragma unroll
        for (int mi = 0; mi < 2; mi++)
#pragma unroll
            for (int j = 0; j < 4; j++)
                u.sc.dlt[wm * 32 + mi * 16 + kg * 4 + j][dl] = softp(accd[mi][ni][j] + bb);
    }
    // BC -> LDS: col c = wn*16 + l15 (0..31); all waves write distinct cells
    {
        const int c = wn * 16 + l15;
#pragma unroll
        for (int mi = 0; mi < 2; mi++)
#pragma unroll
            for (int j = 0; j < 4; j++)
                u.sc.BC[wm * 32 + mi * 16 + kg * 4 + j][c] = accx[mi][j];
    }
    __syncthreads();

    if (tid < 64) {
        const int d = dg * 64 + tid;
        float a[16], s[16];
#pragma unroll
        for (int n = 0; n < 16; n++) { a[n] = -__expf(Alog[(size_t)d * 16 + n]); s[n] = 0.f; }
        const float dv = Dp[d];
        const size_t base = (size_t)b * SEQ;
        float uu = b2f(A[base * DINNER + d]);
        float rr = b2f(srb[base * 1024 + d]);
        for (int l = 0; l < SEQ; l++) {
            float uu_n = 0.f, rr_n = 0.f;
            if (l + 1 < SEQ) {
                uu_n = b2f(A[(base + l + 1) * DINNER + d]);
                rr_n = b2f(srb[(base + l + 1) * 1024 + d]);
            }
            const float dlt = u.sc.dlt[l][tid];
            const float dbu = dlt * uu;
            float acc = 0.f;
#pragma unroll
            for (int n = 0; n < 16; n++) {
                s[n] = __expf(dlt * a[n]) * s[n] + dbu * u.sc.BC[l][n];
                acc = fmaf(s[n], u.sc.BC[l][16 + n], acc);
            }
            acc = fmaf(uu, dv, acc);
            yb[(base + l) * DINNER + d] = f2b(acc * rr);
            uu = uu_n; rr = rr_n;
        }
    }
}

// ================= out_proj: 32x64 tile (grid 256 = full machine) =================
// h += yb @ W^T; writes h fp32 + hb bf16 + ss_out. 4 waves in 1x4 (wave = n-quarter).
__global__ __launch_bounds__(256) void outproj_k(
    const short* __restrict__ A, const short* __restrict__ W,
    float* __restrict__ h, short* __restrict__ hb, float* __restrict__ ss_out)
{
    __shared__ short As[2 * 32 * 32];   // 4 KB dbuf
    __shared__ short Bs[2 * 64 * 32];   // 8 KB dbuf
    constexpr int SZA = 32 * 32, SZB = 64 * 32;
    const int m0 = blockIdx.y * 32, n0 = blockIdx.x * 64;
    const int tid = threadIdx.x, wave = tid >> 6, lane = tid & 63;
    const int l15 = lane & 15, kg = lane >> 4;

    const int p = wave * 64 + lane;   // 0..255
    const short* srcA = A + (size_t)(m0 + (p >> 2)) * 1024 + (p & 3) * 8;   // valid p<128
    const short* srcB = W + (size_t)(n0 + (p >> 2)) * 1024 + (p & 3) * 8;
    const int ob = (wave * 64) * 8;

    f32x4 acc[2] = {};
    if (wave < 2)
        __builtin_amdgcn_global_load_lds((const glb_u32_t*)srcA, (lds_u32_t*)(As + ob), 16, 0, 0);
    __builtin_amdgcn_global_load_lds((const glb_u32_t*)srcB, (lds_u32_t*)(Bs + ob), 16, 0, 0);

    for (int t = 0; t < 32; t++) {
        __syncthreads();
        if (t + 1 < 32) {
            const int k0 = (t + 1) * 32;
            const int sA = ((t + 1) & 1) * SZA, sB = ((t + 1) & 1) * SZB;
            if (wave < 2)
                __builtin_amdgcn_global_load_lds((const glb_u32_t*)(srcA + k0), (lds_u32_t*)(As + sA + ob), 16, 0, 0);
            __builtin_amdgcn_global_load_lds((const glb_u32_t*)(srcB + k0), (lds_u32_t*)(Bs + sB + ob), 16, 0, 0);
        }
        const short* Ab = As + (t & 1) * SZA;
        const short* Bb = Bs + (t & 1) * SZB;
        short8 af[2], bf;
#pragma unroll
        for (int mi = 0; mi < 2; mi++)
            af[mi] = *(const short8*)(Ab + (mi * 16 + l15) * 32 + kg * 8);
        bf = *(const short8*)(Bb + (wave * 16 + l15) * 32 + kg * 8);
#pragma unroll
        for (int mi = 0; mi < 2; mi++)
            acc[mi] = __builtin_amdgcn_mfma_f32_16x16x32_bf16(af[mi], bf, acc[mi], 0, 0, 0);
    }

    const int col = n0 + wave * 16 + l15;
    float vsq[2][4] = {};
#pragma unroll
    for (int mi = 0; mi < 2; mi++)
#pragma unroll
        for (int j = 0; j < 4; j++) {
            const int row = m0 + mi * 16 + kg * 4 + j;
            const float v = acc[mi][j] + h[(size_t)row * 512 + col];
            h[(size_t)row * 512 + col] = v;
            hb[(size_t)row * 512 + col] = f2b(v);
            vsq[mi][j] = v * v;
        }
#pragma unroll
    for (int mi = 0; mi < 2; mi++)
#pragma unroll
        for (int j = 0; j < 4; j++) {
            float t = vsq[mi][j];
            t += __shfl_xor(t, 1, 64);
            t += __shfl_xor(t, 2, 64);
            t += __shfl_xor(t, 4, 64);
            t += __shfl_xor(t, 8, 64);
            if (l15 == 0) {
                const int row = m0 + mi * 16 + kg * 4 + j;
                atomicAdd(ss_out + row, t);
            }
        }
}

// ================= final proj: xr = r[row] * (hb @ (W.gamma)^T) =================
__global__ __launch_bounds__(256) void projf_k(
    const short* __restrict__ A, const short* __restrict__ W,
    const float* __restrict__ ss_in, float* __restrict__ xr)
{
    __shared__ short As[2 * 64 * 32];
    __shared__ short Bs[2 * 64 * 32];
    f32x4 acc[2][2] = {};
    const int m0 = blockIdx.y * 64, n0 = blockIdx.x * 64;
    gemm_core64(acc, A, 512, W, 512, 512, As, Bs, m0, n0);
    const int lane = threadIdx.x & 63, wave = threadIdx.x >> 6;
    const int wm = wave >> 1, wn = wave & 1, l15 = lane & 15, kg = lane >> 4;
#pragma unroll
    for (int mi = 0; mi < 2; mi++)
#pragma unroll
        for (int j = 0; j < 4; j++) {
            const int row = m0 + wm * 32 + mi * 16 + kg * 4 + j;
            const float r = rsqrtf(ss_in[row] * (1.f / 512.f) + 1e-5f);
#pragma unroll
            for (int ni = 0; ni < 2; ni++) {
                const int col = n0 + wn * 32 + ni * 16 + l15;
                xr[(size_t)row * 2048 + col] = acc[mi][ni][j] * r;
            }
        }
}

// ================= coeffs + preds =================
__global__ __launch_bounds__(256) void coeffs_k(
    const float* __restrict__ outp, const float* __restrict__ inp,
    float* __restrict__ coeffs, float* __restrict__ preds)
{
    const int m = blockIdx.x;
    const int b = m >> 6;
    const int tid = threadIdx.x, wave = tid >> 6, lane = tid & 63;
    __shared__ float4 Us[256], Vs[256];
    __shared__ float ins[256];
    __shared__ float4 tpart[4];
    Us[tid] = *(const float4*)(outp + (size_t)m * 2048 + tid * 4);
    Vs[tid] = *(const float4*)(outp + (size_t)m * 2048 + 1024 + tid * 4);
    ins[tid] = inp[(size_t)m * 256 + tid];
    __syncthreads();
    const float4 vq0 = Vs[lane * 4 + 0], vq1 = Vs[lane * 4 + 1];
    const float4 vq2 = Vs[lane * 4 + 2], vq3 = Vs[lane * 4 + 3];
    float* cbase = coeffs + (size_t)m * 65536 + lane * 4;
#pragma unroll 4
    for (int i = 0; i < 64; i++) {
        const int pp = (wave << 6) + i;
        const float4 up = Us[pp];
        float4 c;
        c.x = up.x * vq0.x + up.y * vq0.y + up.z * vq0.z + up.w * vq0.w;
        c.y = up.x * vq1.x + up.y * vq1.y + up.z * vq1.z + up.w * vq1.w;
        c.z = up.x * vq2.x + up.y * vq2.y + up.z * vq2.z + up.w * vq2.w;
        c.w = up.x * vq3.x + up.y * vq3.y + up.z * vq3.z + up.w * vq3.w;
        *(float4*)(cbase + (size_t)pp * 256) = c;
    }
    const float iv = ins[tid];
    const float4 vm = Vs[tid];
    float4 t = make_float4(vm.x * iv, vm.y * iv, vm.z * iv, vm.w * iv);
#pragma unroll
    for (int off = 32; off > 0; off >>= 1) {
        t.x += __shfl_xor(t.x, off, 64);
        t.y += __shfl_xor(t.y, off, 64);
        t.z += __shfl_xor(t.z, off, 64);
        t.w += __shfl_xor(t.w, off, 64);
    }
    if (lane == 0) tpart[wave] = t;
    __syncthreads();
    const float4 t0 = tpart[0], t1 = tpart[1], t2 = tpart[2], t3 = tpart[3];
    const float4 tt = make_float4(t0.x + t1.x + t2.x + t3.x, t0.y + t1.y + t2.y + t3.y,
                                  t0.z + t1.z + t2.z + t3.z, t0.w + t1.w + t2.w + t3.w);
    const float4 up = Us[tid];
    const float pv = up.x * tt.x + up.y * tt.y + up.z * tt.z + up.w * tt.w;
    atomicAdd(preds + (size_t)b * 256 + tid, pv);
}

} // namespace

extern "C" void kernel_launch(void* const* d_in, const int* in_sizes, int n_in,
                              void* d_out, int out_size, void* d_ws, size_t ws_size,
                              hipStream_t stream)
{
    const float* inputs     = (const float*)d_in[0];
    const float* lin1_w     = (const float*)d_in[1];
    const float* lin1_b     = (const float*)d_in[2];
    const float* lin2_w     = (const float*)d_in[3];
    const float* lin2_b     = (const float*)d_in[4];
    const float* gate_w     = (const float*)d_in[5];
    const float* gate_b     = (const float*)d_in[6];
    const float* sp_norm_w  = (const float*)d_in[7];
    const float* in_proj_w  = (const float*)d_in[8];
    const float* conv_w     = (const float*)d_in[9];
    const float* conv_b     = (const float*)d_in[10];
    const float* x_proj_w   = (const float*)d_in[11];
    const float* dt_proj_w  = (const float*)d_in[12];
    const float* dt_proj_b  = (const float*)d_in[13];
    const float* A_log      = (const float*)d_in[14];
    const float* Dvec       = (const float*)d_in[15];
    const float* out_proj_w = (const float*)d_in[16];
    const float* blk_norm_w = (const float*)d_in[17];
    const float* post_norm_w= (const float*)d_in[18];
    const float* proj_w     = (const float*)d_in[19];

    float* ws = (float*)d_ws;
    // fp32 region
    float* h     = ws;                 // 1024 x 512
    float* xr    = ws + 524288;        // 1024 x 2048 (final proj out)
    float* x     = ws + 2621440;       // 1024 x 512 (lin2 out)
    float* g     = ws + 3145728;       // 1024 x 512
    float* ss    = ws + 3670016;       // 5 x 1024 sumsq slots
    // bf16 region
    short* bfb     = (short*)(ws + 3676160);
    short* inputsb = bfb;               // 1024 x 256
    short* h1b     = bfb + 262144;      // 1024 x 512
    short* hb      = bfb + 786432;      // 1024 x 512
    short* xcb     = bfb + 1310720;     // 1024 x 1024
    short* yb      = bfb + 2359296;     // 1024 x 1024
    short* srb     = bfb + 3407872;     // 1024 x 1024 silu(res)
    short* wlin1gb = bfb + 4456448;     // 1024 x 256
    short* wlin2b  = bfb + 4718592;     // 512 x 512
    short* winpb   = bfb + 4980736;     // 4 x 2048 x 512 (gamma-folded)
    short* woutpb  = bfb + 9175040;     // 4 x 512 x 1024
    short* wprojb  = bfb + 11272192;    // 2048 x 512 (gamma-folded)
    short* wxpdb   = bfb + 12320768;    // 4 x 1056 x 1024 ([BC; W_delta])
    float* preds  = (float*)d_out;
    float* coeffs = (float*)d_out + 4096;

    const dim3 blk(256);

    prep_k<<<dim3(1280), blk, 0, stream>>>(
        lin1_w, gate_w, lin2_w, in_proj_w, out_proj_w, proj_w, x_proj_w, dt_proj_w,
        inputs, blk_norm_w, post_norm_w,
        wlin1gb, wlin2b, winpb, woutpb, wprojb, wxpdb, inputsb, preds, ss);

    lin1gate_k<<<dim3(16, 16), blk, 0, stream>>>(inputsb, wlin1gb, lin1_b, gate_b, h1b, g);
    lin2_k<<<dim3(8, 16), blk, 0, stream>>>(h1b, wlin2b, lin2_b, g, x);
    rms_sp_k<<<dim3(256), blk, 0, stream>>>(x, sp_norm_w, h, hb, ss);

    for (int l = 0; l < 4; l++) {
        inprojconv_k<<<dim3(32, 16), blk, 0, stream>>>(
            hb, winpb + (size_t)l * 1048576, ss + l * 1024,
            conv_w + (size_t)l * 4096, conv_b + l * 1024, xcb, srb);
        xpdscan_k<<<dim3(16, 16), blk, 0, stream>>>(
            xcb, wxpdb + (size_t)l * WXPD_STRIDE, dt_proj_b + l * 1024,
            A_log + (size_t)l * 16384, Dvec + l * 1024, srb, yb);
        outproj_k<<<dim3(8, 32), blk, 0, stream>>>(yb, woutpb + (size_t)l * 524288,
                                                   h, hb, ss + (l + 1) * 1024);
    }

    projf_k<<<dim3(32, 16), blk, 0, stream>>>(hb, wprojb, ss + 4096, xr);
    coeffs_k<<<dim3(1024), blk, 0, stream>>>(xr, inputs, coeffs, preds);
}

// Round 11
// 414.140 us; speedup vs baseline: 1.3173x; 1.3173x over previous
//
#include <hip/hip_runtime.h>
#include <hip/hip_bf16.h>
#include <math.h>

namespace {

constexpr int SEQ    = 64;
constexpr int DINNER = 1024;
constexpr int DFF    = 16;
constexpr int DTRANK = 32;
constexpr int WXPD_STRIDE = 1056 * 1024;   // rows 0..31 = BC weights, 32..1055 = W_delta

typedef __attribute__((ext_vector_type(8))) short short8;
typedef __attribute__((ext_vector_type(4))) float f32x4;
typedef __attribute__((address_space(3))) unsigned int lds_u32_t;
typedef __attribute__((address_space(1))) unsigned int glb_u32_t;

__device__ __forceinline__ float sigm(float x) { return 1.f / (1.f + __expf(-x)); }
__device__ __forceinline__ short f2b(float v) {
    __hip_bfloat16 h = __float2bfloat16(v);
    return *(short*)&h;
}
__device__ __forceinline__ float b2f(short s) {
    union { unsigned u; float f; } c; c.u = ((unsigned)(unsigned short)s) << 16; return c.f;
}
__device__ __forceinline__ float softp(float v) {
    return fmaxf(v, 0.f) + log1pf(__expf(-fabsf(v)));
}

// ====== bf16 MFMA GEMM core, 64x64 tile, 2-phase pipelined (R8, verified) ======
__device__ __forceinline__ void gemm_core64(
    f32x4 (&acc)[2][2],
    const short* __restrict__ A, int lda,
    const short* __restrict__ W, int ldw,
    int Kd, short* As, short* Bs, int m0, int n0)
{
    constexpr int SZ = 64 * 32;
    const int tid = threadIdx.x, wave = tid >> 6, lane = tid & 63;
    const int wm = wave >> 1, wn = wave & 1;
    const int l15 = lane & 15, kg = lane >> 4;

    const int p = wave * 64 + lane;   // 16B chunk: row p>>2, slot p&3
    const short* srcA = A + (size_t)(m0 + (p >> 2)) * lda + (p & 3) * 8;
    const short* srcB = W + (size_t)(n0 + (p >> 2)) * ldw + (p & 3) * 8;
    const int ob = (wave * 64) * 8;   // wave-uniform LDS base (shorts)

    const int nt = Kd >> 5;
    __builtin_amdgcn_global_load_lds((const glb_u32_t*)srcA, (lds_u32_t*)(As + ob), 16, 0, 0);
    __builtin_amdgcn_global_load_lds((const glb_u32_t*)srcB, (lds_u32_t*)(Bs + ob), 16, 0, 0);

    for (int t = 0; t < nt; t++) {
        __syncthreads();   // drains stage for buf[t&1] + prior ds_reads
        if (t + 1 < nt) {
            const int k0 = (t + 1) * 32;
            const int s = ((t + 1) & 1) * SZ;
            __builtin_amdgcn_global_load_lds((const glb_u32_t*)(srcA + k0), (lds_u32_t*)(As + s + ob), 16, 0, 0);
            __builtin_amdgcn_global_load_lds((const glb_u32_t*)(srcB + k0), (lds_u32_t*)(Bs + s + ob), 16, 0, 0);
        }
        const short* Ab = As + (t & 1) * SZ;
        const short* Bb = Bs + (t & 1) * SZ;
        short8 af[2], bfr[2];
#pragma unroll
        for (int mi = 0; mi < 2; mi++)
            af[mi] = *(const short8*)(Ab + (wm * 32 + mi * 16 + l15) * 32 + kg * 8);
#pragma unroll
        for (int ni = 0; ni < 2; ni++)
            bfr[ni] = *(const short8*)(Bb + (wn * 32 + ni * 16 + l15) * 32 + kg * 8);
#pragma unroll
        for (int mi = 0; mi < 2; mi++)
#pragma unroll
            for (int ni = 0; ni < 2; ni++)
                acc[mi][ni] = __builtin_amdgcn_mfma_f32_16x16x32_bf16(af[mi], bfr[ni], acc[mi][ni], 0, 0, 0);
    }
}
// C/D frag [m89]: col = n0 + wn*32 + ni*16 + (lane&15);
//                 row = m0 + wm*32 + mi*16 + (lane>>4)*4 + j

// ================= prep: conversions (+gamma fold), W_delta (R9 wave-per-row), zeroing ==
// NOTE (R10 post-mortem): do NOT LDS-stage W_delta here — the 32KB LDS + unrolled
// loops pushed VGPR to 256 w/ scratch spills (185us). xp_w is 1MB = L2-resident;
// redundant re-reads are free. Wave-per-row, direct global reads, low VGPR.
__global__ __launch_bounds__(256) void prep_k(
    const float* __restrict__ lin1_w, const float* __restrict__ gate_w,
    const float* __restrict__ lin2_w, const float* __restrict__ in_proj_w,
    const float* __restrict__ out_proj_w, const float* __restrict__ proj_w,
    const float* __restrict__ x_proj_w, const float* __restrict__ dt_proj_w,
    const float* __restrict__ inputs, const float* __restrict__ blk_norm_w,
    const float* __restrict__ post_norm_w,
    short* __restrict__ wlin1gb, short* __restrict__ wlin2b, short* __restrict__ winpb,
    short* __restrict__ woutpb, short* __restrict__ wprojb, short* __restrict__ wxpdb,
    short* __restrict__ inputsb, float* __restrict__ preds, float* __restrict__ ss)
{
    const int blk = blockIdx.x, tid = threadIdx.x;
    if (blk < 1024) {
        // W_delta = dt_w(1024x32) @ xp_w[:32](32x1024); wave per n-row -> rows 32..1055
        const int wave = tid >> 6, lane = tid & 63;
        const int nrow = blk * 4 + wave;          // 0..4095
        const int l = nrow >> 10, n = nrow & 1023;
        const float* dtw = dt_proj_w + (size_t)l * 32768 + n * 32;
        const float* xpw = x_proj_w + (size_t)l * 65536;
        float4 acc[4] = {};
        for (int r = 0; r < 32; r++) {
            const float s = dtw[r];
#pragma unroll
            for (int rep = 0; rep < 4; rep++) {
                const float4 xv = *(const float4*)(xpw + r * 1024 + rep * 256 + lane * 4);
                acc[rep].x = fmaf(s, xv.x, acc[rep].x);
                acc[rep].y = fmaf(s, xv.y, acc[rep].y);
                acc[rep].z = fmaf(s, xv.z, acc[rep].z);
                acc[rep].w = fmaf(s, xv.w, acc[rep].w);
            }
        }
        short* dst = wxpdb + (size_t)l * WXPD_STRIDE + (size_t)(32 + n) * 1024;
#pragma unroll
        for (int rep = 0; rep < 4; rep++) {
            union { short sh[4]; uint2 u; } pk;
            pk.sh[0] = f2b(acc[rep].x); pk.sh[1] = f2b(acc[rep].y);
            pk.sh[2] = f2b(acc[rep].z); pk.sh[3] = f2b(acc[rep].w);
            *(uint2*)(dst + rep * 256 + lane * 4) = pk.u;
        }
    } else if (blk < 1056) {
        // BC weights: xp_w rows 32..63 -> wxpdb rows 0..31 (bf16)
#pragma unroll
        for (int rep = 0; rep < 4; rep++) {
            const int idx = (blk - 1024) * 4096 + rep * 1024 + tid * 4;   // < 131072
            const int l = idx >> 15, off = idx & 32767;
            const float4 v = *(const float4*)(x_proj_w + (size_t)l * 65536 + 32768 + off);
            union { short sh[4]; uint2 u; } pk;
            pk.sh[0] = f2b(v.x); pk.sh[1] = f2b(v.y); pk.sh[2] = f2b(v.z); pk.sh[3] = f2b(v.w);
            *(uint2*)(wxpdb + (size_t)l * WXPD_STRIDE + off) = pk.u;
        }
    } else if (blk < 2016) {
        constexpr int pre[8] = {0, 128, 256, 512, 4608, 6656, 7680, 7936};
        for (int vb = blk - 1056; vb < 7936; vb += 960) {
            int s = 0;
#pragma unroll
            for (int i = 1; i < 7; i++) s += (vb >= pre[i]);
            const int e = (vb - pre[s]) * 1024 + tid * 4;
            const float* src; short* dst;
            bool hasG = false; const float* gp = nullptr;
            if      (s == 0) { src = lin1_w + e;     dst = wlin1gb + e; }
            else if (s == 1) { src = gate_w + e;     dst = wlin1gb + 131072 + e; }
            else if (s == 2) { src = lin2_w + e;     dst = wlin2b + e; }
            else if (s == 3) { src = in_proj_w + e;  dst = winpb + e;
                               hasG = true; gp = blk_norm_w + (e >> 20) * 512 + (e & 511); }
            else if (s == 4) { src = out_proj_w + e; dst = woutpb + e; }
            else if (s == 5) { src = proj_w + e;     dst = wprojb + e;
                               hasG = true; gp = post_norm_w + (e & 511); }
            else             { src = inputs + e;     dst = inputsb + e; }
            float4 v = *(const float4*)src;
            if (hasG) {
                const float4 gv = *(const float4*)gp;
                v.x *= gv.x; v.y *= gv.y; v.z *= gv.z; v.w *= gv.w;
            }
            union { short sh[4]; uint2 u; } pk;
            pk.sh[0] = f2b(v.x); pk.sh[1] = f2b(v.y); pk.sh[2] = f2b(v.z); pk.sh[3] = f2b(v.w);
            *(uint2*)dst = pk.u;
        }
    } else {
        const int i = (blk - 2016) * 256 + tid;   // < 8192
        if (i < 4096) preds[i] = 0.f;
        else ss[1024 + (i - 4096)] = 0.f;          // zero ss slots 1..4
    }
}

// ================= spatial: lin1|gate merged (N=1024) =================
__global__ __launch_bounds__(256) void lin1gate_k(
    const short* __restrict__ A, const short* __restrict__ W,
    const float* __restrict__ b1, const float* __restrict__ b2,
    short* __restrict__ h1b, float* __restrict__ g)
{
    __shared__ short As[2 * 64 * 32];
    __shared__ short Bs[2 * 64 * 32];
    f32x4 acc[2][2] = {};
    const int m0 = blockIdx.y * 64, n0 = blockIdx.x * 64;
    gemm_core64(acc, A, 256, W, 256, 256, As, Bs, m0, n0);
    const int lane = threadIdx.x & 63, wave = threadIdx.x >> 6;
    const int wm = wave >> 1, wn = wave & 1, l15 = lane & 15, kg = lane >> 4;
#pragma unroll
    for (int ni = 0; ni < 2; ni++) {
        const int col = n0 + wn * 32 + ni * 16 + l15;
        const bool isG = col >= 512;
        const float b = isG ? b2[col - 512] : b1[col];
#pragma unroll
        for (int mi = 0; mi < 2; mi++)
#pragma unroll
            for (int j = 0; j < 4; j++) {
                const int row = m0 + wm * 32 + mi * 16 + kg * 4 + j;
                const float v = acc[mi][ni][j] + b;
                if (isG) g[(size_t)row * 512 + (col - 512)] = sigm(v);
                else     h1b[(size_t)row * 512 + col] = f2b(0.5f * v * (1.f + erff(v * 0.70710678f)));
            }
    }
}

// ================= lin2: x = (h1 @ W^T + b) * g =================
__global__ __launch_bounds__(256) void lin2_k(
    const short* __restrict__ A, const short* __restrict__ W,
    const float* __restrict__ bias, const float* __restrict__ g, float* __restrict__ x)
{
    __shared__ short As[2 * 64 * 32];
    __shared__ short Bs[2 * 64 * 32];
    f32x4 acc[2][2] = {};
    const int m0 = blockIdx.y * 64, n0 = blockIdx.x * 64;
    gemm_core64(acc, A, 512, W, 512, 512, As, Bs, m0, n0);
    const int lane = threadIdx.x & 63, wave = threadIdx.x >> 6;
    const int wm = wave >> 1, wn = wave & 1, l15 = lane & 15, kg = lane >> 4;
#pragma unroll
    for (int ni = 0; ni < 2; ni++) {
        const int col = n0 + wn * 32 + ni * 16 + l15;
        const float b = bias[col];
#pragma unroll
        for (int mi = 0; mi < 2; mi++)
#pragma unroll
            for (int j = 0; j < 4; j++) {
                const int row = m0 + wm * 32 + mi * 16 + kg * 4 + j;
                x[(size_t)row * 512 + col] = (acc[mi][ni][j] + b) * g[(size_t)row * 512 + col];
            }
    }
}

// ================= spatial rmsnorm: h fp32 + hb bf16 + ss[0] =================
__global__ __launch_bounds__(256) void rms_sp_k(
    const float* __restrict__ x, const float* __restrict__ w,
    float* __restrict__ h, short* __restrict__ hb, float* __restrict__ ss0)
{
    const int lane = threadIdx.x & 63;
    const int rowId = blockIdx.x * 4 + (threadIdx.x >> 6);
    const float* ip = x + (size_t)rowId * 512 + lane * 8;
    const float4 v1 = *(const float4*)ip;
    const float4 v2 = *(const float4*)(ip + 4);
    float sq = v1.x * v1.x + v1.y * v1.y + v1.z * v1.z + v1.w * v1.w
             + v2.x * v2.x + v2.y * v2.y + v2.z * v2.z + v2.w * v2.w;
#pragma unroll
    for (int off = 32; off > 0; off >>= 1) sq += __shfl_xor(sq, off, 64);
    const float rs = rsqrtf(sq * (1.f / 512.f) + 1e-5f);
    const float4 w1 = *(const float4*)(w + lane * 8);
    const float4 w2 = *(const float4*)(w + lane * 8 + 4);
    const float o[8] = { v1.x * rs * w1.x, v1.y * rs * w1.y, v1.z * rs * w1.z, v1.w * rs * w1.w,
                         v2.x * rs * w2.x, v2.y * rs * w2.y, v2.z * rs * w2.z, v2.w * rs * w2.w };
    float* op = h + (size_t)rowId * 512 + lane * 8;
    *(float4*)op       = make_float4(o[0], o[1], o[2], o[3]);
    *(float4*)(op + 4) = make_float4(o[4], o[5], o[6], o[7]);
    short8 pk;
#pragma unroll
    for (int i = 0; i < 8; i++) pk[i] = f2b(o[i]);
    *(short8*)(hb + (size_t)rowId * 512 + lane * 8) = pk;
    float s2 = 0.f;
#pragma unroll
    for (int i = 0; i < 8; i++) s2 = fmaf(o[i], o[i], s2);
#pragma unroll
    for (int off = 32; off > 0; off >>= 1) s2 += __shfl_xor(s2, off, 64);
    if (lane == 0) ss0[rowId] = s2;
}

// ================= in_proj + fused depthwise conv + silu (64x64 tile) =================
union ConvU {
    struct { short As[2 * 64 * 32]; short Bs[2 * 64 * 32]; } gm;   // 16 KB (GEMM)
    float cbuf[67][68];                                             // 18.2 KB (conv)
};

__global__ __launch_bounds__(256) void inprojconv_k(
    const short* __restrict__ A, const short* __restrict__ W,
    const float* __restrict__ ss_in, const float* __restrict__ cw,
    const float* __restrict__ cb, short* __restrict__ xcb, short* __restrict__ srb)
{
    __shared__ ConvU u;
    f32x4 acc[2][2] = {};
    const int m0 = blockIdx.y * 64, n0 = blockIdx.x * 64;
    gemm_core64(acc, A, 512, W, 512, 512, u.gm.As, u.gm.Bs, m0, n0);
    const int tid = threadIdx.x;
    const int lane = tid & 63, wave = tid >> 6;
    const int wm = wave >> 1, wn = wave & 1, l15 = lane & 15, kg = lane >> 4;

#pragma unroll
    for (int mi = 0; mi < 2; mi++)
#pragma unroll
        for (int j = 0; j < 4; j++) {
            const int row = m0 + wm * 32 + mi * 16 + kg * 4 + j;
            const float r = rsqrtf(ss_in[row] * (1.f / 512.f) + 1e-5f);
#pragma unroll
            for (int ni = 0; ni < 2; ni++) acc[mi][ni][j] *= r;
        }

    if (n0 < 1024) {
        const int ccol = tid & 63;
        const int rg = tid >> 6;           // 0..3
        const int d = n0 + ccol;
        const float4 w4 = *(const float4*)(cw + d * 4);
        const float bia = cb[d];

        __syncthreads();   // gemm LDS reads done
#pragma unroll
        for (int mi = 0; mi < 2; mi++)
#pragma unroll
            for (int ni = 0; ni < 2; ni++)
#pragma unroll
                for (int j = 0; j < 4; j++)
                    u.cbuf[3 + wm * 32 + mi * 16 + kg * 4 + j][wn * 32 + ni * 16 + l15] = acc[mi][ni][j];
        for (int i = tid; i < 3 * 68; i += 256) u.cbuf[i / 68][i % 68] = 0.f;
        __syncthreads();
#pragma unroll 4
        for (int k = 0; k < 16; k++) {
            const int row = rg + 4 * k;    // 0..63
            float v = bia + w4.x * u.cbuf[row][ccol] + w4.y * u.cbuf[row + 1][ccol]
                          + w4.z * u.cbuf[row + 2][ccol] + w4.w * u.cbuf[row + 3][ccol];
            v = v * sigm(v);
            xcb[(size_t)(m0 + row) * 1024 + d] = f2b(v);
        }
    } else {
#pragma unroll
        for (int ni = 0; ni < 2; ni++) {
            const int scol = n0 - 1024 + wn * 32 + ni * 16 + l15;
#pragma unroll
            for (int mi = 0; mi < 2; mi++)
#pragma unroll
                for (int j = 0; j < 4; j++) {
                    const int row = m0 + wm * 32 + mi * 16 + kg * 4 + j;
                    const float v = acc[mi][ni][j];
                    srb[(size_t)row * 1024 + scol] = f2b(v * sigm(v));
                }
        }
    }
}

// ================= fused x_proj/dt + scan, ONE GEMM pass (R10, verified) =================
union XsU {
    struct { short As[2 * 64 * 32]; short Wd[2 * 64 * 32]; short BC[2 * 32 * 32]; } gm; // 20 KB
    struct { float dlt[64][68]; float BC[64][32]; } sc;                                  // 25.6 KB
};

__global__ __launch_bounds__(256) void xpdscan_k(
    const short* __restrict__ A /*xcb*/, const short* __restrict__ W /*wxpdb layer*/,
    const float* __restrict__ dtb, const float* __restrict__ Alog,
    const float* __restrict__ Dp, const short* __restrict__ srb, short* __restrict__ yb)
{
    __shared__ XsU u;
    const int dg = blockIdx.x, b = blockIdx.y;
    const int m0 = b * 64;
    const int tid = threadIdx.x;
    const int lane = tid & 63, wave = tid >> 6;
    const int wm = wave >> 1, wn = wave & 1, l15 = lane & 15, kg = lane >> 4;

    constexpr int SZA = 64 * 32, SZBC = 32 * 32;
    const int p = wave * 64 + lane;   // chunk id
    const short* srcA  = A + (size_t)(m0 + (p >> 2)) * 1024 + (p & 3) * 8;
    const short* srcWd = W + (size_t)(32 + dg * 64 + (p >> 2)) * 1024 + (p & 3) * 8;
    const short* srcBC = W + (size_t)(p >> 2) * 1024 + (p & 3) * 8;   // valid for p<128 (waves 0,1)
    const int ob = (wave * 64) * 8;

    f32x4 accd[2][2] = {};
    f32x4 accx[2] = {};

    __builtin_amdgcn_global_load_lds((const glb_u32_t*)srcA,  (lds_u32_t*)(u.gm.As + ob), 16, 0, 0);
    __builtin_amdgcn_global_load_lds((const glb_u32_t*)srcWd, (lds_u32_t*)(u.gm.Wd + ob), 16, 0, 0);
    if (wave < 2)
        __builtin_amdgcn_global_load_lds((const glb_u32_t*)srcBC, (lds_u32_t*)(u.gm.BC + ob), 16, 0, 0);

    for (int t = 0; t < 32; t++) {
        __syncthreads();
        if (t + 1 < 32) {
            const int k0 = (t + 1) * 32;
            const int sA = ((t + 1) & 1) * SZA, sBC = ((t + 1) & 1) * SZBC;
            __builtin_amdgcn_global_load_lds((const glb_u32_t*)(srcA + k0),  (lds_u32_t*)(u.gm.As + sA + ob), 16, 0, 0);
            __builtin_amdgcn_global_load_lds((const glb_u32_t*)(srcWd + k0), (lds_u32_t*)(u.gm.Wd + sA + ob), 16, 0, 0);
            if (wave < 2)
                __builtin_amdgcn_global_load_lds((const glb_u32_t*)(srcBC + k0), (lds_u32_t*)(u.gm.BC + sBC + ob), 16, 0, 0);
        }
        const short* Ab  = u.gm.As + (t & 1) * SZA;
        const short* Wdb = u.gm.Wd + (t & 1) * SZA;
        const short* BCb = u.gm.BC + (t & 1) * SZBC;
        short8 af[2], wf[2], bcf;
#pragma unroll
        for (int mi = 0; mi < 2; mi++)
            af[mi] = *(const short8*)(Ab + (wm * 32 + mi * 16 + l15) * 32 + kg * 8);
#pragma unroll
        for (int ni = 0; ni < 2; ni++)
            wf[ni] = *(const short8*)(Wdb + (wn * 32 + ni * 16 + l15) * 32 + kg * 8);
        bcf = *(const short8*)(BCb + (wn * 16 + l15) * 32 + kg * 8);
#pragma unroll
        for (int mi = 0; mi < 2; mi++) {
#pragma unroll
            for (int ni = 0; ni < 2; ni++)
                accd[mi][ni] = __builtin_amdgcn_mfma_f32_16x16x32_bf16(af[mi], wf[ni], accd[mi][ni], 0, 0, 0);
            accx[mi] = __builtin_amdgcn_mfma_f32_16x16x32_bf16(af[mi], bcf, accx[mi], 0, 0, 0);
        }
    }

    __syncthreads();   // gemm LDS reads done before repurposing union
#pragma unroll
    for (int ni = 0; ni < 2; ni++) {
        const int dl = wn * 32 + ni * 16 + l15;
        const float bb = dtb[dg * 64 + dl];
#pragma unroll
        for (int mi = 0; mi < 2; mi++)
#pragma unroll
            for (int j = 0; j < 4; j++)
                u.sc.dlt[wm * 32 + mi * 16 + kg * 4 + j][dl] = softp(accd[mi][ni][j] + bb);
    }
    {
        const int c = wn * 16 + l15;
#pragma unroll
        for (int mi = 0; mi < 2; mi++)
#pragma unroll
            for (int j = 0; j < 4; j++)
                u.sc.BC[wm * 32 + mi * 16 + kg * 4 + j][c] = accx[mi][j];
    }
    __syncthreads();

    if (tid < 64) {
        const int d = dg * 64 + tid;
        float a[16], s[16];
#pragma unroll
        for (int n = 0; n < 16; n++) { a[n] = -__expf(Alog[(size_t)d * 16 + n]); s[n] = 0.f; }
        const float dv = Dp[d];
        const size_t base = (size_t)b * SEQ;
        float uu = b2f(A[base * DINNER + d]);
        float rr = b2f(srb[base * 1024 + d]);
        for (int l = 0; l < SEQ; l++) {
            float uu_n = 0.f, rr_n = 0.f;
            if (l + 1 < SEQ) {
                uu_n = b2f(A[(base + l + 1) * DINNER + d]);
                rr_n = b2f(srb[(base + l + 1) * 1024 + d]);
            }
            const float dlt = u.sc.dlt[l][tid];
            const float dbu = dlt * uu;
            float acc = 0.f;
#pragma unroll
            for (int n = 0; n < 16; n++) {
                s[n] = __expf(dlt * a[n]) * s[n] + dbu * u.sc.BC[l][n];
                acc = fmaf(s[n], u.sc.BC[l][16 + n], acc);
            }
            acc = fmaf(uu, dv, acc);
            yb[(base + l) * DINNER + d] = f2b(acc * rr);
            uu = uu_n; rr = rr_n;
        }
    }
}

// ================= out_proj: 32x64 tile (grid 256 = full machine; R10, verified) =======
__global__ __launch_bounds__(256) void outproj_k(
    const short* __restrict__ A, const short* __restrict__ W,
    float* __restrict__ h, short* __restrict__ hb, float* __restrict__ ss_out)
{
    __shared__ short As[2 * 32 * 32];   // 4 KB dbuf
    __shared__ short Bs[2 * 64 * 32];   // 8 KB dbuf
    constexpr int SZA = 32 * 32, SZB = 64 * 32;
    const int m0 = blockIdx.y * 32, n0 = blockIdx.x * 64;
    const int tid = threadIdx.x, wave = tid >> 6, lane = tid & 63;
    const int l15 = lane & 15, kg = lane >> 4;

    const int p = wave * 64 + lane;   // 0..255
    const short* srcA = A + (size_t)(m0 + (p >> 2)) * 1024 + (p & 3) * 8;   // valid p<128
    const short* srcB = W + (size_t)(n0 + (p >> 2)) * 1024 + (p & 3) * 8;
    const int ob = (wave * 64) * 8;

    f32x4 acc[2] = {};
    if (wave < 2)
        __builtin_amdgcn_global_load_lds((const glb_u32_t*)srcA, (lds_u32_t*)(As + ob), 16, 0, 0);
    __builtin_amdgcn_global_load_lds((const glb_u32_t*)srcB, (lds_u32_t*)(Bs + ob), 16, 0, 0);

    for (int t = 0; t < 32; t++) {
        __syncthreads();
        if (t + 1 < 32) {
            const int k0 = (t + 1) * 32;
            const int sA = ((t + 1) & 1) * SZA, sB = ((t + 1) & 1) * SZB;
            if (wave < 2)
                __builtin_amdgcn_global_load_lds((const glb_u32_t*)(srcA + k0), (lds_u32_t*)(As + sA + ob), 16, 0, 0);
            __builtin_amdgcn_global_load_lds((const glb_u32_t*)(srcB + k0), (lds_u32_t*)(Bs + sB + ob), 16, 0, 0);
        }
        const short* Ab = As + (t & 1) * SZA;
        const short* Bb = Bs + (t & 1) * SZB;
        short8 af[2], bf;
#pragma unroll
        for (int mi = 0; mi < 2; mi++)
            af[mi] = *(const short8*)(Ab + (mi * 16 + l15) * 32 + kg * 8);
        bf = *(const short8*)(Bb + (wave * 16 + l15) * 32 + kg * 8);
#pragma unroll
        for (int mi = 0; mi < 2; mi++)
            acc[mi] = __builtin_amdgcn_mfma_f32_16x16x32_bf16(af[mi], bf, acc[mi], 0, 0, 0);
    }

    const int col = n0 + wave * 16 + l15;
    float vsq[2][4] = {};
#pragma unroll
    for (int mi = 0; mi < 2; mi++)
#pragma unroll
        for (int j = 0; j < 4; j++) {
            const int row = m0 + mi * 16 + kg * 4 + j;
            const float v = acc[mi][j] + h[(size_t)row * 512 + col];
            h[(size_t)row * 512 + col] = v;
            hb[(size_t)row * 512 + col] = f2b(v);
            vsq[mi][j] = v * v;
        }
#pragma unroll
    for (int mi = 0; mi < 2; mi++)
#pragma unroll
        for (int j = 0; j < 4; j++) {
            float t = vsq[mi][j];
            t += __shfl_xor(t, 1, 64);
            t += __shfl_xor(t, 2, 64);
            t += __shfl_xor(t, 4, 64);
            t += __shfl_xor(t, 8, 64);
            if (l15 == 0) {
                const int row = m0 + mi * 16 + kg * 4 + j;
                atomicAdd(ss_out + row, t);
            }
        }
}

// ================= final proj: xr = r[row] * (hb @ (W.gamma)^T) =================
__global__ __launch_bounds__(256) void projf_k(
    const short* __restrict__ A, const short* __restrict__ W,
    const float* __restrict__ ss_in, float* __restrict__ xr)
{
    __shared__ short As[2 * 64 * 32];
    __shared__ short Bs[2 * 64 * 32];
    f32x4 acc[2][2] = {};
    const int m0 = blockIdx.y * 64, n0 = blockIdx.x * 64;
    gemm_core64(acc, A, 512, W, 512, 512, As, Bs, m0, n0);
    const int lane = threadIdx.x & 63, wave = threadIdx.x >> 6;
    const int wm = wave >> 1, wn = wave & 1, l15 = lane & 15, kg = lane >> 4;
#pragma unroll
    for (int mi = 0; mi < 2; mi++)
#pragma unroll
        for (int j = 0; j < 4; j++) {
            const int row = m0 + wm * 32 + mi * 16 + kg * 4 + j;
            const float r = rsqrtf(ss_in[row] * (1.f / 512.f) + 1e-5f);
#pragma unroll
            for (int ni = 0; ni < 2; ni++) {
                const int col = n0 + wn * 32 + ni * 16 + l15;
                xr[(size_t)row * 2048 + col] = acc[mi][ni][j] * r;
            }
        }
}

// ================= coeffs + preds =================
__global__ __launch_bounds__(256) void coeffs_k(
    const float* __restrict__ outp, const float* __restrict__ inp,
    float* __restrict__ coeffs, float* __restrict__ preds)
{
    const int m = blockIdx.x;
    const int b = m >> 6;
    const int tid = threadIdx.x, wave = tid >> 6, lane = tid & 63;
    __shared__ float4 Us[256], Vs[256];
    __shared__ float ins[256];
    __shared__ float4 tpart[4];
    Us[tid] = *(const float4*)(outp + (size_t)m * 2048 + tid * 4);
    Vs[tid] = *(const float4*)(outp + (size_t)m * 2048 + 1024 + tid * 4);
    ins[tid] = inp[(size_t)m * 256 + tid];
    __syncthreads();
    const float4 vq0 = Vs[lane * 4 + 0], vq1 = Vs[lane * 4 + 1];
    const float4 vq2 = Vs[lane * 4 + 2], vq3 = Vs[lane * 4 + 3];
    float* cbase = coeffs + (size_t)m * 65536 + lane * 4;
#pragma unroll 4
    for (int i = 0; i < 64; i++) {
        const int pp = (wave << 6) + i;
        const float4 up = Us[pp];
        float4 c;
        c.x = up.x * vq0.x + up.y * vq0.y + up.z * vq0.z + up.w * vq0.w;
        c.y = up.x * vq1.x + up.y * vq1.y + up.z * vq1.z + up.w * vq1.w;
        c.z = up.x * vq2.x + up.y * vq2.y + up.z * vq2.z + up.w * vq2.w;
        c.w = up.x * vq3.x + up.y * vq3.y + up.z * vq3.z + up.w * vq3.w;
        *(float4*)(cbase + (size_t)pp * 256) = c;
    }
    const float iv = ins[tid];
    const float4 vm = Vs[tid];
    float4 t = make_float4(vm.x * iv, vm.y * iv, vm.z * iv, vm.w * iv);
#pragma unroll
    for (int off = 32; off > 0; off >>= 1) {
        t.x += __shfl_xor(t.x, off, 64);
        t.y += __shfl_xor(t.y, off, 64);
        t.z += __shfl_xor(t.z, off, 64);
        t.w += __shfl_xor(t.w, off, 64);
    }
    if (lane == 0) tpart[wave] = t;
    __syncthreads();
    const float4 t0 = tpart[0], t1 = tpart[1], t2 = tpart[2], t3 = tpart[3];
    const float4 tt = make_float4(t0.x + t1.x + t2.x + t3.x, t0.y + t1.y + t2.y + t3.y,
                                  t0.z + t1.z + t2.z + t3.z, t0.w + t1.w + t2.w + t3.w);
    const float4 up = Us[tid];
    const float pv = up.x * tt.x + up.y * tt.y + up.z * tt.z + up.w * tt.w;
    atomicAdd(preds + (size_t)b * 256 + tid, pv);
}

} // namespace

extern "C" void kernel_launch(void* const* d_in, const int* in_sizes, int n_in,
                              void* d_out, int out_size, void* d_ws, size_t ws_size,
                              hipStream_t stream)
{
    const float* inputs     = (const float*)d_in[0];
    const float* lin1_w     = (const float*)d_in[1];
    const float* lin1_b     = (const float*)d_in[2];
    const float* lin2_w     = (const float*)d_in[3];
    const float* lin2_b     = (const float*)d_in[4];
    const float* gate_w     = (const float*)d_in[5];
    const float* gate_b     = (const float*)d_in[6];
    const float* sp_norm_w  = (const float*)d_in[7];
    const float* in_proj_w  = (const float*)d_in[8];
    const float* conv_w     = (const float*)d_in[9];
    const float* conv_b     = (const float*)d_in[10];
    const float* x_proj_w   = (const float*)d_in[11];
    const float* dt_proj_w  = (const float*)d_in[12];
    const float* dt_proj_b  = (const float*)d_in[13];
    const float* A_log      = (const float*)d_in[14];
    const float* Dvec       = (const float*)d_in[15];
    const float* out_proj_w = (const float*)d_in[16];
    const float* blk_norm_w = (const float*)d_in[17];
    const float* post_norm_w= (const float*)d_in[18];
    const float* proj_w     = (const float*)d_in[19];

    float* ws = (float*)d_ws;
    // fp32 region
    float* h     = ws;                 // 1024 x 512
    float* xr    = ws + 524288;        // 1024 x 2048 (final proj out)
    float* x     = ws + 2621440;       // 1024 x 512 (lin2 out)
    float* g     = ws + 3145728;       // 1024 x 512
    float* ss    = ws + 3670016;       // 5 x 1024 sumsq slots
    // bf16 region
    short* bfb     = (short*)(ws + 3676160);
    short* inputsb = bfb;               // 1024 x 256
    short* h1b     = bfb + 262144;      // 1024 x 512
    short* hb      = bfb + 786432;      // 1024 x 512
    short* xcb     = bfb + 1310720;     // 1024 x 1024
    short* yb      = bfb + 2359296;     // 1024 x 1024
    short* srb     = bfb + 3407872;     // 1024 x 1024 silu(res)
    short* wlin1gb = bfb + 4456448;     // 1024 x 256
    short* wlin2b  = bfb + 4718592;     // 512 x 512
    short* winpb   = bfb + 4980736;     // 4 x 2048 x 512 (gamma-folded)
    short* woutpb  = bfb + 9175040;     // 4 x 512 x 1024
    short* wprojb  = bfb + 11272192;    // 2048 x 512 (gamma-folded)
    short* wxpdb   = bfb + 12320768;    // 4 x 1056 x 1024 ([BC; W_delta])
    float* preds  = (float*)d_out;
    float* coeffs = (float*)d_out + 4096;

    const dim3 blk(256);

    prep_k<<<dim3(2048), blk, 0, stream>>>(
        lin1_w, gate_w, lin2_w, in_proj_w, out_proj_w, proj_w, x_proj_w, dt_proj_w,
        inputs, blk_norm_w, post_norm_w,
        wlin1gb, wlin2b, winpb, woutpb, wprojb, wxpdb, inputsb, preds, ss);

    lin1gate_k<<<dim3(16, 16), blk, 0, stream>>>(inputsb, wlin1gb, lin1_b, gate_b, h1b, g);
    lin2_k<<<dim3(8, 16), blk, 0, stream>>>(h1b, wlin2b, lin2_b, g, x);
    rms_sp_k<<<dim3(256), blk, 0, stream>>>(x, sp_norm_w, h, hb, ss);

    for (int l = 0; l < 4; l++) {
        inprojconv_k<<<dim3(32, 16), blk, 0, stream>>>(
            hb, winpb + (size_t)l * 1048576, ss + l * 1024,
            conv_w + (size_t)l * 4096, conv_b + l * 1024, xcb, srb);
        xpdscan_k<<<dim3(16, 16), blk, 0, stream>>>(
            xcb, wxpdb + (size_t)l * WXPD_STRIDE, dt_proj_b + l * 1024,
            A_log + (size_t)l * 16384, Dvec + l * 1024, srb, yb);
        outproj_k<<<dim3(8, 32), blk, 0, stream>>>(yb, woutpb + (size_t)l * 524288,
                                                   h, hb, ss + (l + 1) * 1024);
    }

    projf_k<<<dim3(32, 16), blk, 0, stream>>>(hb, wprojb, ss + 4096, xr);
    coeffs_k<<<dim3(1024), blk, 0, stream>>>(xr, inputs, coeffs, preds);
}

// Round 12
// 403.964 us; speedup vs baseline: 1.3505x; 1.0252x over previous
//
#include <hip/hip_runtime.h>
#include <hip/hip_bf16.h>
#include <math.h>

namespace {

constexpr int SEQ    = 64;
constexpr int DINNER = 1024;
constexpr int WXPD_STRIDE = 1056 * 1024;   // rows 0..31 = BC weights, 32..1055 = W_delta

typedef __attribute__((ext_vector_type(8))) short short8;
typedef __attribute__((ext_vector_type(4))) float f32x4;
typedef __attribute__((address_space(3))) unsigned int lds_u32_t;
typedef __attribute__((address_space(1))) unsigned int glb_u32_t;

__device__ __forceinline__ float sigm(float x) { return 1.f / (1.f + __expf(-x)); }
__device__ __forceinline__ short f2b(float v) {
    __hip_bfloat16 h = __float2bfloat16(v);
    return *(short*)&h;
}
__device__ __forceinline__ float b2f(short s) {
    union { unsigned u; float f; } c; c.u = ((unsigned)(unsigned short)s) << 16; return c.f;
}
__device__ __forceinline__ float softp(float v) {
    return fmaxf(v, 0.f) + log1pf(__expf(-fabsf(v)));
}

// ====== bf16 MFMA GEMM core, 64x64 tile, 2-phase pipelined (R8, verified) ======
__device__ __forceinline__ void gemm_core64(
    f32x4 (&acc)[2][2],
    const short* __restrict__ A, int lda,
    const short* __restrict__ W, int ldw,
    int Kd, short* As, short* Bs, int m0, int n0)
{
    constexpr int SZ = 64 * 32;
    const int tid = threadIdx.x, wave = tid >> 6, lane = tid & 63;
    const int wm = wave >> 1, wn = wave & 1;
    const int l15 = lane & 15, kg = lane >> 4;

    const int p = wave * 64 + lane;   // 16B chunk: row p>>2, slot p&3
    const short* srcA = A + (size_t)(m0 + (p >> 2)) * lda + (p & 3) * 8;
    const short* srcB = W + (size_t)(n0 + (p >> 2)) * ldw + (p & 3) * 8;
    const int ob = (wave * 64) * 8;   // wave-uniform LDS base (shorts)

    const int nt = Kd >> 5;
    __builtin_amdgcn_global_load_lds((const glb_u32_t*)srcA, (lds_u32_t*)(As + ob), 16, 0, 0);
    __builtin_amdgcn_global_load_lds((const glb_u32_t*)srcB, (lds_u32_t*)(Bs + ob), 16, 0, 0);

    for (int t = 0; t < nt; t++) {
        __syncthreads();   // drains stage for buf[t&1] + prior ds_reads
        if (t + 1 < nt) {
            const int k0 = (t + 1) * 32;
            const int s = ((t + 1) & 1) * SZ;
            __builtin_amdgcn_global_load_lds((const glb_u32_t*)(srcA + k0), (lds_u32_t*)(As + s + ob), 16, 0, 0);
            __builtin_amdgcn_global_load_lds((const glb_u32_t*)(srcB + k0), (lds_u32_t*)(Bs + s + ob), 16, 0, 0);
        }
        const short* Ab = As + (t & 1) * SZ;
        const short* Bb = Bs + (t & 1) * SZ;
        short8 af[2], bfr[2];
#pragma unroll
        for (int mi = 0; mi < 2; mi++)
            af[mi] = *(const short8*)(Ab + (wm * 32 + mi * 16 + l15) * 32 + kg * 8);
#pragma unroll
        for (int ni = 0; ni < 2; ni++)
            bfr[ni] = *(const short8*)(Bb + (wn * 32 + ni * 16 + l15) * 32 + kg * 8);
#pragma unroll
        for (int mi = 0; mi < 2; mi++)
#pragma unroll
            for (int ni = 0; ni < 2; ni++)
                acc[mi][ni] = __builtin_amdgcn_mfma_f32_16x16x32_bf16(af[mi], bfr[ni], acc[mi][ni], 0, 0, 0);
    }
}
// C/D frag [m89]: col = n0 + wn*32 + ni*16 + (lane&15);
//                 row = m0 + wm*32 + mi*16 + (lane>>4)*4 + j

// ================= prep =================
// W_delta branch: 2 rows/wave (halves L2 re-reads); keep VGPR low (R10 lesson: no LDS).
__global__ __launch_bounds__(256) void prep_k(
    const float* __restrict__ lin1_w, const float* __restrict__ gate_w,
    const float* __restrict__ lin2_w, const float* __restrict__ in_proj_w,
    const float* __restrict__ out_proj_w, const float* __restrict__ proj_w,
    const float* __restrict__ x_proj_w, const float* __restrict__ dt_proj_w,
    const float* __restrict__ inputs, const float* __restrict__ blk_norm_w,
    const float* __restrict__ post_norm_w, const float* __restrict__ sp_norm_w,
    short* __restrict__ wlin1gb, short* __restrict__ wlin2b, short* __restrict__ winpb,
    short* __restrict__ woutpb, short* __restrict__ wprojb, short* __restrict__ wxpdb,
    short* __restrict__ inputsb, float* __restrict__ preds, float* __restrict__ ss)
{
    const int blk = blockIdx.x, tid = threadIdx.x;
    if (blk < 512) {
        // W_delta = dt_w(1024x32) @ xp_w[:32](32x1024); 2 n-rows per wave
        const int wave = tid >> 6, lane = tid & 63;
        const int nrow = blk * 8 + wave * 2;      // 0..4094 (even)
        const int l = nrow >> 10, n = nrow & 1023;
        const float* dtw0 = dt_proj_w + (size_t)l * 32768 + n * 32;
        const float* dtw1 = dtw0 + 32;
        const float* xpw = x_proj_w + (size_t)l * 65536;
        float4 a0[4] = {}, a1[4] = {};
        for (int r = 0; r < 32; r++) {
            const float s0 = dtw0[r], s1 = dtw1[r];
#pragma unroll
            for (int rep = 0; rep < 4; rep++) {
                const float4 xv = *(const float4*)(xpw + r * 1024 + rep * 256 + lane * 4);
                a0[rep].x = fmaf(s0, xv.x, a0[rep].x); a0[rep].y = fmaf(s0, xv.y, a0[rep].y);
                a0[rep].z = fmaf(s0, xv.z, a0[rep].z); a0[rep].w = fmaf(s0, xv.w, a0[rep].w);
                a1[rep].x = fmaf(s1, xv.x, a1[rep].x); a1[rep].y = fmaf(s1, xv.y, a1[rep].y);
                a1[rep].z = fmaf(s1, xv.z, a1[rep].z); a1[rep].w = fmaf(s1, xv.w, a1[rep].w);
            }
        }
        short* dst0 = wxpdb + (size_t)l * WXPD_STRIDE + (size_t)(32 + n) * 1024;
        short* dst1 = dst0 + 1024;
#pragma unroll
        for (int rep = 0; rep < 4; rep++) {
            union { short sh[4]; uint2 u; } p0, p1;
            p0.sh[0] = f2b(a0[rep].x); p0.sh[1] = f2b(a0[rep].y);
            p0.sh[2] = f2b(a0[rep].z); p0.sh[3] = f2b(a0[rep].w);
            p1.sh[0] = f2b(a1[rep].x); p1.sh[1] = f2b(a1[rep].y);
            p1.sh[2] = f2b(a1[rep].z); p1.sh[3] = f2b(a1[rep].w);
            *(uint2*)(dst0 + rep * 256 + lane * 4) = p0.u;
            *(uint2*)(dst1 + rep * 256 + lane * 4) = p1.u;
        }
    } else if (blk < 544) {
        // BC weights: xp_w rows 32..63 -> wxpdb rows 0..31 (bf16)
#pragma unroll
        for (int rep = 0; rep < 4; rep++) {
            const int idx = (blk - 512) * 4096 + rep * 1024 + tid * 4;   // < 131072
            const int l = idx >> 15, off = idx & 32767;
            const float4 v = *(const float4*)(x_proj_w + (size_t)l * 65536 + 32768 + off);
            union { short sh[4]; uint2 u; } pk;
            pk.sh[0] = f2b(v.x); pk.sh[1] = f2b(v.y); pk.sh[2] = f2b(v.z); pk.sh[3] = f2b(v.w);
            *(uint2*)(wxpdb + (size_t)l * WXPD_STRIDE + off) = pk.u;
        }
    } else if (blk < 1504) {
        constexpr int pre[8] = {0, 128, 256, 512, 4608, 6656, 7680, 7936};
        for (int vb = blk - 544; vb < 7936; vb += 960) {
            int s = 0;
#pragma unroll
            for (int i = 1; i < 7; i++) s += (vb >= pre[i]);
            const int e = (vb - pre[s]) * 1024 + tid * 4;
            const float* src; short* dst;
            bool hasG = false; const float* gp = nullptr;
            bool hasSp = false;
            if      (s == 0) { src = lin1_w + e;     dst = wlin1gb + e; }
            else if (s == 1) { src = gate_w + e;     dst = wlin1gb + 131072 + e; }
            else if (s == 2) { src = lin2_w + e;     dst = wlin2b + e; }
            else if (s == 3) { src = in_proj_w + e;  dst = winpb + e;
                               hasG = true; gp = blk_norm_w + (e >> 20) * 512 + (e & 511);
                               hasSp = ((e >> 20) == 0); }   // layer 0: fold gamma_sp too
            else if (s == 4) { src = out_proj_w + e; dst = woutpb + e; }
            else if (s == 5) { src = proj_w + e;     dst = wprojb + e;
                               hasG = true; gp = post_norm_w + (e & 511); }
            else             { src = inputs + e;     dst = inputsb + e; }
            float4 v = *(const float4*)src;
            if (hasG) {
                const float4 gv = *(const float4*)gp;
                v.x *= gv.x; v.y *= gv.y; v.z *= gv.z; v.w *= gv.w;
            }
            if (hasSp) {
                const float4 sv = *(const float4*)(sp_norm_w + (e & 511));
                v.x *= sv.x; v.y *= sv.y; v.z *= sv.z; v.w *= sv.w;
            }
            union { short sh[4]; uint2 u; } pk;
            pk.sh[0] = f2b(v.x); pk.sh[1] = f2b(v.y); pk.sh[2] = f2b(v.z); pk.sh[3] = f2b(v.w);
            *(uint2*)dst = pk.u;
        }
    } else {
        const int i = (blk - 1504) * 256 + tid;   // < 10240
        if (i < 4096) preds[i] = 0.f;
        else ss[i - 4096] = 0.f;                   // zero ss slots 0..5 (6144 floats)
    }
}

// ================= spatial: lin1|gate merged (N=1024) =================
__global__ __launch_bounds__(256) void lin1gate_k(
    const short* __restrict__ A, const short* __restrict__ W,
    const float* __restrict__ b1, const float* __restrict__ b2,
    short* __restrict__ h1b, float* __restrict__ g)
{
    __shared__ short As[2 * 64 * 32];
    __shared__ short Bs[2 * 64 * 32];
    f32x4 acc[2][2] = {};
    const int m0 = blockIdx.y * 64, n0 = blockIdx.x * 64;
    gemm_core64(acc, A, 256, W, 256, 256, As, Bs, m0, n0);
    const int lane = threadIdx.x & 63, wave = threadIdx.x >> 6;
    const int wm = wave >> 1, wn = wave & 1, l15 = lane & 15, kg = lane >> 4;
#pragma unroll
    for (int ni = 0; ni < 2; ni++) {
        const int col = n0 + wn * 32 + ni * 16 + l15;
        const bool isG = col >= 512;
        const float b = isG ? b2[col - 512] : b1[col];
#pragma unroll
        for (int mi = 0; mi < 2; mi++)
#pragma unroll
            for (int j = 0; j < 4; j++) {
                const int row = m0 + wm * 32 + mi * 16 + kg * 4 + j;
                const float v = acc[mi][ni][j] + b;
                if (isG) g[(size_t)row * 512 + (col - 512)] = sigm(v);
                else     h1b[(size_t)row * 512 + col] = f2b(0.5f * v * (1.f + erff(v * 0.70710678f)));
            }
    }
}

// ================= lin2: x = (h1 @ W^T + b) * g; writes x fp32 + xb bf16 + S1/S2 ======
// S1 = sum x^2, S2 = sum (x*gamma_sp)^2 per row (atomics). Replaces rms_sp_k:
// layer-0 norm scale is recovered exactly from (S1,S2) downstream.
__global__ __launch_bounds__(256) void lin2_k(
    const short* __restrict__ A, const short* __restrict__ W,
    const float* __restrict__ bias, const float* __restrict__ g,
    const float* __restrict__ gsp, float* __restrict__ x, short* __restrict__ xb,
    float* __restrict__ ssS1, float* __restrict__ ssS2)
{
    __shared__ short As[2 * 64 * 32];
    __shared__ short Bs[2 * 64 * 32];
    f32x4 acc[2][2] = {};
    const int m0 = blockIdx.y * 64, n0 = blockIdx.x * 64;
    gemm_core64(acc, A, 512, W, 512, 512, As, Bs, m0, n0);
    const int lane = threadIdx.x & 63, wave = threadIdx.x >> 6;
    const int wm = wave >> 1, wn = wave & 1, l15 = lane & 15, kg = lane >> 4;
    float vs1[2][4] = {}, vs2[2][4] = {};
#pragma unroll
    for (int ni = 0; ni < 2; ni++) {
        const int col = n0 + wn * 32 + ni * 16 + l15;
        const float b = bias[col];
        const float gc = gsp[col];
#pragma unroll
        for (int mi = 0; mi < 2; mi++)
#pragma unroll
            for (int j = 0; j < 4; j++) {
                const int row = m0 + wm * 32 + mi * 16 + kg * 4 + j;
                const float v = (acc[mi][ni][j] + b) * g[(size_t)row * 512 + col];
                x[(size_t)row * 512 + col] = v;
                xb[(size_t)row * 512 + col] = f2b(v);
                vs1[mi][j] = fmaf(v, v, vs1[mi][j]);
                const float w = v * gc;
                vs2[mi][j] = fmaf(w, w, vs2[mi][j]);
            }
    }
#pragma unroll
    for (int mi = 0; mi < 2; mi++)
#pragma unroll
        for (int j = 0; j < 4; j++) {
            float t1 = vs1[mi][j], t2 = vs2[mi][j];
            t1 += __shfl_xor(t1, 1, 64); t2 += __shfl_xor(t2, 1, 64);
            t1 += __shfl_xor(t1, 2, 64); t2 += __shfl_xor(t2, 2, 64);
            t1 += __shfl_xor(t1, 4, 64); t2 += __shfl_xor(t2, 4, 64);
            t1 += __shfl_xor(t1, 8, 64); t2 += __shfl_xor(t2, 8, 64);
            if (l15 == 0) {
                const int row = m0 + wm * 32 + mi * 16 + kg * 4 + j;
                atomicAdd(ssS1 + row, t1);
                atomicAdd(ssS2 + row, t2);
            }
        }
}

// ================= in_proj + fused depthwise conv + silu (64x64 tile) =================
// COMB=1 (layer 0): A = xb, r = rs_x * rsqrt(rs_x^2*S2/512 + eps)  [exact double-rms]
// COMB=0 (layers 1-3): A = hb, r = rsqrt(ssA/512 + eps)
union ConvU {
    struct { short As[2 * 64 * 32]; short Bs[2 * 64 * 32]; } gm;   // 16 KB (GEMM)
    float cbuf[67][68];                                             // 18.2 KB (conv)
};

template <int COMB>
__global__ __launch_bounds__(256) void inprojconv_k(
    const short* __restrict__ A, const short* __restrict__ W,
    const float* __restrict__ ssA, const float* __restrict__ ssB,
    const float* __restrict__ cw, const float* __restrict__ cb,
    short* __restrict__ xcb, short* __restrict__ srb)
{
    __shared__ ConvU u;
    f32x4 acc[2][2] = {};
    const int m0 = blockIdx.y * 64, n0 = blockIdx.x * 64;
    gemm_core64(acc, A, 512, W, 512, 512, u.gm.As, u.gm.Bs, m0, n0);
    const int tid = threadIdx.x;
    const int lane = tid & 63, wave = tid >> 6;
    const int wm = wave >> 1, wn = wave & 1, l15 = lane & 15, kg = lane >> 4;

#pragma unroll
    for (int mi = 0; mi < 2; mi++)
#pragma unroll
        for (int j = 0; j < 4; j++) {
            const int row = m0 + wm * 32 + mi * 16 + kg * 4 + j;
            float r;
            if constexpr (COMB) {
                const float rx = rsqrtf(ssA[row] * (1.f / 512.f) + 1e-5f);
                r = rx * rsqrtf(rx * rx * ssB[row] * (1.f / 512.f) + 1e-5f);
            } else {
                r = rsqrtf(ssA[row] * (1.f / 512.f) + 1e-5f);
            }
#pragma unroll
            for (int ni = 0; ni < 2; ni++) acc[mi][ni][j] *= r;
        }

    if (n0 < 1024) {
        const int ccol = tid & 63;
        const int rg = tid >> 6;           // 0..3
        const int d = n0 + ccol;
        const float4 w4 = *(const float4*)(cw + d * 4);
        const float bia = cb[d];

        __syncthreads();   // gemm LDS reads done
#pragma unroll
        for (int mi = 0; mi < 2; mi++)
#pragma unroll
            for (int ni = 0; ni < 2; ni++)
#pragma unroll
                for (int j = 0; j < 4; j++)
                    u.cbuf[3 + wm * 32 + mi * 16 + kg * 4 + j][wn * 32 + ni * 16 + l15] = acc[mi][ni][j];
        for (int i = tid; i < 3 * 68; i += 256) u.cbuf[i / 68][i % 68] = 0.f;
        __syncthreads();
#pragma unroll 4
        for (int k = 0; k < 16; k++) {
            const int row = rg + 4 * k;    // 0..63
            float v = bia + w4.x * u.cbuf[row][ccol] + w4.y * u.cbuf[row + 1][ccol]
                          + w4.z * u.cbuf[row + 2][ccol] + w4.w * u.cbuf[row + 3][ccol];
            v = v * sigm(v);
            xcb[(size_t)(m0 + row) * 1024 + d] = f2b(v);
        }
    } else {
#pragma unroll
        for (int ni = 0; ni < 2; ni++) {
            const int scol = n0 - 1024 + wn * 32 + ni * 16 + l15;
#pragma unroll
            for (int mi = 0; mi < 2; mi++)
#pragma unroll
                for (int j = 0; j < 4; j++) {
                    const int row = m0 + wm * 32 + mi * 16 + kg * 4 + j;
                    const float v = acc[mi][ni][j];
                    srb[(size_t)row * 1024 + scol] = f2b(v * sigm(v));
                }
        }
    }
}

// ================= fused x_proj/dt + scan (4-lane-parallel scan) =================
union XsU {
    struct { short As[2 * 64 * 32]; short Wd[2 * 64 * 32]; short BC[2 * 32 * 32]; } gm; // 20 KB
    struct { float dlt[64][68]; float BC[64][32]; } sc;                                  // 25.6 KB
};

__global__ __launch_bounds__(256) void xpdscan_k(
    const short* __restrict__ A /*xcb*/, const short* __restrict__ W /*wxpdb layer*/,
    const float* __restrict__ dtb, const float* __restrict__ Alog,
    const float* __restrict__ Dp, const short* __restrict__ srb, short* __restrict__ yb)
{
    __shared__ XsU u;
    const int dg = blockIdx.x, b = blockIdx.y;
    const int m0 = b * 64;
    const int tid = threadIdx.x;
    const int lane = tid & 63, wave = tid >> 6;
    const int wm = wave >> 1, wn = wave & 1, l15 = lane & 15, kg = lane >> 4;

    constexpr int SZA = 64 * 32, SZBC = 32 * 32;
    const int p = wave * 64 + lane;   // chunk id
    const short* srcA  = A + (size_t)(m0 + (p >> 2)) * 1024 + (p & 3) * 8;
    const short* srcWd = W + (size_t)(32 + dg * 64 + (p >> 2)) * 1024 + (p & 3) * 8;
    const short* srcBC = W + (size_t)(p >> 2) * 1024 + (p & 3) * 8;   // valid for p<128 (waves 0,1)
    const int ob = (wave * 64) * 8;

    f32x4 accd[2][2] = {};
    f32x4 accx[2] = {};

    __builtin_amdgcn_global_load_lds((const glb_u32_t*)srcA,  (lds_u32_t*)(u.gm.As + ob), 16, 0, 0);
    __builtin_amdgcn_global_load_lds((const glb_u32_t*)srcWd, (lds_u32_t*)(u.gm.Wd + ob), 16, 0, 0);
    if (wave < 2)
        __builtin_amdgcn_global_load_lds((const glb_u32_t*)srcBC, (lds_u32_t*)(u.gm.BC + ob), 16, 0, 0);

    for (int t = 0; t < 32; t++) {
        __syncthreads();
        if (t + 1 < 32) {
            const int k0 = (t + 1) * 32;
            const int sA = ((t + 1) & 1) * SZA, sBC = ((t + 1) & 1) * SZBC;
            __builtin_amdgcn_global_load_lds((const glb_u32_t*)(srcA + k0),  (lds_u32_t*)(u.gm.As + sA + ob), 16, 0, 0);
            __builtin_amdgcn_global_load_lds((const glb_u32_t*)(srcWd + k0), (lds_u32_t*)(u.gm.Wd + sA + ob), 16, 0, 0);
            if (wave < 2)
                __builtin_amdgcn_global_load_lds((const glb_u32_t*)(srcBC + k0), (lds_u32_t*)(u.gm.BC + sBC + ob), 16, 0, 0);
        }
        const short* Ab  = u.gm.As + (t & 1) * SZA;
        const short* Wdb = u.gm.Wd + (t & 1) * SZA;
        const short* BCb = u.gm.BC + (t & 1) * SZBC;
        short8 af[2], wf[2], bcf;
#pragma unroll
        for (int mi = 0; mi < 2; mi++)
            af[mi] = *(const short8*)(Ab + (wm * 32 + mi * 16 + l15) * 32 + kg * 8);
#pragma unroll
        for (int ni = 0; ni < 2; ni++)
            wf[ni] = *(const short8*)(Wdb + (wn * 32 + ni * 16 + l15) * 32 + kg * 8);
        bcf = *(const short8*)(BCb + (wn * 16 + l15) * 32 + kg * 8);
#pragma unroll
        for (int mi = 0; mi < 2; mi++) {
#pragma unroll
            for (int ni = 0; ni < 2; ni++)
                accd[mi][ni] = __builtin_amdgcn_mfma_f32_16x16x32_bf16(af[mi], wf[ni], accd[mi][ni], 0, 0, 0);
            accx[mi] = __builtin_amdgcn_mfma_f32_16x16x32_bf16(af[mi], bcf, accx[mi], 0, 0, 0);
        }
    }

    __syncthreads();   // gemm LDS reads done before repurposing union
#pragma unroll
    for (int ni = 0; ni < 2; ni++) {
        const int dl = wn * 32 + ni * 16 + l15;
        const float bb = dtb[dg * 64 + dl];
#pragma unroll
        for (int mi = 0; mi < 2; mi++)
#pragma unroll
            for (int j = 0; j < 4; j++)
                u.sc.dlt[wm * 32 + mi * 16 + kg * 4 + j][dl] = softp(accd[mi][ni][j] + bb);
    }
    {
        const int c = wn * 16 + l15;
#pragma unroll
        for (int mi = 0; mi < 2; mi++)
#pragma unroll
            for (int j = 0; j < 4; j++)
                u.sc.BC[wm * 32 + mi * 16 + kg * 4 + j][c] = accx[mi][j];
    }
    __syncthreads();

    // 4-lane-parallel scan: thread group of 4 per d, 4 states each
    {
        const int d_l = tid >> 2;          // 0..63
        const int ns = (tid & 3) << 2;     // 0,4,8,12
        const int d = dg * 64 + d_l;
        float a[4], s[4];
#pragma unroll
        for (int n = 0; n < 4; n++) {
            a[n] = -__expf(Alog[(size_t)d * 16 + ns + n]);
            s[n] = 0.f;
        }
        const float dv = Dp[d];
        const size_t base = (size_t)b * SEQ;
        float uu = b2f(A[base * DINNER + d]);
        float rr = b2f(srb[base * 1024 + d]);
        for (int l = 0; l < SEQ; l++) {
            float uu_n = 0.f, rr_n = 0.f;
            if (l + 1 < SEQ) {
                uu_n = b2f(A[(base + l + 1) * DINNER + d]);
                rr_n = b2f(srb[(base + l + 1) * 1024 + d]);
            }
            const float dlt = u.sc.dlt[l][d_l];
            const float dbu = dlt * uu;
            float part = 0.f;
#pragma unroll
            for (int n = 0; n < 4; n++) {
                s[n] = __expf(dlt * a[n]) * s[n] + dbu * u.sc.BC[l][ns + n];
                part = fmaf(s[n], u.sc.BC[l][16 + ns + n], part);
            }
            part += __shfl_xor(part, 1, 64);
            part += __shfl_xor(part, 2, 64);
            if ((tid & 3) == 0)
                yb[(base + l) * DINNER + d] = f2b((part + uu * dv) * rr);
            uu = uu_n; rr = rr_n;
        }
    }
}

// ================= out_proj: 32x64 tile =================
// FIRST=1 (layer 0): residual base h0 = x * rs_x * gamma_sp computed on the fly.
template <int FIRST>
__global__ __launch_bounds__(256) void outproj_k(
    const short* __restrict__ A, const short* __restrict__ W,
    float* __restrict__ h, short* __restrict__ hb, float* __restrict__ ss_out,
    const float* __restrict__ xsrc, const float* __restrict__ gsp,
    const float* __restrict__ ssS1)
{
    __shared__ short As[2 * 32 * 32];   // 4 KB dbuf
    __shared__ short Bs[2 * 64 * 32];   // 8 KB dbuf
    constexpr int SZA = 32 * 32, SZB = 64 * 32;
    const int m0 = blockIdx.y * 32, n0 = blockIdx.x * 64;
    const int tid = threadIdx.x, wave = tid >> 6, lane = tid & 63;
    const int l15 = lane & 15, kg = lane >> 4;

    const int p = wave * 64 + lane;   // 0..255
    const short* srcA = A + (size_t)(m0 + (p >> 2)) * 1024 + (p & 3) * 8;   // valid p<128
    const short* srcB = W + (size_t)(n0 + (p >> 2)) * 1024 + (p & 3) * 8;
    const int ob = (wave * 64) * 8;

    f32x4 acc[2] = {};
    if (wave < 2)
        __builtin_amdgcn_global_load_lds((const glb_u32_t*)srcA, (lds_u32_t*)(As + ob), 16, 0, 0);
    __builtin_amdgcn_global_load_lds((const glb_u32_t*)srcB, (lds_u32_t*)(Bs + ob), 16, 0, 0);

    for (int t = 0; t < 32; t++) {
        __syncthreads();
        if (t + 1 < 32) {
            const int k0 = (t + 1) * 32;
            const int sA = ((t + 1) & 1) * SZA, sB = ((t + 1) & 1) * SZB;
            if (wave < 2)
                __builtin_amdgcn_global_load_lds((const glb_u32_t*)(srcA + k0), (lds_u32_t*)(As + sA + ob), 16, 0, 0);
            __builtin_amdgcn_global_load_lds((const glb_u32_t*)(srcB + k0), (lds_u32_t*)(Bs + sB + ob), 16, 0, 0);
        }
        const short* Ab = As + (t & 1) * SZA;
        const short* Bb = Bs + (t & 1) * SZB;
        short8 af[2], bf;
#pragma unroll
        for (int mi = 0; mi < 2; mi++)
            af[mi] = *(const short8*)(Ab + (mi * 16 + l15) * 32 + kg * 8);
        bf = *(const short8*)(Bb + (wave * 16 + l15) * 32 + kg * 8);
#pragma unroll
        for (int mi = 0; mi < 2; mi++)
            acc[mi] = __builtin_amdgcn_mfma_f32_16x16x32_bf16(af[mi], bf, acc[mi], 0, 0, 0);
    }

    const int col = n0 + wave * 16 + l15;
    const float gc = FIRST ? gsp[col] : 0.f;
    float vsq[2][4] = {};
#pragma unroll
    for (int mi = 0; mi < 2; mi++)
#pragma unroll
        for (int j = 0; j < 4; j++) {
            const int row = m0 + mi * 16 + kg * 4 + j;
            float hold;
            if constexpr (FIRST) {
                const float rx = rsqrtf(ssS1[row] * (1.f / 512.f) + 1e-5f);
                hold = xsrc[(size_t)row * 512 + col] * rx * gc;
            } else {
                hold = h[(size_t)row * 512 + col];
            }
            const float v = acc[mi][j] + hold;
            h[(size_t)row * 512 + col] = v;
            hb[(size_t)row * 512 + col] = f2b(v);
            vsq[mi][j] = v * v;
        }
#pragma unroll
    for (int mi = 0; mi < 2; mi++)
#pragma unroll
        for (int j = 0; j < 4; j++) {
            float t = vsq[mi][j];
            t += __shfl_xor(t, 1, 64);
            t += __shfl_xor(t, 2, 64);
            t += __shfl_xor(t, 4, 64);
            t += __shfl_xor(t, 8, 64);
            if (l15 == 0) {
                const int row = m0 + mi * 16 + kg * 4 + j;
                atomicAdd(ss_out + row, t);
            }
        }
}

// ================= final proj: xr = r[row] * (hb @ (W.gamma)^T) =================
__global__ __launch_bounds__(256) void projf_k(
    const short* __restrict__ A, const short* __restrict__ W,
    const float* __restrict__ ss_in, float* __restrict__ xr)
{
    __shared__ short As[2 * 64 * 32];
    __shared__ short Bs[2 * 64 * 32];
    f32x4 acc[2][2] = {};
    const int m0 = blockIdx.y * 64, n0 = blockIdx.x * 64;
    gemm_core64(acc, A, 512, W, 512, 512, As, Bs, m0, n0);
    const int lane = threadIdx.x & 63, wave = threadIdx.x >> 6;
    const int wm = wave >> 1, wn = wave & 1, l15 = lane & 15, kg = lane >> 4;
#pragma unroll
    for (int mi = 0; mi < 2; mi++)
#pragma unroll
        for (int j = 0; j < 4; j++) {
            const int row = m0 + wm * 32 + mi * 16 + kg * 4 + j;
            const float r = rsqrtf(ss_in[row] * (1.f / 512.f) + 1e-5f);
#pragma unroll
            for (int ni = 0; ni < 2; ni++) {
                const int col = n0 + wn * 32 + ni * 16 + l15;
                xr[(size_t)row * 2048 + col] = acc[mi][ni][j] * r;
            }
        }
}

// ================= coeffs + preds =================
__global__ __launch_bounds__(256) void coeffs_k(
    const float* __restrict__ outp, const float* __restrict__ inp,
    float* __restrict__ coeffs, float* __restrict__ preds)
{
    const int m = blockIdx.x;
    const int b = m >> 6;
    const int tid = threadIdx.x, wave = tid >> 6, lane = tid & 63;
    __shared__ float4 Us[256], Vs[256];
    __shared__ float ins[256];
    __shared__ float4 tpart[4];
    Us[tid] = *(const float4*)(outp + (size_t)m * 2048 + tid * 4);
    Vs[tid] = *(const float4*)(outp + (size_t)m * 2048 + 1024 + tid * 4);
    ins[tid] = inp[(size_t)m * 256 + tid];
    __syncthreads();
    const float4 vq0 = Vs[lane * 4 + 0], vq1 = Vs[lane * 4 + 1];
    const float4 vq2 = Vs[lane * 4 + 2], vq3 = Vs[lane * 4 + 3];
    float* cbase = coeffs + (size_t)m * 65536 + lane * 4;
#pragma unroll 4
    for (int i = 0; i < 64; i++) {
        const int pp = (wave << 6) + i;
        const float4 up = Us[pp];
        float4 c;
        c.x = up.x * vq0.x + up.y * vq0.y + up.z * vq0.z + up.w * vq0.w;
        c.y = up.x * vq1.x + up.y * vq1.y + up.z * vq1.z + up.w * vq1.w;
        c.z = up.x * vq2.x + up.y * vq2.y + up.z * vq2.z + up.w * vq2.w;
        c.w = up.x * vq3.x + up.y * vq3.y + up.z * vq3.z + up.w * vq3.w;
        *(float4*)(cbase + (size_t)pp * 256) = c;
    }
    const float iv = ins[tid];
    const float4 vm = Vs[tid];
    float4 t = make_float4(vm.x * iv, vm.y * iv, vm.z * iv, vm.w * iv);
#pragma unroll
    for (int off = 32; off > 0; off >>= 1) {
        t.x += __shfl_xor(t.x, off, 64);
        t.y += __shfl_xor(t.y, off, 64);
        t.z += __shfl_xor(t.z, off, 64);
        t.w += __shfl_xor(t.w, off, 64);
    }
    if (lane == 0) tpart[wave] = t;
    __syncthreads();
    const float4 t0 = tpart[0], t1 = tpart[1], t2 = tpart[2], t3 = tpart[3];
    const float4 tt = make_float4(t0.x + t1.x + t2.x + t3.x, t0.y + t1.y + t2.y + t3.y,
                                  t0.z + t1.z + t2.z + t3.z, t0.w + t1.w + t2.w + t3.w);
    const float4 up = Us[tid];
    const float pv = up.x * tt.x + up.y * tt.y + up.z * tt.z + up.w * tt.w;
    atomicAdd(preds + (size_t)b * 256 + tid, pv);
}

} // namespace

extern "C" void kernel_launch(void* const* d_in, const int* in_sizes, int n_in,
                              void* d_out, int out_size, void* d_ws, size_t ws_size,
                              hipStream_t stream)
{
    const float* inputs     = (const float*)d_in[0];
    const float* lin1_w     = (const float*)d_in[1];
    const float* lin1_b     = (const float*)d_in[2];
    const float* lin2_w     = (const float*)d_in[3];
    const float* lin2_b     = (const float*)d_in[4];
    const float* gate_w     = (const float*)d_in[5];
    const float* gate_b     = (const float*)d_in[6];
    const float* sp_norm_w  = (const float*)d_in[7];
    const float* in_proj_w  = (const float*)d_in[8];
    const float* conv_w     = (const float*)d_in[9];
    const float* conv_b     = (const float*)d_in[10];
    const float* x_proj_w   = (const float*)d_in[11];
    const float* dt_proj_w  = (const float*)d_in[12];
    const float* dt_proj_b  = (const float*)d_in[13];
    const float* A_log      = (const float*)d_in[14];
    const float* Dvec       = (const float*)d_in[15];
    const float* out_proj_w = (const float*)d_in[16];
    const float* blk_norm_w = (const float*)d_in[17];
    const float* post_norm_w= (const float*)d_in[18];
    const float* proj_w     = (const float*)d_in[19];

    float* ws = (float*)d_ws;
    // fp32 region
    float* h     = ws;                 // 1024 x 512
    float* xr    = ws + 524288;        // 1024 x 2048 (final proj out)
    float* x     = ws + 2621440;       // 1024 x 512 (lin2 out)
    float* g     = ws + 3145728;       // 1024 x 512
    float* ss    = ws + 3670016;       // slots: 0=S1, 1..4=sum h^2, 5=S2 (6144 floats)
    // bf16 region
    short* bfb     = (short*)(ws + 3676160);
    short* inputsb = bfb;               // 1024 x 256
    short* h1b     = bfb + 262144;      // 1024 x 512
    short* hb      = bfb + 786432;      // 1024 x 512
    short* xcb     = bfb + 1310720;     // 1024 x 1024
    short* yb      = bfb + 2359296;     // 1024 x 1024
    short* xb      = yb;                // 1024 x 512 ALIAS: dead until xpdscan l0 writes yb
    short* srb     = bfb + 3407872;     // 1024 x 1024 silu(res)
    short* wlin1gb = bfb + 4456448;     // 1024 x 256
    short* wlin2b  = bfb + 4718592;     // 512 x 512
    short* winpb   = bfb + 4980736;     // 4 x 2048 x 512 (gamma-folded; l0 also gamma_sp)
    short* woutpb  = bfb + 9175040;     // 4 x 512 x 1024
    short* wprojb  = bfb + 11272192;    // 2048 x 512 (gamma-folded)
    short* wxpdb   = bfb + 12320768;    // 4 x 1056 x 1024 ([BC; W_delta])
    float* preds  = (float*)d_out;
    float* coeffs = (float*)d_out + 4096;

    const dim3 blk(256);

    prep_k<<<dim3(1544), blk, 0, stream>>>(
        lin1_w, gate_w, lin2_w, in_proj_w, out_proj_w, proj_w, x_proj_w, dt_proj_w,
        inputs, blk_norm_w, post_norm_w, sp_norm_w,
        wlin1gb, wlin2b, winpb, woutpb, wprojb, wxpdb, inputsb, preds, ss);

    lin1gate_k<<<dim3(16, 16), blk, 0, stream>>>(inputsb, wlin1gb, lin1_b, gate_b, h1b, g);
    lin2_k<<<dim3(8, 16), blk, 0, stream>>>(h1b, wlin2b, lin2_b, g, sp_norm_w,
                                            x, xb, ss, ss + 5120);

    for (int l = 0; l < 4; l++) {
        if (l == 0)
            inprojconv_k<1><<<dim3(32, 16), blk, 0, stream>>>(
                xb, winpb, ss, ss + 5120,
                conv_w, conv_b, xcb, srb);
        else
            inprojconv_k<0><<<dim3(32, 16), blk, 0, stream>>>(
                hb, winpb + (size_t)l * 1048576, ss + l * 1024, nullptr,
                conv_w + (size_t)l * 4096, conv_b + l * 1024, xcb, srb);
        xpdscan_k<<<dim3(16, 16), blk, 0, stream>>>(
            xcb, wxpdb + (size_t)l * WXPD_STRIDE, dt_proj_b + l * 1024,
            A_log + (size_t)l * 16384, Dvec + l * 1024, srb, yb);
        if (l == 0)
            outproj_k<1><<<dim3(8, 32), blk, 0, stream>>>(yb, woutpb,
                h, hb, ss + 1024, x, sp_norm_w, ss);
        else
            outproj_k<0><<<dim3(8, 32), blk, 0, stream>>>(yb, woutpb + (size_t)l * 524288,
                h, hb, ss + (l + 1) * 1024, nullptr, nullptr, nullptr);
    }

    projf_k<<<dim3(32, 16), blk, 0, stream>>>(hb, wprojb, ss + 4096, xr);
    coeffs_k<<<dim3(1024), blk, 0, stream>>>(xr, inputs, coeffs, preds);
}

// Round 13
// 375.201 us; speedup vs baseline: 1.4540x; 1.0767x over previous
//
#include <hip/hip_runtime.h>
#include <hip/hip_bf16.h>
#include <math.h>

namespace {

constexpr int SEQ    = 64;
constexpr int DINNER = 1024;
constexpr int WXPD_STRIDE = 1056 * 1024;   // rows 0..31 = BC weights, 32..1055 = W_delta

typedef __attribute__((ext_vector_type(8))) short short8;
typedef __attribute__((ext_vector_type(4))) float f32x4;
typedef __attribute__((address_space(3))) unsigned int lds_u32_t;
typedef __attribute__((address_space(1))) unsigned int glb_u32_t;

__device__ __forceinline__ float sigm(float x) { return 1.f / (1.f + __expf(-x)); }
__device__ __forceinline__ short f2b(float v) {
    __hip_bfloat16 h = __float2bfloat16(v);
    return *(short*)&h;
}
__device__ __forceinline__ float b2f(short s) {
    union { unsigned u; float f; } c; c.u = ((unsigned)(unsigned short)s) << 16; return c.f;
}
__device__ __forceinline__ float softp(float v) {
    return fmaxf(v, 0.f) + log1pf(__expf(-fabsf(v)));
}

// ====== bf16 MFMA GEMM core, 64x64 tile, BK=64, 2-phase pipelined ======
// Halves barrier-drain count vs BK=32 (each __syncthreads emits vmcnt(0)).
// 128B row stride needs T2 XOR-swizzle: linear LDS dest + inverse-swizzled
// global SOURCE (rule #21) + swizzled ds_read: slot' = slot ^ (row&7).
__device__ __forceinline__ void gemm_core64(
    f32x4 (&acc)[2][2],
    const short* __restrict__ A, int lda,
    const short* __restrict__ W, int ldw,
    int Kd, short* As, short* Bs, int m0, int n0)
{
    constexpr int SZ = 64 * 64;          // shorts per buffer
    const int tid = threadIdx.x, wave = tid >> 6, lane = tid & 63;
    const int wm = wave >> 1, wn = wave & 1;
    const int l15 = lane & 15, kg = lane >> 4;

    // staging: 512 chunks (16B) per tile, 2 per thread. chunk q: row q>>3, slot q&7.
    const int r0 = tid >> 3,        s0 = tid & 7;
    const int r1 = 32 + (tid >> 3), s1 = s0;
    const short* srcA0 = A + (size_t)(m0 + r0) * lda + ((s0 ^ (r0 & 7)) * 8);
    const short* srcA1 = A + (size_t)(m0 + r1) * lda + ((s1 ^ (r1 & 7)) * 8);
    const short* srcB0 = W + (size_t)(n0 + r0) * ldw + ((s0 ^ (r0 & 7)) * 8);
    const short* srcB1 = W + (size_t)(n0 + r1) * ldw + ((s1 ^ (r1 & 7)) * 8);
    const int ob0 = wave * 512;           // wave-uniform LDS base (shorts)
    const int ob1 = 2048 + wave * 512;

    const int nt = Kd >> 6;
    __builtin_amdgcn_global_load_lds((const glb_u32_t*)srcA0, (lds_u32_t*)(As + ob0), 16, 0, 0);
    __builtin_amdgcn_global_load_lds((const glb_u32_t*)srcA1, (lds_u32_t*)(As + ob1), 16, 0, 0);
    __builtin_amdgcn_global_load_lds((const glb_u32_t*)srcB0, (lds_u32_t*)(Bs + ob0), 16, 0, 0);
    __builtin_amdgcn_global_load_lds((const glb_u32_t*)srcB1, (lds_u32_t*)(Bs + ob1), 16, 0, 0);

    for (int t = 0; t < nt; t++) {
        __syncthreads();   // drains stage for buf[t&1] + prior ds_reads
        if (t + 1 < nt) {
            const int k0 = (t + 1) * 64;
            const int s = ((t + 1) & 1) * SZ;
            __builtin_amdgcn_global_load_lds((const glb_u32_t*)(srcA0 + k0), (lds_u32_t*)(As + s + ob0), 16, 0, 0);
            __builtin_amdgcn_global_load_lds((const glb_u32_t*)(srcA1 + k0), (lds_u32_t*)(As + s + ob1), 16, 0, 0);
            __builtin_amdgcn_global_load_lds((const glb_u32_t*)(srcB0 + k0), (lds_u32_t*)(Bs + s + ob0), 16, 0, 0);
            __builtin_amdgcn_global_load_lds((const glb_u32_t*)(srcB1 + k0), (lds_u32_t*)(Bs + s + ob1), 16, 0, 0);
        }
        const short* Ab = As + (t & 1) * SZ;
        const short* Bb = Bs + (t & 1) * SZ;
        short8 af[2][2], bfr[2][2];   // [hk][mi/ni]
#pragma unroll
        for (int hk = 0; hk < 2; hk++) {
#pragma unroll
            for (int mi = 0; mi < 2; mi++) {
                const int row = wm * 32 + mi * 16 + l15;
                af[hk][mi] = *(const short8*)(Ab + row * 64 + (((hk * 4 + kg) ^ (row & 7)) * 8));
            }
#pragma unroll
            for (int ni = 0; ni < 2; ni++) {
                const int row = wn * 32 + ni * 16 + l15;
                bfr[hk][ni] = *(const short8*)(Bb + row * 64 + (((hk * 4 + kg) ^ (row & 7)) * 8));
            }
        }
#pragma unroll
        for (int hk = 0; hk < 2; hk++)
#pragma unroll
            for (int mi = 0; mi < 2; mi++)
#pragma unroll
                for (int ni = 0; ni < 2; ni++)
                    acc[mi][ni] = __builtin_amdgcn_mfma_f32_16x16x32_bf16(af[hk][mi], bfr[hk][ni], acc[mi][ni], 0, 0, 0);
    }
}
// C/D frag [m89]: col = n0 + wn*32 + ni*16 + (lane&15);
//                 row = m0 + wm*32 + mi*16 + (lane>>4)*4 + j

// ================= prep (R12, verified) =================
__global__ __launch_bounds__(256) void prep_k(
    const float* __restrict__ lin1_w, const float* __restrict__ gate_w,
    const float* __restrict__ lin2_w, const float* __restrict__ in_proj_w,
    const float* __restrict__ out_proj_w, const float* __restrict__ proj_w,
    const float* __restrict__ x_proj_w, const float* __restrict__ dt_proj_w,
    const float* __restrict__ inputs, const float* __restrict__ blk_norm_w,
    const float* __restrict__ post_norm_w, const float* __restrict__ sp_norm_w,
    short* __restrict__ wlin1gb, short* __restrict__ wlin2b, short* __restrict__ winpb,
    short* __restrict__ woutpb, short* __restrict__ wprojb, short* __restrict__ wxpdb,
    short* __restrict__ inputsb, float* __restrict__ preds, float* __restrict__ ss)
{
    const int blk = blockIdx.x, tid = threadIdx.x;
    if (blk < 512) {
        const int wave = tid >> 6, lane = tid & 63;
        const int nrow = blk * 8 + wave * 2;
        const int l = nrow >> 10, n = nrow & 1023;
        const float* dtw0 = dt_proj_w + (size_t)l * 32768 + n * 32;
        const float* dtw1 = dtw0 + 32;
        const float* xpw = x_proj_w + (size_t)l * 65536;
        float4 a0[4] = {}, a1[4] = {};
        for (int r = 0; r < 32; r++) {
            const float s0 = dtw0[r], s1 = dtw1[r];
#pragma unroll
            for (int rep = 0; rep < 4; rep++) {
                const float4 xv = *(const float4*)(xpw + r * 1024 + rep * 256 + lane * 4);
                a0[rep].x = fmaf(s0, xv.x, a0[rep].x); a0[rep].y = fmaf(s0, xv.y, a0[rep].y);
                a0[rep].z = fmaf(s0, xv.z, a0[rep].z); a0[rep].w = fmaf(s0, xv.w, a0[rep].w);
                a1[rep].x = fmaf(s1, xv.x, a1[rep].x); a1[rep].y = fmaf(s1, xv.y, a1[rep].y);
                a1[rep].z = fmaf(s1, xv.z, a1[rep].z); a1[rep].w = fmaf(s1, xv.w, a1[rep].w);
            }
        }
        short* dst0 = wxpdb + (size_t)l * WXPD_STRIDE + (size_t)(32 + n) * 1024;
        short* dst1 = dst0 + 1024;
#pragma unroll
        for (int rep = 0; rep < 4; rep++) {
            union { short sh[4]; uint2 u; } p0, p1;
            p0.sh[0] = f2b(a0[rep].x); p0.sh[1] = f2b(a0[rep].y);
            p0.sh[2] = f2b(a0[rep].z); p0.sh[3] = f2b(a0[rep].w);
            p1.sh[0] = f2b(a1[rep].x); p1.sh[1] = f2b(a1[rep].y);
            p1.sh[2] = f2b(a1[rep].z); p1.sh[3] = f2b(a1[rep].w);
            *(uint2*)(dst0 + rep * 256 + lane * 4) = p0.u;
            *(uint2*)(dst1 + rep * 256 + lane * 4) = p1.u;
        }
    } else if (blk < 544) {
#pragma unroll
        for (int rep = 0; rep < 4; rep++) {
            const int idx = (blk - 512) * 4096 + rep * 1024 + tid * 4;   // < 131072
            const int l = idx >> 15, off = idx & 32767;
            const float4 v = *(const float4*)(x_proj_w + (size_t)l * 65536 + 32768 + off);
            union { short sh[4]; uint2 u; } pk;
            pk.sh[0] = f2b(v.x); pk.sh[1] = f2b(v.y); pk.sh[2] = f2b(v.z); pk.sh[3] = f2b(v.w);
            *(uint2*)(wxpdb + (size_t)l * WXPD_STRIDE + off) = pk.u;
        }
    } else if (blk < 1504) {
        constexpr int pre[8] = {0, 128, 256, 512, 4608, 6656, 7680, 7936};
        for (int vb = blk - 544; vb < 7936; vb += 960) {
            int s = 0;
#pragma unroll
            for (int i = 1; i < 7; i++) s += (vb >= pre[i]);
            const int e = (vb - pre[s]) * 1024 + tid * 4;
            const float* src; short* dst;
            bool hasG = false; const float* gp = nullptr;
            bool hasSp = false;
            if      (s == 0) { src = lin1_w + e;     dst = wlin1gb + e; }
            else if (s == 1) { src = gate_w + e;     dst = wlin1gb + 131072 + e; }
            else if (s == 2) { src = lin2_w + e;     dst = wlin2b + e; }
            else if (s == 3) { src = in_proj_w + e;  dst = winpb + e;
                               hasG = true; gp = blk_norm_w + (e >> 20) * 512 + (e & 511);
                               hasSp = ((e >> 20) == 0); }
            else if (s == 4) { src = out_proj_w + e; dst = woutpb + e; }
            else if (s == 5) { src = proj_w + e;     dst = wprojb + e;
                               hasG = true; gp = post_norm_w + (e & 511); }
            else             { src = inputs + e;     dst = inputsb + e; }
            float4 v = *(const float4*)src;
            if (hasG) {
                const float4 gv = *(const float4*)gp;
                v.x *= gv.x; v.y *= gv.y; v.z *= gv.z; v.w *= gv.w;
            }
            if (hasSp) {
                const float4 sv = *(const float4*)(sp_norm_w + (e & 511));
                v.x *= sv.x; v.y *= sv.y; v.z *= sv.z; v.w *= sv.w;
            }
            union { short sh[4]; uint2 u; } pk;
            pk.sh[0] = f2b(v.x); pk.sh[1] = f2b(v.y); pk.sh[2] = f2b(v.z); pk.sh[3] = f2b(v.w);
            *(uint2*)dst = pk.u;
        }
    } else {
        const int i = (blk - 1504) * 256 + tid;   // < 10240
        if (i < 4096) preds[i] = 0.f;
        else ss[i - 4096] = 0.f;                   // zero ss slots 0..5
    }
}

// ================= spatial: lin1|gate merged (N=1024) =================
__global__ __launch_bounds__(256) void lin1gate_k(
    const short* __restrict__ A, const short* __restrict__ W,
    const float* __restrict__ b1, const float* __restrict__ b2,
    short* __restrict__ h1b, float* __restrict__ g)
{
    __shared__ short As[2 * 64 * 64];
    __shared__ short Bs[2 * 64 * 64];
    f32x4 acc[2][2] = {};
    const int m0 = blockIdx.y * 64, n0 = blockIdx.x * 64;
    gemm_core64(acc, A, 256, W, 256, 256, As, Bs, m0, n0);
    const int lane = threadIdx.x & 63, wave = threadIdx.x >> 6;
    const int wm = wave >> 1, wn = wave & 1, l15 = lane & 15, kg = lane >> 4;
#pragma unroll
    for (int ni = 0; ni < 2; ni++) {
        const int col = n0 + wn * 32 + ni * 16 + l15;
        const bool isG = col >= 512;
        const float b = isG ? b2[col - 512] : b1[col];
#pragma unroll
        for (int mi = 0; mi < 2; mi++)
#pragma unroll
            for (int j = 0; j < 4; j++) {
                const int row = m0 + wm * 32 + mi * 16 + kg * 4 + j;
                const float v = acc[mi][ni][j] + b;
                if (isG) g[(size_t)row * 512 + (col - 512)] = sigm(v);
                else     h1b[(size_t)row * 512 + col] = f2b(0.5f * v * (1.f + erff(v * 0.70710678f)));
            }
    }
}

// ================= lin2 (R12, + BK=64 core) =================
__global__ __launch_bounds__(256) void lin2_k(
    const short* __restrict__ A, const short* __restrict__ W,
    const float* __restrict__ bias, const float* __restrict__ g,
    const float* __restrict__ gsp, float* __restrict__ x, short* __restrict__ xb,
    float* __restrict__ ssS1, float* __restrict__ ssS2)
{
    __shared__ short As[2 * 64 * 64];
    __shared__ short Bs[2 * 64 * 64];
    f32x4 acc[2][2] = {};
    const int m0 = blockIdx.y * 64, n0 = blockIdx.x * 64;
    gemm_core64(acc, A, 512, W, 512, 512, As, Bs, m0, n0);
    const int lane = threadIdx.x & 63, wave = threadIdx.x >> 6;
    const int wm = wave >> 1, wn = wave & 1, l15 = lane & 15, kg = lane >> 4;
    float vs1[2][4] = {}, vs2[2][4] = {};
#pragma unroll
    for (int ni = 0; ni < 2; ni++) {
        const int col = n0 + wn * 32 + ni * 16 + l15;
        const float b = bias[col];
        const float gc = gsp[col];
#pragma unroll
        for (int mi = 0; mi < 2; mi++)
#pragma unroll
            for (int j = 0; j < 4; j++) {
                const int row = m0 + wm * 32 + mi * 16 + kg * 4 + j;
                const float v = (acc[mi][ni][j] + b) * g[(size_t)row * 512 + col];
                x[(size_t)row * 512 + col] = v;
                xb[(size_t)row * 512 + col] = f2b(v);
                vs1[mi][j] = fmaf(v, v, vs1[mi][j]);
                const float w = v * gc;
                vs2[mi][j] = fmaf(w, w, vs2[mi][j]);
            }
    }
#pragma unroll
    for (int mi = 0; mi < 2; mi++)
#pragma unroll
        for (int j = 0; j < 4; j++) {
            float t1 = vs1[mi][j], t2 = vs2[mi][j];
            t1 += __shfl_xor(t1, 1, 64); t2 += __shfl_xor(t2, 1, 64);
            t1 += __shfl_xor(t1, 2, 64); t2 += __shfl_xor(t2, 2, 64);
            t1 += __shfl_xor(t1, 4, 64); t2 += __shfl_xor(t2, 4, 64);
            t1 += __shfl_xor(t1, 8, 64); t2 += __shfl_xor(t2, 8, 64);
            if (l15 == 0) {
                const int row = m0 + wm * 32 + mi * 16 + kg * 4 + j;
                atomicAdd(ssS1 + row, t1);
                atomicAdd(ssS2 + row, t2);
            }
        }
}

// ================= in_proj + fused depthwise conv + silu =================
union ConvU {
    struct { short As[2 * 64 * 64]; short Bs[2 * 64 * 64]; } gm;   // 32 KB (GEMM)
    float cbuf[67][68];                                             // 18.2 KB (conv)
};

template <int COMB>
__global__ __launch_bounds__(256) void inprojconv_k(
    const short* __restrict__ A, const short* __restrict__ W,
    const float* __restrict__ ssA, const float* __restrict__ ssB,
    const float* __restrict__ cw, const float* __restrict__ cb,
    short* __restrict__ xcb, short* __restrict__ srb)
{
    __shared__ ConvU u;
    f32x4 acc[2][2] = {};
    const int m0 = blockIdx.y * 64, n0 = blockIdx.x * 64;
    gemm_core64(acc, A, 512, W, 512, 512, u.gm.As, u.gm.Bs, m0, n0);
    const int tid = threadIdx.x;
    const int lane = tid & 63, wave = tid >> 6;
    const int wm = wave >> 1, wn = wave & 1, l15 = lane & 15, kg = lane >> 4;

#pragma unroll
    for (int mi = 0; mi < 2; mi++)
#pragma unroll
        for (int j = 0; j < 4; j++) {
            const int row = m0 + wm * 32 + mi * 16 + kg * 4 + j;
            float r;
            if constexpr (COMB) {
                const float rx = rsqrtf(ssA[row] * (1.f / 512.f) + 1e-5f);
                r = rx * rsqrtf(rx * rx * ssB[row] * (1.f / 512.f) + 1e-5f);
            } else {
                r = rsqrtf(ssA[row] * (1.f / 512.f) + 1e-5f);
            }
#pragma unroll
            for (int ni = 0; ni < 2; ni++) acc[mi][ni][j] *= r;
        }

    if (n0 < 1024) {
        const int ccol = tid & 63;
        const int rg = tid >> 6;           // 0..3
        const int d = n0 + ccol;
        const float4 w4 = *(const float4*)(cw + d * 4);
        const float bia = cb[d];

        __syncthreads();   // gemm LDS reads done
#pragma unroll
        for (int mi = 0; mi < 2; mi++)
#pragma unroll
            for (int ni = 0; ni < 2; ni++)
#pragma unroll
                for (int j = 0; j < 4; j++)
                    u.cbuf[3 + wm * 32 + mi * 16 + kg * 4 + j][wn * 32 + ni * 16 + l15] = acc[mi][ni][j];
        for (int i = tid; i < 3 * 68; i += 256) u.cbuf[i / 68][i % 68] = 0.f;
        __syncthreads();
#pragma unroll 4
        for (int k = 0; k < 16; k++) {
            const int row = rg + 4 * k;    // 0..63
            float v = bia + w4.x * u.cbuf[row][ccol] + w4.y * u.cbuf[row + 1][ccol]
                          + w4.z * u.cbuf[row + 2][ccol] + w4.w * u.cbuf[row + 3][ccol];
            v = v * sigm(v);
            xcb[(size_t)(m0 + row) * 1024 + d] = f2b(v);
        }
    } else {
#pragma unroll
        for (int ni = 0; ni < 2; ni++) {
            const int scol = n0 - 1024 + wn * 32 + ni * 16 + l15;
#pragma unroll
            for (int mi = 0; mi < 2; mi++)
#pragma unroll
                for (int j = 0; j < 4; j++) {
                    const int row = m0 + wm * 32 + mi * 16 + kg * 4 + j;
                    const float v = acc[mi][ni][j];
                    srb[(size_t)row * 1024 + scol] = f2b(v * sigm(v));
                }
        }
    }
}

// ================= fused x_proj/dt + scan (LDS-staged scan operands) =================
union XsU {
    struct { short As[2 * 64 * 32]; short Wd[2 * 64 * 32]; short BC[2 * 32 * 32]; } gm; // 20 KB
    struct { float dlt[64][68]; float BC[64][32]; short ub[64][64]; float yt[64][68]; } sc; // 51 KB
};

__global__ __launch_bounds__(256) void xpdscan_k(
    const short* __restrict__ A /*xcb*/, const short* __restrict__ W /*wxpdb layer*/,
    const float* __restrict__ dtb, const float* __restrict__ Alog,
    const float* __restrict__ Dp, const short* __restrict__ srb, short* __restrict__ yb)
{
    __shared__ XsU u;
    const int dg = blockIdx.x, b = blockIdx.y;
    const int m0 = b * 64;
    const int tid = threadIdx.x;
    const int lane = tid & 63, wave = tid >> 6;
    const int wm = wave >> 1, wn = wave & 1, l15 = lane & 15, kg = lane >> 4;

    constexpr int SZA = 64 * 32, SZBC = 32 * 32;
    const int p = wave * 64 + lane;   // chunk id
    const short* srcA  = A + (size_t)(m0 + (p >> 2)) * 1024 + (p & 3) * 8;
    const short* srcWd = W + (size_t)(32 + dg * 64 + (p >> 2)) * 1024 + (p & 3) * 8;
    const short* srcBC = W + (size_t)(p >> 2) * 1024 + (p & 3) * 8;   // valid p<128 (waves 0,1)
    const int ob = (wave * 64) * 8;

    f32x4 accd[2][2] = {};
    f32x4 accx[2] = {};

    __builtin_amdgcn_global_load_lds((const glb_u32_t*)srcA,  (lds_u32_t*)(u.gm.As + ob), 16, 0, 0);
    __builtin_amdgcn_global_load_lds((const glb_u32_t*)srcWd, (lds_u32_t*)(u.gm.Wd + ob), 16, 0, 0);
    if (wave < 2)
        __builtin_amdgcn_global_load_lds((const glb_u32_t*)srcBC, (lds_u32_t*)(u.gm.BC + ob), 16, 0, 0);

    for (int t = 0; t < 32; t++) {
        __syncthreads();
        if (t + 1 < 32) {
            const int k0 = (t + 1) * 32;
            const int sA = ((t + 1) & 1) * SZA, sBC = ((t + 1) & 1) * SZBC;
            __builtin_amdgcn_global_load_lds((const glb_u32_t*)(srcA + k0),  (lds_u32_t*)(u.gm.As + sA + ob), 16, 0, 0);
            __builtin_amdgcn_global_load_lds((const glb_u32_t*)(srcWd + k0), (lds_u32_t*)(u.gm.Wd + sA + ob), 16, 0, 0);
            if (wave < 2)
                __builtin_amdgcn_global_load_lds((const glb_u32_t*)(srcBC + k0), (lds_u32_t*)(u.gm.BC + sBC + ob), 16, 0, 0);
        }
        const short* Ab  = u.gm.As + (t & 1) * SZA;
        const short* Wdb = u.gm.Wd + (t & 1) * SZA;
        const short* BCb = u.gm.BC + (t & 1) * SZBC;
        short8 af[2], wf[2], bcf;
#pragma unroll
        for (int mi = 0; mi < 2; mi++)
            af[mi] = *(const short8*)(Ab + (wm * 32 + mi * 16 + l15) * 32 + kg * 8);
#pragma unroll
        for (int ni = 0; ni < 2; ni++)
            wf[ni] = *(const short8*)(Wdb + (wn * 32 + ni * 16 + l15) * 32 + kg * 8);
        bcf = *(const short8*)(BCb + (wn * 16 + l15) * 32 + kg * 8);
#pragma unroll
        for (int mi = 0; mi < 2; mi++) {
#pragma unroll
            for (int ni = 0; ni < 2; ni++)
                accd[mi][ni] = __builtin_amdgcn_mfma_f32_16x16x32_bf16(af[mi], wf[ni], accd[mi][ni], 0, 0, 0);
            accx[mi] = __builtin_amdgcn_mfma_f32_16x16x32_bf16(af[mi], bcf, accx[mi], 0, 0, 0);
        }
    }

    __syncthreads();   // gemm LDS reads done before repurposing union
#pragma unroll
    for (int ni = 0; ni < 2; ni++) {
        const int dl = wn * 32 + ni * 16 + l15;
        const float bb = dtb[dg * 64 + dl];
#pragma unroll
        for (int mi = 0; mi < 2; mi++)
#pragma unroll
            for (int j = 0; j < 4; j++)
                u.sc.dlt[wm * 32 + mi * 16 + kg * 4 + j][dl] = softp(accd[mi][ni][j] + bb);
    }
    {
        const int c = wn * 16 + l15;
#pragma unroll
        for (int mi = 0; mi < 2; mi++)
#pragma unroll
            for (int j = 0; j < 4; j++)
                u.sc.BC[wm * 32 + mi * 16 + kg * 4 + j][c] = accx[mi][j];
    }
    // stage u-tile (64 l x 64 d bf16) into LDS, coalesced
#pragma unroll
    for (int k = 0; k < 2; k++) {
        const int c = tid + k * 256;           // 0..511 chunks of 16B
        const int row = c >> 3, sl = c & 7;
        *(uint4*)&u.sc.ub[row][sl * 8] =
            *(const uint4*)(A + (size_t)(m0 + row) * 1024 + dg * 64 + sl * 8);
    }
    __syncthreads();

    // 4-lane-parallel scan, all operands in LDS; y accumulated into LDS fp32 tile
    {
        const int d_l = tid >> 2;          // 0..63
        const int ns = (tid & 3) << 2;     // 0,4,8,12
        const int d = dg * 64 + d_l;
        float a[4], s[4];
#pragma unroll
        for (int n = 0; n < 4; n++) {
            a[n] = -__expf(Alog[(size_t)d * 16 + ns + n]);
            s[n] = 0.f;
        }
        const float dv = Dp[d];
        for (int l = 0; l < SEQ; l++) {
            const float dlt = u.sc.dlt[l][d_l];
            const float uu = b2f(u.sc.ub[l][d_l]);
            const float dbu = dlt * uu;
            float part = 0.f;
#pragma unroll
            for (int n = 0; n < 4; n++) {
                s[n] = __expf(dlt * a[n]) * s[n] + dbu * u.sc.BC[l][ns + n];
                part = fmaf(s[n], u.sc.BC[l][16 + ns + n], part);
            }
            part += __shfl_xor(part, 1, 64);
            part += __shfl_xor(part, 2, 64);
            if ((tid & 3) == 0) u.sc.yt[l][d_l] = part + uu * dv;
        }
    }
    __syncthreads();
    // flush: y = yt * silu(res), coalesced
#pragma unroll
    for (int k = 0; k < 2; k++) {
        const int c = tid + k * 256;
        const int row = c >> 3, sl = c & 7;
        const short8 rv = *(const short8*)(srb + (size_t)(m0 + row) * 1024 + dg * 64 + sl * 8);
        short8 out;
#pragma unroll
        for (int j = 0; j < 8; j++)
            out[j] = f2b(u.sc.yt[row][sl * 8 + j] * b2f(rv[j]));
        *(short8*)(yb + (size_t)(m0 + row) * 1024 + dg * 64 + sl * 8) = out;
    }
}

// ================= out_proj: 32x64 tile (R10/R11, verified) =================
template <int FIRST>
__global__ __launch_bounds__(256) void outproj_k(
    const short* __restrict__ A, const short* __restrict__ W,
    float* __restrict__ h, short* __restrict__ hb, float* __restrict__ ss_out,
    const float* __restrict__ xsrc, const float* __restrict__ gsp,
    const float* __restrict__ ssS1)
{
    __shared__ short As[2 * 32 * 32];   // 4 KB dbuf
    __shared__ short Bs[2 * 64 * 32];   // 8 KB dbuf
    constexpr int SZA = 32 * 32, SZB = 64 * 32;
    const int m0 = blockIdx.y * 32, n0 = blockIdx.x * 64;
    const int tid = threadIdx.x, wave = tid >> 6, lane = tid & 63;
    const int l15 = lane & 15, kg = lane >> 4;

    const int p = wave * 64 + lane;   // 0..255
    const short* srcA = A + (size_t)(m0 + (p >> 2)) * 1024 + (p & 3) * 8;   // valid p<128
    const short* srcB = W + (size_t)(n0 + (p >> 2)) * 1024 + (p & 3) * 8;
    const int ob = (wave * 64) * 8;

    f32x4 acc[2] = {};
    if (wave < 2)
        __builtin_amdgcn_global_load_lds((const glb_u32_t*)srcA, (lds_u32_t*)(As + ob), 16, 0, 0);
    __builtin_amdgcn_global_load_lds((const glb_u32_t*)srcB, (lds_u32_t*)(Bs + ob), 16, 0, 0);

    for (int t = 0; t < 32; t++) {
        __syncthreads();
        if (t + 1 < 32) {
            const int k0 = (t + 1) * 32;
            const int sA = ((t + 1) & 1) * SZA, sB = ((t + 1) & 1) * SZB;
            if (wave < 2)
                __builtin_amdgcn_global_load_lds((const glb_u32_t*)(srcA + k0), (lds_u32_t*)(As + sA + ob), 16, 0, 0);
            __builtin_amdgcn_global_load_lds((const glb_u32_t*)(srcB + k0), (lds_u32_t*)(Bs + sB + ob), 16, 0, 0);
        }
        const short* Ab = As + (t & 1) * SZA;
        const short* Bb = Bs + (t & 1) * SZB;
        short8 af[2], bf;
#pragma unroll
        for (int mi = 0; mi < 2; mi++)
            af[mi] = *(const short8*)(Ab + (mi * 16 + l15) * 32 + kg * 8);
        bf = *(const short8*)(Bb + (wave * 16 + l15) * 32 + kg * 8);
#pragma unroll
        for (int mi = 0; mi < 2; mi++)
            acc[mi] = __builtin_amdgcn_mfma_f32_16x16x32_bf16(af[mi], bf, acc[mi], 0, 0, 0);
    }

    const int col = n0 + wave * 16 + l15;
    const float gc = FIRST ? gsp[col] : 0.f;
    float vsq[2][4] = {};
#pragma unroll
    for (int mi = 0; mi < 2; mi++)
#pragma unroll
        for (int j = 0; j < 4; j++) {
            const int row = m0 + mi * 16 + kg * 4 + j;
            float hold;
            if constexpr (FIRST) {
                const float rx = rsqrtf(ssS1[row] * (1.f / 512.f) + 1e-5f);
                hold = xsrc[(size_t)row * 512 + col] * rx * gc;
            } else {
                hold = h[(size_t)row * 512 + col];
            }
            const float v = acc[mi][j] + hold;
            h[(size_t)row * 512 + col] = v;
            hb[(size_t)row * 512 + col] = f2b(v);
            vsq[mi][j] = v * v;
        }
#pragma unroll
    for (int mi = 0; mi < 2; mi++)
#pragma unroll
        for (int j = 0; j < 4; j++) {
            float t = vsq[mi][j];
            t += __shfl_xor(t, 1, 64);
            t += __shfl_xor(t, 2, 64);
            t += __shfl_xor(t, 4, 64);
            t += __shfl_xor(t, 8, 64);
            if (l15 == 0) {
                const int row = m0 + mi * 16 + kg * 4 + j;
                atomicAdd(ss_out + row, t);
            }
        }
}

// ================= final proj (BK=64 core) =================
__global__ __launch_bounds__(256) void projf_k(
    const short* __restrict__ A, const short* __restrict__ W,
    const float* __restrict__ ss_in, float* __restrict__ xr)
{
    __shared__ short As[2 * 64 * 64];
    __shared__ short Bs[2 * 64 * 64];
    f32x4 acc[2][2] = {};
    const int m0 = blockIdx.y * 64, n0 = blockIdx.x * 64;
    gemm_core64(acc, A, 512, W, 512, 512, As, Bs, m0, n0);
    const int lane = threadIdx.x & 63, wave = threadIdx.x >> 6;
    const int wm = wave >> 1, wn = wave & 1, l15 = lane & 15, kg = lane >> 4;
#pragma unroll
    for (int mi = 0; mi < 2; mi++)
#pragma unroll
        for (int j = 0; j < 4; j++) {
            const int row = m0 + wm * 32 + mi * 16 + kg * 4 + j;
            const float r = rsqrtf(ss_in[row] * (1.f / 512.f) + 1e-5f);
#pragma unroll
            for (int ni = 0; ni < 2; ni++) {
                const int col = n0 + wn * 32 + ni * 16 + l15;
                xr[(size_t)row * 2048 + col] = acc[mi][ni][j] * r;
            }
        }
}

// ================= coeffs + preds =================
__global__ __launch_bounds__(256) void coeffs_k(
    const float* __restrict__ outp, const float* __restrict__ inp,
    float* __restrict__ coeffs, float* __restrict__ preds)
{
    const int m = blockIdx.x;
    const int b = m >> 6;
    const int tid = threadIdx.x, wave = tid >> 6, lane = tid & 63;
    __shared__ float4 Us[256], Vs[256];
    __shared__ float ins[256];
    __shared__ float4 tpart[4];
    Us[tid] = *(const float4*)(outp + (size_t)m * 2048 + tid * 4);
    Vs[tid] = *(const float4*)(outp + (size_t)m * 2048 + 1024 + tid * 4);
    ins[tid] = inp[(size_t)m * 256 + tid];
    __syncthreads();
    const float4 vq0 = Vs[lane * 4 + 0], vq1 = Vs[lane * 4 + 1];
    const float4 vq2 = Vs[lane * 4 + 2], vq3 = Vs[lane * 4 + 3];
    float* cbase = coeffs + (size_t)m * 65536 + lane * 4;
#pragma unroll 4
    for (int i = 0; i < 64; i++) {
        const int pp = (wave << 6) + i;
        const float4 up = Us[pp];
        float4 c;
        c.x = up.x * vq0.x + up.y * vq0.y + up.z * vq0.z + up.w * vq0.w;
        c.y = up.x * vq1.x + up.y * vq1.y + up.z * vq1.z + up.w * vq1.w;
        c.z = up.x * vq2.x + up.y * vq2.y + up.z * vq2.z + up.w * vq2.w;
        c.w = up.x * vq3.x + up.y * vq3.y + up.z * vq3.z + up.w * vq3.w;
        *(float4*)(cbase + (size_t)pp * 256) = c;
    }
    const float iv = ins[tid];
    const float4 vm = Vs[tid];
    float4 t = make_float4(vm.x * iv, vm.y * iv, vm.z * iv, vm.w * iv);
#pragma unroll
    for (int off = 32; off > 0; off >>= 1) {
        t.x += __shfl_xor(t.x, off, 64);
        t.y += __shfl_xor(t.y, off, 64);
        t.z += __shfl_xor(t.z, off, 64);
        t.w += __shfl_xor(t.w, off, 64);
    }
    if (lane == 0) tpart[wave] = t;
    __syncthreads();
    const float4 t0 = tpart[0], t1 = tpart[1], t2 = tpart[2], t3 = tpart[3];
    const float4 tt = make_float4(t0.x + t1.x + t2.x + t3.x, t0.y + t1.y + t2.y + t3.y,
                                  t0.z + t1.z + t2.z + t3.z, t0.w + t1.w + t2.w + t3.w);
    const float4 up = Us[tid];
    const float pv = up.x * tt.x + up.y * tt.y + up.z * tt.z + up.w * tt.w;
    atomicAdd(preds + (size_t)b * 256 + tid, pv);
}

} // namespace

extern "C" void kernel_launch(void* const* d_in, const int* in_sizes, int n_in,
                              void* d_out, int out_size, void* d_ws, size_t ws_size,
                              hipStream_t stream)
{
    const float* inputs     = (const float*)d_in[0];
    const float* lin1_w     = (const float*)d_in[1];
    const float* lin1_b     = (const float*)d_in[2];
    const float* lin2_w     = (const float*)d_in[3];
    const float* lin2_b     = (const float*)d_in[4];
    const float* gate_w     = (const float*)d_in[5];
    const float* gate_b     = (const float*)d_in[6];
    const float* sp_norm_w  = (const float*)d_in[7];
    const float* in_proj_w  = (const float*)d_in[8];
    const float* conv_w     = (const float*)d_in[9];
    const float* conv_b     = (const float*)d_in[10];
    const float* x_proj_w   = (const float*)d_in[11];
    const float* dt_proj_w  = (const float*)d_in[12];
    const float* dt_proj_b  = (const float*)d_in[13];
    const float* A_log      = (const float*)d_in[14];
    const float* Dvec       = (const float*)d_in[15];
    const float* out_proj_w = (const float*)d_in[16];
    const float* blk_norm_w = (const float*)d_in[17];
    const float* post_norm_w= (const float*)d_in[18];
    const float* proj_w     = (const float*)d_in[19];

    float* ws = (float*)d_ws;
    // fp32 region
    float* h     = ws;                 // 1024 x 512
    float* xr    = ws + 524288;        // 1024 x 2048 (final proj out)
    float* x     = ws + 2621440;       // 1024 x 512 (lin2 out)
    float* g     = ws + 3145728;       // 1024 x 512
    float* ss    = ws + 3670016;       // slots: 0=S1, 1..4=sum h^2, 5=S2
    // bf16 region
    short* bfb     = (short*)(ws + 3676160);
    short* inputsb = bfb;               // 1024 x 256
    short* h1b     = bfb + 262144;      // 1024 x 512
    short* hb      = bfb + 786432;      // 1024 x 512
    short* xcb     = bfb + 1310720;     // 1024 x 1024
    short* yb      = bfb + 2359296;     // 1024 x 1024
    short* xb      = yb;                // 1024 x 512 ALIAS (dead until xpdscan l0)
    short* srb     = bfb + 3407872;     // 1024 x 1024 silu(res)
    short* wlin1gb = bfb + 4456448;     // 1024 x 256
    short* wlin2b  = bfb + 4718592;     // 512 x 512
    short* winpb   = bfb + 4980736;     // 4 x 2048 x 512 (gamma-folded; l0 also gamma_sp)
    short* woutpb  = bfb + 9175040;     // 4 x 512 x 1024
    short* wprojb  = bfb + 11272192;    // 2048 x 512 (gamma-folded)
    short* wxpdb   = bfb + 12320768;    // 4 x 1056 x 1024 ([BC; W_delta])
    float* preds  = (float*)d_out;
    float* coeffs = (float*)d_out + 4096;

    const dim3 blk(256);

    prep_k<<<dim3(1544), blk, 0, stream>>>(
        lin1_w, gate_w, lin2_w, in_proj_w, out_proj_w, proj_w, x_proj_w, dt_proj_w,
        inputs, blk_norm_w, post_norm_w, sp_norm_w,
        wlin1gb, wlin2b, winpb, woutpb, wprojb, wxpdb, inputsb, preds, ss);

    lin1gate_k<<<dim3(16, 16), blk, 0, stream>>>(inputsb, wlin1gb, lin1_b, gate_b, h1b, g);
    lin2_k<<<dim3(8, 16), blk, 0, stream>>>(h1b, wlin2b, lin2_b, g, sp_norm_w,
                                            x, xb, ss, ss + 5120);

    for (int l = 0; l < 4; l++) {
        if (l == 0)
            inprojconv_k<1><<<dim3(32, 16), blk, 0, stream>>>(
                xb, winpb, ss, ss + 5120,
                conv_w, conv_b, xcb, srb);
        else
            inprojconv_k<0><<<dim3(32, 16), blk, 0, stream>>>(
                hb, winpb + (size_t)l * 1048576, ss + l * 1024, nullptr,
                conv_w + (size_t)l * 4096, conv_b + l * 1024, xcb, srb);
        xpdscan_k<<<dim3(16, 16), blk, 0, stream>>>(
            xcb, wxpdb + (size_t)l * WXPD_STRIDE, dt_proj_b + l * 1024,
            A_log + (size_t)l * 16384, Dvec + l * 1024, srb, yb);
        if (l == 0)
            outproj_k<1><<<dim3(8, 32), blk, 0, stream>>>(yb, woutpb,
                h, hb, ss + 1024, x, sp_norm_w, ss);
        else
            outproj_k<0><<<dim3(8, 32), blk, 0, stream>>>(yb, woutpb + (size_t)l * 524288,
                h, hb, ss + (l + 1) * 1024, nullptr, nullptr, nullptr);
    }

    projf_k<<<dim3(32, 16), blk, 0, stream>>>(hb, wprojb, ss + 4096, xr);
    coeffs_k<<<dim3(1024), blk, 0, stream>>>(xr, inputs, coeffs, preds);
}

// Round 14
// 359.021 us; speedup vs baseline: 1.5196x; 1.0451x over previous
//
#include <hip/hip_runtime.h>
#include <hip/hip_bf16.h>
#include <math.h>

namespace {

constexpr int SEQ    = 64;
constexpr int DINNER = 1024;
constexpr int WXPD_STRIDE = 1056 * 1024;   // rows 0..31 = BC weights, 32..1055 = W_delta

typedef __attribute__((ext_vector_type(8))) short short8;
typedef __attribute__((ext_vector_type(4))) float f32x4;
typedef __attribute__((address_space(3))) unsigned int lds_u32_t;
typedef __attribute__((address_space(1))) unsigned int glb_u32_t;

__device__ __forceinline__ float sigm(float x) { return 1.f / (1.f + __expf(-x)); }
__device__ __forceinline__ short f2b(float v) {
    __hip_bfloat16 h = __float2bfloat16(v);
    return *(short*)&h;
}
__device__ __forceinline__ float b2f(short s) {
    union { unsigned u; float f; } c; c.u = ((unsigned)(unsigned short)s) << 16; return c.f;
}
__device__ __forceinline__ float softp(float v) {
    return fmaxf(v, 0.f) + log1pf(__expf(-fabsf(v)));
}

// ====== bf16 MFMA GEMM core, 64x64 tile, BK=64, 2-phase pipelined (R13, verified) ======
// T2 XOR-swizzle: linear LDS dest + inverse-swizzled global SOURCE (rule #21)
// + swizzled ds_read: slot' = slot ^ (row&7).
__device__ __forceinline__ void gemm_core64(
    f32x4 (&acc)[2][2],
    const short* __restrict__ A, int lda,
    const short* __restrict__ W, int ldw,
    int Kd, short* As, short* Bs, int m0, int n0)
{
    constexpr int SZ = 64 * 64;          // shorts per buffer
    const int tid = threadIdx.x, wave = tid >> 6, lane = tid & 63;
    const int wm = wave >> 1, wn = wave & 1;
    const int l15 = lane & 15, kg = lane >> 4;

    const int r0 = tid >> 3,        s0 = tid & 7;
    const int r1 = 32 + (tid >> 3), s1 = s0;
    const short* srcA0 = A + (size_t)(m0 + r0) * lda + ((s0 ^ (r0 & 7)) * 8);
    const short* srcA1 = A + (size_t)(m0 + r1) * lda + ((s1 ^ (r1 & 7)) * 8);
    const short* srcB0 = W + (size_t)(n0 + r0) * ldw + ((s0 ^ (r0 & 7)) * 8);
    const short* srcB1 = W + (size_t)(n0 + r1) * ldw + ((s1 ^ (r1 & 7)) * 8);
    const int ob0 = wave * 512;
    const int ob1 = 2048 + wave * 512;

    const int nt = Kd >> 6;
    __builtin_amdgcn_global_load_lds((const glb_u32_t*)srcA0, (lds_u32_t*)(As + ob0), 16, 0, 0);
    __builtin_amdgcn_global_load_lds((const glb_u32_t*)srcA1, (lds_u32_t*)(As + ob1), 16, 0, 0);
    __builtin_amdgcn_global_load_lds((const glb_u32_t*)srcB0, (lds_u32_t*)(Bs + ob0), 16, 0, 0);
    __builtin_amdgcn_global_load_lds((const glb_u32_t*)srcB1, (lds_u32_t*)(Bs + ob1), 16, 0, 0);

    for (int t = 0; t < nt; t++) {
        __syncthreads();
        if (t + 1 < nt) {
            const int k0 = (t + 1) * 64;
            const int s = ((t + 1) & 1) * SZ;
            __builtin_amdgcn_global_load_lds((const glb_u32_t*)(srcA0 + k0), (lds_u32_t*)(As + s + ob0), 16, 0, 0);
            __builtin_amdgcn_global_load_lds((const glb_u32_t*)(srcA1 + k0), (lds_u32_t*)(As + s + ob1), 16, 0, 0);
            __builtin_amdgcn_global_load_lds((const glb_u32_t*)(srcB0 + k0), (lds_u32_t*)(Bs + s + ob0), 16, 0, 0);
            __builtin_amdgcn_global_load_lds((const glb_u32_t*)(srcB1 + k0), (lds_u32_t*)(Bs + s + ob1), 16, 0, 0);
        }
        const short* Ab = As + (t & 1) * SZ;
        const short* Bb = Bs + (t & 1) * SZ;
        short8 af[2][2], bfr[2][2];
#pragma unroll
        for (int hk = 0; hk < 2; hk++) {
#pragma unroll
            for (int mi = 0; mi < 2; mi++) {
                const int row = wm * 32 + mi * 16 + l15;
                af[hk][mi] = *(const short8*)(Ab + row * 64 + (((hk * 4 + kg) ^ (row & 7)) * 8));
            }
#pragma unroll
            for (int ni = 0; ni < 2; ni++) {
                const int row = wn * 32 + ni * 16 + l15;
                bfr[hk][ni] = *(const short8*)(Bb + row * 64 + (((hk * 4 + kg) ^ (row & 7)) * 8));
            }
        }
#pragma unroll
        for (int hk = 0; hk < 2; hk++)
#pragma unroll
            for (int mi = 0; mi < 2; mi++)
#pragma unroll
                for (int ni = 0; ni < 2; ni++)
                    acc[mi][ni] = __builtin_amdgcn_mfma_f32_16x16x32_bf16(af[hk][mi], bfr[hk][ni], acc[mi][ni], 0, 0, 0);
    }
}
// C/D frag [m89]: col = n0 + wn*32 + ni*16 + (lane&15);
//                 row = m0 + wm*32 + mi*16 + (lane>>4)*4 + j

// ================= prep_early: small conversions + zeroing (fast head) =================
__global__ __launch_bounds__(256) void prep_early_k(
    const float* __restrict__ lin1_w, const float* __restrict__ gate_w,
    const float* __restrict__ lin2_w, const float* __restrict__ inputs,
    short* __restrict__ wlin1gb, short* __restrict__ wlin2b, short* __restrict__ inputsb,
    float* __restrict__ preds, float* __restrict__ ss)
{
    const int blk = blockIdx.x, tid = threadIdx.x;
    if (blk < 768) {
        const float* src; short* dst;
        int e;
        if (blk < 128)      { e = blk * 1024 + tid * 4;          src = lin1_w + e;  dst = wlin1gb + e; }
        else if (blk < 256) { e = (blk - 128) * 1024 + tid * 4;  src = gate_w + e;  dst = wlin1gb + 131072 + e; }
        else if (blk < 512) { e = (blk - 256) * 1024 + tid * 4;  src = lin2_w + e;  dst = wlin2b + e; }
        else                { e = (blk - 512) * 1024 + tid * 4;  src = inputs + e;  dst = inputsb + e; }
        const float4 v = *(const float4*)src;
        union { short sh[4]; uint2 u; } pk;
        pk.sh[0] = f2b(v.x); pk.sh[1] = f2b(v.y); pk.sh[2] = f2b(v.z); pk.sh[3] = f2b(v.w);
        *(uint2*)dst = pk.u;
    } else {
        const int i = (blk - 768) * 256 + tid;   // < 10240
        if (i < 4096) preds[i] = 0.f;
        else if (i < 10240) ss[i - 4096] = 0.f;   // ss slots 0..5
    }
}

// ================= lin1gate + aux prep (W_delta, BC, big-weight conversions) ==========
// blk<256: spatial GEMM. blk>=256: aux work whose outputs are first consumed
// 2+ kernels later (kernel ordering guarantees completion). R10 lesson: aux
// branches stay register-light (no LDS staging, wave-per-row W_delta).
__global__ __launch_bounds__(256) void lin1gate_k(
    const short* __restrict__ A, const short* __restrict__ W,
    const float* __restrict__ b1, const float* __restrict__ b2,
    short* __restrict__ h1b, float* __restrict__ g,
    const float* __restrict__ x_proj_w, const float* __restrict__ dt_proj_w,
    const float* __restrict__ in_proj_w, const float* __restrict__ out_proj_w,
    const float* __restrict__ proj_w, const float* __restrict__ blk_norm_w,
    const float* __restrict__ post_norm_w, const float* __restrict__ sp_norm_w,
    short* __restrict__ winpb, short* __restrict__ woutpb,
    short* __restrict__ wprojb, short* __restrict__ wxpdb)
{
    __shared__ short As[2 * 64 * 64];
    __shared__ short Bs[2 * 64 * 64];
    const int blk = blockIdx.x, tid = threadIdx.x;

    if (blk < 256) {
        f32x4 acc[2][2] = {};
        const int m0 = (blk >> 4) * 64, n0 = (blk & 15) * 64;
        gemm_core64(acc, A, 256, W, 256, 256, As, Bs, m0, n0);
        const int lane = tid & 63, wave = tid >> 6;
        const int wm = wave >> 1, wn = wave & 1, l15 = lane & 15, kg = lane >> 4;
#pragma unroll
        for (int ni = 0; ni < 2; ni++) {
            const int col = n0 + wn * 32 + ni * 16 + l15;
            const bool isG = col >= 512;
            const float b = isG ? b2[col - 512] : b1[col];
#pragma unroll
            for (int mi = 0; mi < 2; mi++)
#pragma unroll
                for (int j = 0; j < 4; j++) {
                    const int row = m0 + wm * 32 + mi * 16 + kg * 4 + j;
                    const float v = acc[mi][ni][j] + b;
                    if (isG) g[(size_t)row * 512 + (col - 512)] = sigm(v);
                    else     h1b[(size_t)row * 512 + col] = f2b(0.5f * v * (1.f + erff(v * 0.70710678f)));
                }
        }
    } else if (blk < 768) {
        // W_delta = dt_w @ xp_w[:32]; 2 n-rows per wave (R12, verified low-VGPR)
        const int wave = tid >> 6, lane = tid & 63;
        const int nrow = (blk - 256) * 8 + wave * 2;
        const int l = nrow >> 10, n = nrow & 1023;
        const float* dtw0 = dt_proj_w + (size_t)l * 32768 + n * 32;
        const float* dtw1 = dtw0 + 32;
        const float* xpw = x_proj_w + (size_t)l * 65536;
        float4 a0[4] = {}, a1[4] = {};
        for (int r = 0; r < 32; r++) {
            const float s0 = dtw0[r], s1 = dtw1[r];
#pragma unroll
            for (int rep = 0; rep < 4; rep++) {
                const float4 xv = *(const float4*)(xpw + r * 1024 + rep * 256 + lane * 4);
                a0[rep].x = fmaf(s0, xv.x, a0[rep].x); a0[rep].y = fmaf(s0, xv.y, a0[rep].y);
                a0[rep].z = fmaf(s0, xv.z, a0[rep].z); a0[rep].w = fmaf(s0, xv.w, a0[rep].w);
                a1[rep].x = fmaf(s1, xv.x, a1[rep].x); a1[rep].y = fmaf(s1, xv.y, a1[rep].y);
                a1[rep].z = fmaf(s1, xv.z, a1[rep].z); a1[rep].w = fmaf(s1, xv.w, a1[rep].w);
            }
        }
        short* dst0 = wxpdb + (size_t)l * WXPD_STRIDE + (size_t)(32 + n) * 1024;
        short* dst1 = dst0 + 1024;
#pragma unroll
        for (int rep = 0; rep < 4; rep++) {
            union { short sh[4]; uint2 u; } p0, p1;
            p0.sh[0] = f2b(a0[rep].x); p0.sh[1] = f2b(a0[rep].y);
            p0.sh[2] = f2b(a0[rep].z); p0.sh[3] = f2b(a0[rep].w);
            p1.sh[0] = f2b(a1[rep].x); p1.sh[1] = f2b(a1[rep].y);
            p1.sh[2] = f2b(a1[rep].z); p1.sh[3] = f2b(a1[rep].w);
            *(uint2*)(dst0 + rep * 256 + lane * 4) = p0.u;
            *(uint2*)(dst1 + rep * 256 + lane * 4) = p1.u;
        }
    } else if (blk < 800) {
        // BC weights: xp_w rows 32..63 -> wxpdb rows 0..31
#pragma unroll
        for (int rep = 0; rep < 4; rep++) {
            const int idx = (blk - 768) * 4096 + rep * 1024 + tid * 4;   // < 131072
            const int l = idx >> 15, off = idx & 32767;
            const float4 v = *(const float4*)(x_proj_w + (size_t)l * 65536 + 32768 + off);
            union { short sh[4]; uint2 u; } pk;
            pk.sh[0] = f2b(v.x); pk.sh[1] = f2b(v.y); pk.sh[2] = f2b(v.z); pk.sh[3] = f2b(v.w);
            *(uint2*)(wxpdb + (size_t)l * WXPD_STRIDE + off) = pk.u;
        }
    } else {
        // big-weight conversions: in_proj (4096 chunks), out_proj (2048), proj (1024)
        for (int c = blk - 800; c < 7168; c += 960) {
            const float* src; short* dst;
            bool hasG = false; const float* gp = nullptr;
            bool hasSp = false;
            int e;
            if (c < 4096) {
                e = c * 1024 + tid * 4;
                src = in_proj_w + e; dst = winpb + e;
                hasG = true; gp = blk_norm_w + (e >> 20) * 512 + (e & 511);
                hasSp = ((e >> 20) == 0);
            } else if (c < 6144) {
                e = (c - 4096) * 1024 + tid * 4;
                src = out_proj_w + e; dst = woutpb + e;
            } else {
                e = (c - 6144) * 1024 + tid * 4;
                src = proj_w + e; dst = wprojb + e;
                hasG = true; gp = post_norm_w + (e & 511);
            }
            float4 v = *(const float4*)src;
            if (hasG) {
                const float4 gv = *(const float4*)gp;
                v.x *= gv.x; v.y *= gv.y; v.z *= gv.z; v.w *= gv.w;
            }
            if (hasSp) {
                const float4 sv = *(const float4*)(sp_norm_w + (e & 511));
                v.x *= sv.x; v.y *= sv.y; v.z *= sv.z; v.w *= sv.w;
            }
            union { short sh[4]; uint2 u; } pk;
            pk.sh[0] = f2b(v.x); pk.sh[1] = f2b(v.y); pk.sh[2] = f2b(v.z); pk.sh[3] = f2b(v.w);
            *(uint2*)dst = pk.u;
        }
    }
}

// ================= lin2 (R12/R13, verified) =================
__global__ __launch_bounds__(256) void lin2_k(
    const short* __restrict__ A, const short* __restrict__ W,
    const float* __restrict__ bias, const float* __restrict__ g,
    const float* __restrict__ gsp, float* __restrict__ x, short* __restrict__ xb,
    float* __restrict__ ssS1, float* __restrict__ ssS2)
{
    __shared__ short As[2 * 64 * 64];
    __shared__ short Bs[2 * 64 * 64];
    f32x4 acc[2][2] = {};
    const int m0 = blockIdx.y * 64, n0 = blockIdx.x * 64;
    gemm_core64(acc, A, 512, W, 512, 512, As, Bs, m0, n0);
    const int lane = threadIdx.x & 63, wave = threadIdx.x >> 6;
    const int wm = wave >> 1, wn = wave & 1, l15 = lane & 15, kg = lane >> 4;
    float vs1[2][4] = {}, vs2[2][4] = {};
#pragma unroll
    for (int ni = 0; ni < 2; ni++) {
        const int col = n0 + wn * 32 + ni * 16 + l15;
        const float b = bias[col];
        const float gc = gsp[col];
#pragma unroll
        for (int mi = 0; mi < 2; mi++)
#pragma unroll
            for (int j = 0; j < 4; j++) {
                const int row = m0 + wm * 32 + mi * 16 + kg * 4 + j;
                const float v = (acc[mi][ni][j] + b) * g[(size_t)row * 512 + col];
                x[(size_t)row * 512 + col] = v;
                xb[(size_t)row * 512 + col] = f2b(v);
                vs1[mi][j] = fmaf(v, v, vs1[mi][j]);
                const float w = v * gc;
                vs2[mi][j] = fmaf(w, w, vs2[mi][j]);
            }
    }
#pragma unroll
    for (int mi = 0; mi < 2; mi++)
#pragma unroll
        for (int j = 0; j < 4; j++) {
            float t1 = vs1[mi][j], t2 = vs2[mi][j];
            t1 += __shfl_xor(t1, 1, 64); t2 += __shfl_xor(t2, 1, 64);
            t1 += __shfl_xor(t1, 2, 64); t2 += __shfl_xor(t2, 2, 64);
            t1 += __shfl_xor(t1, 4, 64); t2 += __shfl_xor(t2, 4, 64);
            t1 += __shfl_xor(t1, 8, 64); t2 += __shfl_xor(t2, 8, 64);
            if (l15 == 0) {
                const int row = m0 + wm * 32 + mi * 16 + kg * 4 + j;
                atomicAdd(ssS1 + row, t1);
                atomicAdd(ssS2 + row, t2);
            }
        }
}

// ================= in_proj + fused depthwise conv + silu (R13, verified) =============
union ConvU {
    struct { short As[2 * 64 * 64]; short Bs[2 * 64 * 64]; } gm;   // 32 KB (GEMM)
    float cbuf[67][68];                                             // 18.2 KB (conv)
};

template <int COMB>
__global__ __launch_bounds__(256) void inprojconv_k(
    const short* __restrict__ A, const short* __restrict__ W,
    const float* __restrict__ ssA, const float* __restrict__ ssB,
    const float* __restrict__ cw, const float* __restrict__ cb,
    short* __restrict__ xcb, short* __restrict__ srb)
{
    __shared__ ConvU u;
    f32x4 acc[2][2] = {};
    const int m0 = blockIdx.y * 64, n0 = blockIdx.x * 64;
    gemm_core64(acc, A, 512, W, 512, 512, u.gm.As, u.gm.Bs, m0, n0);
    const int tid = threadIdx.x;
    const int lane = tid & 63, wave = tid >> 6;
    const int wm = wave >> 1, wn = wave & 1, l15 = lane & 15, kg = lane >> 4;

#pragma unroll
    for (int mi = 0; mi < 2; mi++)
#pragma unroll
        for (int j = 0; j < 4; j++) {
            const int row = m0 + wm * 32 + mi * 16 + kg * 4 + j;
            float r;
            if constexpr (COMB) {
                const float rx = rsqrtf(ssA[row] * (1.f / 512.f) + 1e-5f);
                r = rx * rsqrtf(rx * rx * ssB[row] * (1.f / 512.f) + 1e-5f);
            } else {
                r = rsqrtf(ssA[row] * (1.f / 512.f) + 1e-5f);
            }
#pragma unroll
            for (int ni = 0; ni < 2; ni++) acc[mi][ni][j] *= r;
        }

    if (n0 < 1024) {
        const int ccol = tid & 63;
        const int rg = tid >> 6;           // 0..3
        const int d = n0 + ccol;
        const float4 w4 = *(const float4*)(cw + d * 4);
        const float bia = cb[d];

        __syncthreads();   // gemm LDS reads done
#pragma unroll
        for (int mi = 0; mi < 2; mi++)
#pragma unroll
            for (int ni = 0; ni < 2; ni++)
#pragma unroll
                for (int j = 0; j < 4; j++)
                    u.cbuf[3 + wm * 32 + mi * 16 + kg * 4 + j][wn * 32 + ni * 16 + l15] = acc[mi][ni][j];
        for (int i = tid; i < 3 * 68; i += 256) u.cbuf[i / 68][i % 68] = 0.f;
        __syncthreads();
#pragma unroll 4
        for (int k = 0; k < 16; k++) {
            const int row = rg + 4 * k;    // 0..63
            float v = bia + w4.x * u.cbuf[row][ccol] + w4.y * u.cbuf[row + 1][ccol]
                          + w4.z * u.cbuf[row + 2][ccol] + w4.w * u.cbuf[row + 3][ccol];
            v = v * sigm(v);
            xcb[(size_t)(m0 + row) * 1024 + d] = f2b(v);
        }
    } else {
#pragma unroll
        for (int ni = 0; ni < 2; ni++) {
            const int scol = n0 - 1024 + wn * 32 + ni * 16 + l15;
#pragma unroll
            for (int mi = 0; mi < 2; mi++)
#pragma unroll
                for (int j = 0; j < 4; j++) {
                    const int row = m0 + wm * 32 + mi * 16 + kg * 4 + j;
                    const float v = acc[mi][ni][j];
                    srb[(size_t)row * 1024 + scol] = f2b(v * sigm(v));
                }
        }
    }
}

// ================= fused x_proj/dt + scan (R13, verified) =================
union XsU {
    struct { short As[2 * 64 * 32]; short Wd[2 * 64 * 32]; short BC[2 * 32 * 32]; } gm; // 20 KB
    struct { float dlt[64][68]; float BC[64][32]; short ub[64][64]; float yt[64][68]; } sc; // 51 KB
};

__global__ __launch_bounds__(256) void xpdscan_k(
    const short* __restrict__ A /*xcb*/, const short* __restrict__ W /*wxpdb layer*/,
    const float* __restrict__ dtb, const float* __restrict__ Alog,
    const float* __restrict__ Dp, const short* __restrict__ srb, short* __restrict__ yb)
{
    __shared__ XsU u;
    const int dg = blockIdx.x, b = blockIdx.y;
    const int m0 = b * 64;
    const int tid = threadIdx.x;
    const int lane = tid & 63, wave = tid >> 6;
    const int wm = wave >> 1, wn = wave & 1, l15 = lane & 15, kg = lane >> 4;

    constexpr int SZA = 64 * 32, SZBC = 32 * 32;
    const int p = wave * 64 + lane;
    const short* srcA  = A + (size_t)(m0 + (p >> 2)) * 1024 + (p & 3) * 8;
    const short* srcWd = W + (size_t)(32 + dg * 64 + (p >> 2)) * 1024 + (p & 3) * 8;
    const short* srcBC = W + (size_t)(p >> 2) * 1024 + (p & 3) * 8;   // valid p<128
    const int ob = (wave * 64) * 8;

    f32x4 accd[2][2] = {};
    f32x4 accx[2] = {};

    __builtin_amdgcn_global_load_lds((const glb_u32_t*)srcA,  (lds_u32_t*)(u.gm.As + ob), 16, 0, 0);
    __builtin_amdgcn_global_load_lds((const glb_u32_t*)srcWd, (lds_u32_t*)(u.gm.Wd + ob), 16, 0, 0);
    if (wave < 2)
        __builtin_amdgcn_global_load_lds((const glb_u32_t*)srcBC, (lds_u32_t*)(u.gm.BC + ob), 16, 0, 0);

    for (int t = 0; t < 32; t++) {
        __syncthreads();
        if (t + 1 < 32) {
            const int k0 = (t + 1) * 32;
            const int sA = ((t + 1) & 1) * SZA, sBC = ((t + 1) & 1) * SZBC;
            __builtin_amdgcn_global_load_lds((const glb_u32_t*)(srcA + k0),  (lds_u32_t*)(u.gm.As + sA + ob), 16, 0, 0);
            __builtin_amdgcn_global_load_lds((const glb_u32_t*)(srcWd + k0), (lds_u32_t*)(u.gm.Wd + sA + ob), 16, 0, 0);
            if (wave < 2)
                __builtin_amdgcn_global_load_lds((const glb_u32_t*)(srcBC + k0), (lds_u32_t*)(u.gm.BC + sBC + ob), 16, 0, 0);
        }
        const short* Ab  = u.gm.As + (t & 1) * SZA;
        const short* Wdb = u.gm.Wd + (t & 1) * SZA;
        const short* BCb = u.gm.BC + (t & 1) * SZBC;
        short8 af[2], wf[2], bcf;
#pragma unroll
        for (int mi = 0; mi < 2; mi++)
            af[mi] = *(const short8*)(Ab + (wm * 32 + mi * 16 + l15) * 32 + kg * 8);
#pragma unroll
        for (int ni = 0; ni < 2; ni++)
            wf[ni] = *(const short8*)(Wdb + (wn * 32 + ni * 16 + l15) * 32 + kg * 8);
        bcf = *(const short8*)(BCb + (wn * 16 + l15) * 32 + kg * 8);
#pragma unroll
        for (int mi = 0; mi < 2; mi++) {
#pragma unroll
            for (int ni = 0; ni < 2; ni++)
                accd[mi][ni] = __builtin_amdgcn_mfma_f32_16x16x32_bf16(af[mi], wf[ni], accd[mi][ni], 0, 0, 0);
            accx[mi] = __builtin_amdgcn_mfma_f32_16x16x32_bf16(af[mi], bcf, accx[mi], 0, 0, 0);
        }
    }

    __syncthreads();
#pragma unroll
    for (int ni = 0; ni < 2; ni++) {
        const int dl = wn * 32 + ni * 16 + l15;
        const float bb = dtb[dg * 64 + dl];
#pragma unroll
        for (int mi = 0; mi < 2; mi++)
#pragma unroll
            for (int j = 0; j < 4; j++)
                u.sc.dlt[wm * 32 + mi * 16 + kg * 4 + j][dl] = softp(accd[mi][ni][j] + bb);
    }
    {
        const int c = wn * 16 + l15;
#pragma unroll
        for (int mi = 0; mi < 2; mi++)
#pragma unroll
            for (int j = 0; j < 4; j++)
                u.sc.BC[wm * 32 + mi * 16 + kg * 4 + j][c] = accx[mi][j];
    }
#pragma unroll
    for (int k = 0; k < 2; k++) {
        const int c = tid + k * 256;
        const int row = c >> 3, sl = c & 7;
        *(uint4*)&u.sc.ub[row][sl * 8] =
            *(const uint4*)(A + (size_t)(m0 + row) * 1024 + dg * 64 + sl * 8);
    }
    __syncthreads();

    {
        const int d_l = tid >> 2;
        const int ns = (tid & 3) << 2;
        const int d = dg * 64 + d_l;
        float a[4], s[4];
#pragma unroll
        for (int n = 0; n < 4; n++) {
            a[n] = -__expf(Alog[(size_t)d * 16 + ns + n]);
            s[n] = 0.f;
        }
        const float dv = Dp[d];
        for (int l = 0; l < SEQ; l++) {
            const float dlt = u.sc.dlt[l][d_l];
            const float uu = b2f(u.sc.ub[l][d_l]);
            const float dbu = dlt * uu;
            float part = 0.f;
#pragma unroll
            for (int n = 0; n < 4; n++) {
                s[n] = __expf(dlt * a[n]) * s[n] + dbu * u.sc.BC[l][ns + n];
                part = fmaf(s[n], u.sc.BC[l][16 + ns + n], part);
            }
            part += __shfl_xor(part, 1, 64);
            part += __shfl_xor(part, 2, 64);
            if ((tid & 3) == 0) u.sc.yt[l][d_l] = part + uu * dv;
        }
    }
    __syncthreads();
#pragma unroll
    for (int k = 0; k < 2; k++) {
        const int c = tid + k * 256;
        const int row = c >> 3, sl = c & 7;
        const short8 rv = *(const short8*)(srb + (size_t)(m0 + row) * 1024 + dg * 64 + sl * 8);
        short8 out;
#pragma unroll
        for (int j = 0; j < 8; j++)
            out[j] = f2b(u.sc.yt[row][sl * 8 + j] * b2f(rv[j]));
        *(short8*)(yb + (size_t)(m0 + row) * 1024 + dg * 64 + sl * 8) = out;
    }
}

// ================= out_proj: 32x64 tile, BK=64 swizzled =================
template <int FIRST>
__global__ __launch_bounds__(256) void outproj_k(
    const short* __restrict__ A, const short* __restrict__ W,
    float* __restrict__ h, short* __restrict__ hb, float* __restrict__ ss_out,
    const float* __restrict__ xsrc, const float* __restrict__ gsp,
    const float* __restrict__ ssS1)
{
    __shared__ short As[2 * 32 * 64];   // 8 KB dbuf
    __shared__ short Bs[2 * 64 * 64];   // 16 KB dbuf
    constexpr int SZA = 32 * 64, SZB = 64 * 64;
    const int m0 = blockIdx.y * 32, n0 = blockIdx.x * 64;
    const int tid = threadIdx.x, wave = tid >> 6, lane = tid & 63;
    const int l15 = lane & 15, kg = lane >> 4;

    // A: 256 chunks (1/thread); B: 512 chunks (2/thread). Source pre-swizzled.
    const int ra = tid >> 3, sa = tid & 7;
    const short* srcA = A + (size_t)(m0 + ra) * 1024 + ((sa ^ (ra & 7)) * 8);
    const int rb1 = 32 + (tid >> 3);
    const short* srcB0 = W + (size_t)(n0 + ra) * 1024 + ((sa ^ (ra & 7)) * 8);
    const short* srcB1 = W + (size_t)(n0 + rb1) * 1024 + ((sa ^ (rb1 & 7)) * 8);
    const int obA = wave * 512;
    const int obB0 = wave * 512, obB1 = 2048 + wave * 512;

    f32x4 acc[2] = {};
    __builtin_amdgcn_global_load_lds((const glb_u32_t*)srcA,  (lds_u32_t*)(As + obA), 16, 0, 0);
    __builtin_amdgcn_global_load_lds((const glb_u32_t*)srcB0, (lds_u32_t*)(Bs + obB0), 16, 0, 0);
    __builtin_amdgcn_global_load_lds((const glb_u32_t*)srcB1, (lds_u32_t*)(Bs + obB1), 16, 0, 0);

    for (int t = 0; t < 16; t++) {
        __syncthreads();
        if (t + 1 < 16) {
            const int k0 = (t + 1) * 64;
            const int sA = ((t + 1) & 1) * SZA, sB = ((t + 1) & 1) * SZB;
            __builtin_amdgcn_global_load_lds((const glb_u32_t*)(srcA + k0),  (lds_u32_t*)(As + sA + obA), 16, 0, 0);
            __builtin_amdgcn_global_load_lds((const glb_u32_t*)(srcB0 + k0), (lds_u32_t*)(Bs + sB + obB0), 16, 0, 0);
            __builtin_amdgcn_global_load_lds((const glb_u32_t*)(srcB1 + k0), (lds_u32_t*)(Bs + sB + obB1), 16, 0, 0);
        }
        const short* Ab = As + (t & 1) * SZA;
        const short* Bb = Bs + (t & 1) * SZB;
        short8 af[2][2], bf[2];
#pragma unroll
        for (int hk = 0; hk < 2; hk++) {
#pragma unroll
            for (int mi = 0; mi < 2; mi++) {
                const int row = mi * 16 + l15;
                af[hk][mi] = *(const short8*)(Ab + row * 64 + (((hk * 4 + kg) ^ (row & 7)) * 8));
            }
            const int rowb = wave * 16 + l15;
            bf[hk] = *(const short8*)(Bb + rowb * 64 + (((hk * 4 + kg) ^ (rowb & 7)) * 8));
        }
#pragma unroll
        for (int hk = 0; hk < 2; hk++)
#pragma unroll
            for (int mi = 0; mi < 2; mi++)
                acc[mi] = __builtin_amdgcn_mfma_f32_16x16x32_bf16(af[hk][mi], bf[hk], acc[mi], 0, 0, 0);
    }

    const int col = n0 + wave * 16 + l15;
    const float gc = FIRST ? gsp[col] : 0.f;
    float vsq[2][4] = {};
#pragma unroll
    for (int mi = 0; mi < 2; mi++)
#pragma unroll
        for (int j = 0; j < 4; j++) {
            const int row = m0 + mi * 16 + kg * 4 + j;
            float hold;
            if constexpr (FIRST) {
                const float rx = rsqrtf(ssS1[row] * (1.f / 512.f) + 1e-5f);
                hold = xsrc[(size_t)row * 512 + col] * rx * gc;
            } else {
                hold = h[(size_t)row * 512 + col];
            }
            const float v = acc[mi][j] + hold;
            h[(size_t)row * 512 + col] = v;
            hb[(size_t)row * 512 + col] = f2b(v);
            vsq[mi][j] = v * v;
        }
#pragma unroll
    for (int mi = 0; mi < 2; mi++)
#pragma unroll
        for (int j = 0; j < 4; j++) {
            float t = vsq[mi][j];
            t += __shfl_xor(t, 1, 64);
            t += __shfl_xor(t, 2, 64);
            t += __shfl_xor(t, 4, 64);
            t += __shfl_xor(t, 8, 64);
            if (l15 == 0) {
                const int row = m0 + mi * 16 + kg * 4 + j;
                atomicAdd(ss_out + row, t);
            }
        }
}

// ================= final proj (R13, verified) =================
__global__ __launch_bounds__(256) void projf_k(
    const short* __restrict__ A, const short* __restrict__ W,
    const float* __restrict__ ss_in, float* __restrict__ xr)
{
    __shared__ short As[2 * 64 * 64];
    __shared__ short Bs[2 * 64 * 64];
    f32x4 acc[2][2] = {};
    const int m0 = blockIdx.y * 64, n0 = blockIdx.x * 64;
    gemm_core64(acc, A, 512, W, 512, 512, As, Bs, m0, n0);
    const int lane = threadIdx.x & 63, wave = threadIdx.x >> 6;
    const int wm = wave >> 1, wn = wave & 1, l15 = lane & 15, kg = lane >> 4;
#pragma unroll
    for (int mi = 0; mi < 2; mi++)
#pragma unroll
        for (int j = 0; j < 4; j++) {
            const int row = m0 + wm * 32 + mi * 16 + kg * 4 + j;
            const float r = rsqrtf(ss_in[row] * (1.f / 512.f) + 1e-5f);
#pragma unroll
            for (int ni = 0; ni < 2; ni++) {
                const int col = n0 + wn * 32 + ni * 16 + l15;
                xr[(size_t)row * 2048 + col] = acc[mi][ni][j] * r;
            }
        }
}

// ================= coeffs + preds (R2, verified) =================
__global__ __launch_bounds__(256) void coeffs_k(
    const float* __restrict__ outp, const float* __restrict__ inp,
    float* __restrict__ coeffs, float* __restrict__ preds)
{
    const int m = blockIdx.x;
    const int b = m >> 6;
    const int tid = threadIdx.x, wave = tid >> 6, lane = tid & 63;
    __shared__ float4 Us[256], Vs[256];
    __shared__ float ins[256];
    __shared__ float4 tpart[4];
    Us[tid] = *(const float4*)(outp + (size_t)m * 2048 + tid * 4);
    Vs[tid] = *(const float4*)(outp + (size_t)m * 2048 + 1024 + tid * 4);
    ins[tid] = inp[(size_t)m * 256 + tid];
    __syncthreads();
    const float4 vq0 = Vs[lane * 4 + 0], vq1 = Vs[lane * 4 + 1];
    const float4 vq2 = Vs[lane * 4 + 2], vq3 = Vs[lane * 4 + 3];
    float* cbase = coeffs + (size_t)m * 65536 + lane * 4;
#pragma unroll 4
    for (int i = 0; i < 64; i++) {
        const int pp = (wave << 6) + i;
        const float4 up = Us[pp];
        float4 c;
        c.x = up.x * vq0.x + up.y * vq0.y + up.z * vq0.z + up.w * vq0.w;
        c.y = up.x * vq1.x + up.y * vq1.y + up.z * vq1.z + up.w * vq1.w;
        c.z = up.x * vq2.x + up.y * vq2.y + up.z * vq2.z + up.w * vq2.w;
        c.w = up.x * vq3.x + up.y * vq3.y + up.z * vq3.z + up.w * vq3.w;
        *(float4*)(cbase + (size_t)pp * 256) = c;
    }
    const float iv = ins[tid];
    const float4 vm = Vs[tid];
    float4 t = make_float4(vm.x * iv, vm.y * iv, vm.z * iv, vm.w * iv);
#pragma unroll
    for (int off = 32; off > 0; off >>= 1) {
        t.x += __shfl_xor(t.x, off, 64);
        t.y += __shfl_xor(t.y, off, 64);
        t.z += __shfl_xor(t.z, off, 64);
        t.w += __shfl_xor(t.w, off, 64);
    }
    if (lane == 0) tpart[wave] = t;
    __syncthreads();
    const float4 t0 = tpart[0], t1 = tpart[1], t2 = tpart[2], t3 = tpart[3];
    const float4 tt = make_float4(t0.x + t1.x + t2.x + t3.x, t0.y + t1.y + t2.y + t3.y,
                                  t0.z + t1.z + t2.z + t3.z, t0.w + t1.w + t2.w + t3.w);
    const float4 up = Us[tid];
    const float pv = up.x * tt.x + up.y * tt.y + up.z * tt.z + up.w * tt.w;
    atomicAdd(preds + (size_t)b * 256 + tid, pv);
}

} // namespace

extern "C" void kernel_launch(void* const* d_in, const int* in_sizes, int n_in,
                              void* d_out, int out_size, void* d_ws, size_t ws_size,
                              hipStream_t stream)
{
    const float* inputs     = (const float*)d_in[0];
    const float* lin1_w     = (const float*)d_in[1];
    const float* lin1_b     = (const float*)d_in[2];
    const float* lin2_w     = (const float*)d_in[3];
    const float* lin2_b     = (const float*)d_in[4];
    const float* gate_w     = (const float*)d_in[5];
    const float* gate_b     = (const float*)d_in[6];
    const float* sp_norm_w  = (const float*)d_in[7];
    const float* in_proj_w  = (const float*)d_in[8];
    const float* conv_w     = (const float*)d_in[9];
    const float* conv_b     = (const float*)d_in[10];
    const float* x_proj_w   = (const float*)d_in[11];
    const float* dt_proj_w  = (const float*)d_in[12];
    const float* dt_proj_b  = (const float*)d_in[13];
    const float* A_log      = (const float*)d_in[14];
    const float* Dvec       = (const float*)d_in[15];
    const float* out_proj_w = (const float*)d_in[16];
    const float* blk_norm_w = (const float*)d_in[17];
    const float* post_norm_w= (const float*)d_in[18];
    const float* proj_w     = (const float*)d_in[19];

    float* ws = (float*)d_ws;
    // fp32 region
    float* h     = ws;                 // 1024 x 512
    float* xr    = ws + 524288;        // 1024 x 2048 (final proj out)
    float* x     = ws + 2621440;       // 1024 x 512 (lin2 out)
    float* g     = ws + 3145728;       // 1024 x 512
    float* ss    = ws + 3670016;       // slots: 0=S1, 1..4=sum h^2, 5=S2
    // bf16 region
    short* bfb     = (short*)(ws + 3676160);
    short* inputsb = bfb;               // 1024 x 256
    short* h1b     = bfb + 262144;      // 1024 x 512
    short* hb      = bfb + 786432;      // 1024 x 512
    short* xcb     = bfb + 1310720;     // 1024 x 1024
    short* yb      = bfb + 2359296;     // 1024 x 1024
    short* xb      = yb;                // 1024 x 512 ALIAS (dead until xpdscan l0)
    short* srb     = bfb + 3407872;     // 1024 x 1024 silu(res)
    short* wlin1gb = bfb + 4456448;     // 1024 x 256
    short* wlin2b  = bfb + 4718592;     // 512 x 512
    short* winpb   = bfb + 4980736;     // 4 x 2048 x 512 (gamma-folded; l0 also gamma_sp)
    short* woutpb  = bfb + 9175040;     // 4 x 512 x 1024
    short* wprojb  = bfb + 11272192;    // 2048 x 512 (gamma-folded)
    short* wxpdb   = bfb + 12320768;    // 4 x 1056 x 1024 ([BC; W_delta])
    float* preds  = (float*)d_out;
    float* coeffs = (float*)d_out + 4096;

    const dim3 blk(256);

    prep_early_k<<<dim3(808), blk, 0, stream>>>(
        lin1_w, gate_w, lin2_w, inputs, wlin1gb, wlin2b, inputsb, preds, ss);

    lin1gate_k<<<dim3(1760), blk, 0, stream>>>(
        inputsb, wlin1gb, lin1_b, gate_b, h1b, g,
        x_proj_w, dt_proj_w, in_proj_w, out_proj_w, proj_w,
        blk_norm_w, post_norm_w, sp_norm_w,
        winpb, woutpb, wprojb, wxpdb);

    lin2_k<<<dim3(8, 16), blk, 0, stream>>>(h1b, wlin2b, lin2_b, g, sp_norm_w,
                                            x, xb, ss, ss + 5120);

    for (int l = 0; l < 4; l++) {
        if (l == 0)
            inprojconv_k<1><<<dim3(32, 16), blk, 0, stream>>>(
                xb, winpb, ss, ss + 5120,
                conv_w, conv_b, xcb, srb);
        else
            inprojconv_k<0><<<dim3(32, 16), blk, 0, stream>>>(
                hb, winpb + (size_t)l * 1048576, ss + l * 1024, nullptr,
                conv_w + (size_t)l * 4096, conv_b + l * 1024, xcb, srb);
        xpdscan_k<<<dim3(16, 16), blk, 0, stream>>>(
            xcb, wxpdb + (size_t)l * WXPD_STRIDE, dt_proj_b + l * 1024,
            A_log + (size_t)l * 16384, Dvec + l * 1024, srb, yb);
        if (l == 0)
            outproj_k<1><<<dim3(8, 32), blk, 0, stream>>>(yb, woutpb,
                h, hb, ss + 1024, x, sp_norm_w, ss);
        else
            outproj_k<0><<<dim3(8, 32), blk, 0, stream>>>(yb, woutpb + (size_t)l * 524288,
                h, hb, ss + (l + 1) * 1024, nullptr, nullptr, nullptr);
    }

    projf_k<<<dim3(32, 16), blk, 0, stream>>>(hb, wprojb, ss + 4096, xr);
    coeffs_k<<<dim3(1024), blk, 0, stream>>>(xr, inputs, coeffs, preds);
}

// Round 15
// 352.134 us; speedup vs baseline: 1.5493x; 1.0196x over previous
//
#include <hip/hip_runtime.h>
#include <hip/hip_bf16.h>
#include <math.h>

namespace {

constexpr int SEQ    = 64;
constexpr int DINNER = 1024;
constexpr int WXPD_STRIDE = 1056 * 1024;   // rows 0..31 = BC weights, 32..1055 = W_delta

typedef __attribute__((ext_vector_type(8))) short short8;
typedef __attribute__((ext_vector_type(4))) float f32x4;
typedef __attribute__((address_space(3))) unsigned int lds_u32_t;
typedef __attribute__((address_space(1))) unsigned int glb_u32_t;

__device__ __forceinline__ float sigm(float x) { return 1.f / (1.f + __expf(-x)); }
__device__ __forceinline__ short f2b(float v) {
    __hip_bfloat16 h = __float2bfloat16(v);
    return *(short*)&h;
}
__device__ __forceinline__ float b2f(short s) {
    union { unsigned u; float f; } c; c.u = ((unsigned)(unsigned short)s) << 16; return c.f;
}
__device__ __forceinline__ float softp(float v) {
    return fmaxf(v, 0.f) + log1pf(__expf(-fabsf(v)));
}

// ====== bf16 MFMA GEMM core, 64x64 tile, BK=64, 2-phase pipelined (R13, verified) ======
__device__ __forceinline__ void gemm_core64(
    f32x4 (&acc)[2][2],
    const short* __restrict__ A, int lda,
    const short* __restrict__ W, int ldw,
    int Kd, short* As, short* Bs, int m0, int n0)
{
    constexpr int SZ = 64 * 64;
    const int tid = threadIdx.x, wave = tid >> 6, lane = tid & 63;
    const int wm = wave >> 1, wn = wave & 1;
    const int l15 = lane & 15, kg = lane >> 4;

    const int r0 = tid >> 3,        s0 = tid & 7;
    const int r1 = 32 + (tid >> 3), s1 = s0;
    const short* srcA0 = A + (size_t)(m0 + r0) * lda + ((s0 ^ (r0 & 7)) * 8);
    const short* srcA1 = A + (size_t)(m0 + r1) * lda + ((s1 ^ (r1 & 7)) * 8);
    const short* srcB0 = W + (size_t)(n0 + r0) * ldw + ((s0 ^ (r0 & 7)) * 8);
    const short* srcB1 = W + (size_t)(n0 + r1) * ldw + ((s1 ^ (r1 & 7)) * 8);
    const int ob0 = wave * 512;
    const int ob1 = 2048 + wave * 512;

    const int nt = Kd >> 6;
    __builtin_amdgcn_global_load_lds((const glb_u32_t*)srcA0, (lds_u32_t*)(As + ob0), 16, 0, 0);
    __builtin_amdgcn_global_load_lds((const glb_u32_t*)srcA1, (lds_u32_t*)(As + ob1), 16, 0, 0);
    __builtin_amdgcn_global_load_lds((const glb_u32_t*)srcB0, (lds_u32_t*)(Bs + ob0), 16, 0, 0);
    __builtin_amdgcn_global_load_lds((const glb_u32_t*)srcB1, (lds_u32_t*)(Bs + ob1), 16, 0, 0);

    for (int t = 0; t < nt; t++) {
        __syncthreads();
        if (t + 1 < nt) {
            const int k0 = (t + 1) * 64;
            const int s = ((t + 1) & 1) * SZ;
            __builtin_amdgcn_global_load_lds((const glb_u32_t*)(srcA0 + k0), (lds_u32_t*)(As + s + ob0), 16, 0, 0);
            __builtin_amdgcn_global_load_lds((const glb_u32_t*)(srcA1 + k0), (lds_u32_t*)(As + s + ob1), 16, 0, 0);
            __builtin_amdgcn_global_load_lds((const glb_u32_t*)(srcB0 + k0), (lds_u32_t*)(Bs + s + ob0), 16, 0, 0);
            __builtin_amdgcn_global_load_lds((const glb_u32_t*)(srcB1 + k0), (lds_u32_t*)(Bs + s + ob1), 16, 0, 0);
        }
        const short* Ab = As + (t & 1) * SZ;
        const short* Bb = Bs + (t & 1) * SZ;
        short8 af[2][2], bfr[2][2];
#pragma unroll
        for (int hk = 0; hk < 2; hk++) {
#pragma unroll
            for (int mi = 0; mi < 2; mi++) {
                const int row = wm * 32 + mi * 16 + l15;
                af[hk][mi] = *(const short8*)(Ab + row * 64 + (((hk * 4 + kg) ^ (row & 7)) * 8));
            }
#pragma unroll
            for (int ni = 0; ni < 2; ni++) {
                const int row = wn * 32 + ni * 16 + l15;
                bfr[hk][ni] = *(const short8*)(Bb + row * 64 + (((hk * 4 + kg) ^ (row & 7)) * 8));
            }
        }
#pragma unroll
        for (int hk = 0; hk < 2; hk++)
#pragma unroll
            for (int mi = 0; mi < 2; mi++)
#pragma unroll
                for (int ni = 0; ni < 2; ni++)
                    acc[mi][ni] = __builtin_amdgcn_mfma_f32_16x16x32_bf16(af[hk][mi], bfr[hk][ni], acc[mi][ni], 0, 0, 0);
    }
}
// C/D frag [m89]: col = n0 + wn*32 + ni*16 + (lane&15);
//                 row = m0 + wm*32 + mi*16 + (lane>>4)*4 + j

// ================= prep_early: small conversions + zeroing (R14, verified) ============
__global__ __launch_bounds__(256) void prep_early_k(
    const float* __restrict__ lin1_w, const float* __restrict__ gate_w,
    const float* __restrict__ lin2_w, const float* __restrict__ inputs,
    short* __restrict__ wlin1gb, short* __restrict__ wlin2b, short* __restrict__ inputsb,
    float* __restrict__ preds, float* __restrict__ ss)
{
    const int blk = blockIdx.x, tid = threadIdx.x;
    if (blk < 768) {
        const float* src; short* dst;
        int e;
        if (blk < 128)      { e = blk * 1024 + tid * 4;          src = lin1_w + e;  dst = wlin1gb + e; }
        else if (blk < 256) { e = (blk - 128) * 1024 + tid * 4;  src = gate_w + e;  dst = wlin1gb + 131072 + e; }
        else if (blk < 512) { e = (blk - 256) * 1024 + tid * 4;  src = lin2_w + e;  dst = wlin2b + e; }
        else                { e = (blk - 512) * 1024 + tid * 4;  src = inputs + e;  dst = inputsb + e; }
        const float4 v = *(const float4*)src;
        union { short sh[4]; uint2 u; } pk;
        pk.sh[0] = f2b(v.x); pk.sh[1] = f2b(v.y); pk.sh[2] = f2b(v.z); pk.sh[3] = f2b(v.w);
        *(uint2*)dst = pk.u;
    } else {
        const int i = (blk - 768) * 256 + tid;   // < 10240
        if (i < 4096) preds[i] = 0.f;
        else if (i < 10240) ss[i - 4096] = 0.f;   // ss slots 0..5
    }
}

// ================= lin1gate + aux prep (R14, verified) =================
__global__ __launch_bounds__(256) void lin1gate_k(
    const short* __restrict__ A, const short* __restrict__ W,
    const float* __restrict__ b1, const float* __restrict__ b2,
    short* __restrict__ h1b, float* __restrict__ g,
    const float* __restrict__ x_proj_w, const float* __restrict__ dt_proj_w,
    const float* __restrict__ in_proj_w, const float* __restrict__ out_proj_w,
    const float* __restrict__ proj_w, const float* __restrict__ blk_norm_w,
    const float* __restrict__ post_norm_w, const float* __restrict__ sp_norm_w,
    short* __restrict__ winpb, short* __restrict__ woutpb,
    short* __restrict__ wprojb, short* __restrict__ wxpdb)
{
    __shared__ short As[2 * 64 * 64];
    __shared__ short Bs[2 * 64 * 64];
    const int blk = blockIdx.x, tid = threadIdx.x;

    if (blk < 256) {
        f32x4 acc[2][2] = {};
        const int m0 = (blk >> 4) * 64, n0 = (blk & 15) * 64;
        gemm_core64(acc, A, 256, W, 256, 256, As, Bs, m0, n0);
        const int lane = tid & 63, wave = tid >> 6;
        const int wm = wave >> 1, wn = wave & 1, l15 = lane & 15, kg = lane >> 4;
#pragma unroll
        for (int ni = 0; ni < 2; ni++) {
            const int col = n0 + wn * 32 + ni * 16 + l15;
            const bool isG = col >= 512;
            const float b = isG ? b2[col - 512] : b1[col];
#pragma unroll
            for (int mi = 0; mi < 2; mi++)
#pragma unroll
                for (int j = 0; j < 4; j++) {
                    const int row = m0 + wm * 32 + mi * 16 + kg * 4 + j;
                    const float v = acc[mi][ni][j] + b;
                    if (isG) g[(size_t)row * 512 + (col - 512)] = sigm(v);
                    else     h1b[(size_t)row * 512 + col] = f2b(0.5f * v * (1.f + erff(v * 0.70710678f)));
                }
        }
    } else if (blk < 768) {
        const int wave = tid >> 6, lane = tid & 63;
        const int nrow = (blk - 256) * 8 + wave * 2;
        const int l = nrow >> 10, n = nrow & 1023;
        const float* dtw0 = dt_proj_w + (size_t)l * 32768 + n * 32;
        const float* dtw1 = dtw0 + 32;
        const float* xpw = x_proj_w + (size_t)l * 65536;
        float4 a0[4] = {}, a1[4] = {};
        for (int r = 0; r < 32; r++) {
            const float s0 = dtw0[r], s1 = dtw1[r];
#pragma unroll
            for (int rep = 0; rep < 4; rep++) {
                const float4 xv = *(const float4*)(xpw + r * 1024 + rep * 256 + lane * 4);
                a0[rep].x = fmaf(s0, xv.x, a0[rep].x); a0[rep].y = fmaf(s0, xv.y, a0[rep].y);
                a0[rep].z = fmaf(s0, xv.z, a0[rep].z); a0[rep].w = fmaf(s0, xv.w, a0[rep].w);
                a1[rep].x = fmaf(s1, xv.x, a1[rep].x); a1[rep].y = fmaf(s1, xv.y, a1[rep].y);
                a1[rep].z = fmaf(s1, xv.z, a1[rep].z); a1[rep].w = fmaf(s1, xv.w, a1[rep].w);
            }
        }
        short* dst0 = wxpdb + (size_t)l * WXPD_STRIDE + (size_t)(32 + n) * 1024;
        short* dst1 = dst0 + 1024;
#pragma unroll
        for (int rep = 0; rep < 4; rep++) {
            union { short sh[4]; uint2 u; } p0, p1;
            p0.sh[0] = f2b(a0[rep].x); p0.sh[1] = f2b(a0[rep].y);
            p0.sh[2] = f2b(a0[rep].z); p0.sh[3] = f2b(a0[rep].w);
            p1.sh[0] = f2b(a1[rep].x); p1.sh[1] = f2b(a1[rep].y);
            p1.sh[2] = f2b(a1[rep].z); p1.sh[3] = f2b(a1[rep].w);
            *(uint2*)(dst0 + rep * 256 + lane * 4) = p0.u;
            *(uint2*)(dst1 + rep * 256 + lane * 4) = p1.u;
        }
    } else if (blk < 800) {
#pragma unroll
        for (int rep = 0; rep < 4; rep++) {
            const int idx = (blk - 768) * 4096 + rep * 1024 + tid * 4;   // < 131072
            const int l = idx >> 15, off = idx & 32767;
            const float4 v = *(const float4*)(x_proj_w + (size_t)l * 65536 + 32768 + off);
            union { short sh[4]; uint2 u; } pk;
            pk.sh[0] = f2b(v.x); pk.sh[1] = f2b(v.y); pk.sh[2] = f2b(v.z); pk.sh[3] = f2b(v.w);
            *(uint2*)(wxpdb + (size_t)l * WXPD_STRIDE + off) = pk.u;
        }
    } else {
        for (int c = blk - 800; c < 7168; c += 960) {
            const float* src; short* dst;
            bool hasG = false; const float* gp = nullptr;
            bool hasSp = false;
            int e;
            if (c < 4096) {
                e = c * 1024 + tid * 4;
                src = in_proj_w + e; dst = winpb + e;
                hasG = true; gp = blk_norm_w + (e >> 20) * 512 + (e & 511);
                hasSp = ((e >> 20) == 0);
            } else if (c < 6144) {
                e = (c - 4096) * 1024 + tid * 4;
                src = out_proj_w + e; dst = woutpb + e;
            } else {
                e = (c - 6144) * 1024 + tid * 4;
                src = proj_w + e; dst = wprojb + e;
                hasG = true; gp = post_norm_w + (e & 511);
            }
            float4 v = *(const float4*)src;
            if (hasG) {
                const float4 gv = *(const float4*)gp;
                v.x *= gv.x; v.y *= gv.y; v.z *= gv.z; v.w *= gv.w;
            }
            if (hasSp) {
                const float4 sv = *(const float4*)(sp_norm_w + (e & 511));
                v.x *= sv.x; v.y *= sv.y; v.z *= sv.z; v.w *= sv.w;
            }
            union { short sh[4]; uint2 u; } pk;
            pk.sh[0] = f2b(v.x); pk.sh[1] = f2b(v.y); pk.sh[2] = f2b(v.z); pk.sh[3] = f2b(v.w);
            *(uint2*)dst = pk.u;
        }
    }
}

// ================= lin2 (R12/R13, verified) =================
__global__ __launch_bounds__(256) void lin2_k(
    const short* __restrict__ A, const short* __restrict__ W,
    const float* __restrict__ bias, const float* __restrict__ g,
    const float* __restrict__ gsp, float* __restrict__ x, short* __restrict__ xb,
    float* __restrict__ ssS1, float* __restrict__ ssS2)
{
    __shared__ short As[2 * 64 * 64];
    __shared__ short Bs[2 * 64 * 64];
    f32x4 acc[2][2] = {};
    const int m0 = blockIdx.y * 64, n0 = blockIdx.x * 64;
    gemm_core64(acc, A, 512, W, 512, 512, As, Bs, m0, n0);
    const int lane = threadIdx.x & 63, wave = threadIdx.x >> 6;
    const int wm = wave >> 1, wn = wave & 1, l15 = lane & 15, kg = lane >> 4;
    float vs1[2][4] = {}, vs2[2][4] = {};
#pragma unroll
    for (int ni = 0; ni < 2; ni++) {
        const int col = n0 + wn * 32 + ni * 16 + l15;
        const float b = bias[col];
        const float gc = gsp[col];
#pragma unroll
        for (int mi = 0; mi < 2; mi++)
#pragma unroll
            for (int j = 0; j < 4; j++) {
                const int row = m0 + wm * 32 + mi * 16 + kg * 4 + j;
                const float v = (acc[mi][ni][j] + b) * g[(size_t)row * 512 + col];
                x[(size_t)row * 512 + col] = v;
                xb[(size_t)row * 512 + col] = f2b(v);
                vs1[mi][j] = fmaf(v, v, vs1[mi][j]);
                const float w = v * gc;
                vs2[mi][j] = fmaf(w, w, vs2[mi][j]);
            }
    }
#pragma unroll
    for (int mi = 0; mi < 2; mi++)
#pragma unroll
        for (int j = 0; j < 4; j++) {
            float t1 = vs1[mi][j], t2 = vs2[mi][j];
            t1 += __shfl_xor(t1, 1, 64); t2 += __shfl_xor(t2, 1, 64);
            t1 += __shfl_xor(t1, 2, 64); t2 += __shfl_xor(t2, 2, 64);
            t1 += __shfl_xor(t1, 4, 64); t2 += __shfl_xor(t2, 4, 64);
            t1 += __shfl_xor(t1, 8, 64); t2 += __shfl_xor(t2, 8, 64);
            if (l15 == 0) {
                const int row = m0 + wm * 32 + mi * 16 + kg * 4 + j;
                atomicAdd(ssS1 + row, t1);
                atomicAdd(ssS2 + row, t2);
            }
        }
}

// ================= in_proj + fused depthwise conv + silu (R13, verified) =============
union ConvU {
    struct { short As[2 * 64 * 64]; short Bs[2 * 64 * 64]; } gm;   // 32 KB (GEMM)
    float cbuf[67][68];                                             // 18.2 KB (conv)
};

template <int COMB>
__global__ __launch_bounds__(256) void inprojconv_k(
    const short* __restrict__ A, const short* __restrict__ W,
    const float* __restrict__ ssA, const float* __restrict__ ssB,
    const float* __restrict__ cw, const float* __restrict__ cb,
    short* __restrict__ xcb, short* __restrict__ srb)
{
    __shared__ ConvU u;
    f32x4 acc[2][2] = {};
    const int m0 = blockIdx.y * 64, n0 = blockIdx.x * 64;
    gemm_core64(acc, A, 512, W, 512, 512, u.gm.As, u.gm.Bs, m0, n0);
    const int tid = threadIdx.x;
    const int lane = tid & 63, wave = tid >> 6;
    const int wm = wave >> 1, wn = wave & 1, l15 = lane & 15, kg = lane >> 4;

#pragma unroll
    for (int mi = 0; mi < 2; mi++)
#pragma unroll
        for (int j = 0; j < 4; j++) {
            const int row = m0 + wm * 32 + mi * 16 + kg * 4 + j;
            float r;
            if constexpr (COMB) {
                const float rx = rsqrtf(ssA[row] * (1.f / 512.f) + 1e-5f);
                r = rx * rsqrtf(rx * rx * ssB[row] * (1.f / 512.f) + 1e-5f);
            } else {
                r = rsqrtf(ssA[row] * (1.f / 512.f) + 1e-5f);
            }
#pragma unroll
            for (int ni = 0; ni < 2; ni++) acc[mi][ni][j] *= r;
        }

    if (n0 < 1024) {
        const int ccol = tid & 63;
        const int rg = tid >> 6;           // 0..3
        const int d = n0 + ccol;
        const float4 w4 = *(const float4*)(cw + d * 4);
        const float bia = cb[d];

        __syncthreads();   // gemm LDS reads done
#pragma unroll
        for (int mi = 0; mi < 2; mi++)
#pragma unroll
            for (int ni = 0; ni < 2; ni++)
#pragma unroll
                for (int j = 0; j < 4; j++)
                    u.cbuf[3 + wm * 32 + mi * 16 + kg * 4 + j][wn * 32 + ni * 16 + l15] = acc[mi][ni][j];
        for (int i = tid; i < 3 * 68; i += 256) u.cbuf[i / 68][i % 68] = 0.f;
        __syncthreads();
#pragma unroll 4
        for (int k = 0; k < 16; k++) {
            const int row = rg + 4 * k;    // 0..63
            float v = bia + w4.x * u.cbuf[row][ccol] + w4.y * u.cbuf[row + 1][ccol]
                          + w4.z * u.cbuf[row + 2][ccol] + w4.w * u.cbuf[row + 3][ccol];
            v = v * sigm(v);
            xcb[(size_t)(m0 + row) * 1024 + d] = f2b(v);
        }
    } else {
#pragma unroll
        for (int ni = 0; ni < 2; ni++) {
            const int scol = n0 - 1024 + wn * 32 + ni * 16 + l15;
#pragma unroll
            for (int mi = 0; mi < 2; mi++)
#pragma unroll
                for (int j = 0; j < 4; j++) {
                    const int row = m0 + wm * 32 + mi * 16 + kg * 4 + j;
                    const float v = acc[mi][ni][j];
                    srb[(size_t)row * 1024 + scol] = f2b(v * sigm(v));
                }
        }
    }
}

// ================= fused x_proj/dt + scan, BK=64 swizzled GEMM =================
// W layout: rows 0..31 = BC, rows 32..1055 = W_delta. One K=1024 pass, nt=16.
union XsU {
    struct { short As[2 * 64 * 64]; short Wd[2 * 64 * 64]; short BC[2 * 32 * 64]; } gm; // 40 KB
    struct { float dlt[64][68]; float BC[64][32]; short ub[64][64]; float yt[64][68]; } sc; // 51 KB
};

__global__ __launch_bounds__(256) void xpdscan_k(
    const short* __restrict__ A /*xcb*/, const short* __restrict__ W /*wxpdb layer*/,
    const float* __restrict__ dtb, const float* __restrict__ Alog,
    const float* __restrict__ Dp, const short* __restrict__ srb, short* __restrict__ yb)
{
    __shared__ XsU u;
    const int dg = blockIdx.x, b = blockIdx.y;
    const int m0 = b * 64;
    const int tid = threadIdx.x;
    const int lane = tid & 63, wave = tid >> 6;
    const int wm = wave >> 1, wn = wave & 1, l15 = lane & 15, kg = lane >> 4;

    constexpr int SZA = 64 * 64, SZBC = 32 * 64;
    // staging (inverse-swizzled sources, rule #21): chunk id == tid (+256 for *1)
    const int r0 = tid >> 3, s0 = tid & 7;
    const int r1 = 32 + r0;
    const short* srcA0  = A + (size_t)(m0 + r0) * 1024 + ((s0 ^ (r0 & 7)) * 8);
    const short* srcA1  = A + (size_t)(m0 + r1) * 1024 + ((s0 ^ (r1 & 7)) * 8);
    const short* srcWd0 = W + (size_t)(32 + dg * 64 + r0) * 1024 + ((s0 ^ (r0 & 7)) * 8);
    const short* srcWd1 = W + (size_t)(32 + dg * 64 + r1) * 1024 + ((s0 ^ (r1 & 7)) * 8);
    const short* srcBC  = W + (size_t)r0 * 1024 + ((s0 ^ (r0 & 7)) * 8);   // rows 0..31
    const int ob0 = wave * 512, ob1 = 2048 + wave * 512;

    f32x4 accd[2][2] = {};
    f32x4 accx[2] = {};

    __builtin_amdgcn_global_load_lds((const glb_u32_t*)srcA0,  (lds_u32_t*)(u.gm.As + ob0), 16, 0, 0);
    __builtin_amdgcn_global_load_lds((const glb_u32_t*)srcA1,  (lds_u32_t*)(u.gm.As + ob1), 16, 0, 0);
    __builtin_amdgcn_global_load_lds((const glb_u32_t*)srcWd0, (lds_u32_t*)(u.gm.Wd + ob0), 16, 0, 0);
    __builtin_amdgcn_global_load_lds((const glb_u32_t*)srcWd1, (lds_u32_t*)(u.gm.Wd + ob1), 16, 0, 0);
    __builtin_amdgcn_global_load_lds((const glb_u32_t*)srcBC,  (lds_u32_t*)(u.gm.BC + ob0), 16, 0, 0);

    for (int t = 0; t < 16; t++) {
        __syncthreads();
        if (t + 1 < 16) {
            const int k0 = (t + 1) * 64;
            const int sA = ((t + 1) & 1) * SZA, sBC = ((t + 1) & 1) * SZBC;
            __builtin_amdgcn_global_load_lds((const glb_u32_t*)(srcA0 + k0),  (lds_u32_t*)(u.gm.As + sA + ob0), 16, 0, 0);
            __builtin_amdgcn_global_load_lds((const glb_u32_t*)(srcA1 + k0),  (lds_u32_t*)(u.gm.As + sA + ob1), 16, 0, 0);
            __builtin_amdgcn_global_load_lds((const glb_u32_t*)(srcWd0 + k0), (lds_u32_t*)(u.gm.Wd + sA + ob0), 16, 0, 0);
            __builtin_amdgcn_global_load_lds((const glb_u32_t*)(srcWd1 + k0), (lds_u32_t*)(u.gm.Wd + sA + ob1), 16, 0, 0);
            __builtin_amdgcn_global_load_lds((const glb_u32_t*)(srcBC + k0),  (lds_u32_t*)(u.gm.BC + sBC + ob0), 16, 0, 0);
        }
        const short* Ab  = u.gm.As + (t & 1) * SZA;
        const short* Wdb = u.gm.Wd + (t & 1) * SZA;
        const short* BCb = u.gm.BC + (t & 1) * SZBC;
        short8 af[2][2], wf[2][2], bcf[2];
#pragma unroll
        for (int hk = 0; hk < 2; hk++) {
#pragma unroll
            for (int mi = 0; mi < 2; mi++) {
                const int row = wm * 32 + mi * 16 + l15;
                af[hk][mi] = *(const short8*)(Ab + row * 64 + (((hk * 4 + kg) ^ (row & 7)) * 8));
            }
#pragma unroll
            for (int ni = 0; ni < 2; ni++) {
                const int row = wn * 32 + ni * 16 + l15;
                wf[hk][ni] = *(const short8*)(Wdb + row * 64 + (((hk * 4 + kg) ^ (row & 7)) * 8));
            }
            {
                const int row = wn * 16 + l15;   // 0..31
                bcf[hk] = *(const short8*)(BCb + row * 64 + (((hk * 4 + kg) ^ (row & 7)) * 8));
            }
        }
#pragma unroll
        for (int hk = 0; hk < 2; hk++)
#pragma unroll
            for (int mi = 0; mi < 2; mi++) {
#pragma unroll
                for (int ni = 0; ni < 2; ni++)
                    accd[mi][ni] = __builtin_amdgcn_mfma_f32_16x16x32_bf16(af[hk][mi], wf[hk][ni], accd[mi][ni], 0, 0, 0);
                accx[mi] = __builtin_amdgcn_mfma_f32_16x16x32_bf16(af[hk][mi], bcf[hk], accx[mi], 0, 0, 0);
            }
    }

    __syncthreads();   // gemm LDS reads done before repurposing union
#pragma unroll
    for (int ni = 0; ni < 2; ni++) {
        const int dl = wn * 32 + ni * 16 + l15;
        const float bb = dtb[dg * 64 + dl];
#pragma unroll
        for (int mi = 0; mi < 2; mi++)
#pragma unroll
            for (int j = 0; j < 4; j++)
                u.sc.dlt[wm * 32 + mi * 16 + kg * 4 + j][dl] = softp(accd[mi][ni][j] + bb);
    }
    {
        const int c = wn * 16 + l15;
#pragma unroll
        for (int mi = 0; mi < 2; mi++)
#pragma unroll
            for (int j = 0; j < 4; j++)
                u.sc.BC[wm * 32 + mi * 16 + kg * 4 + j][c] = accx[mi][j];
    }
#pragma unroll
    for (int k = 0; k < 2; k++) {
        const int c = tid + k * 256;
        const int row = c >> 3, sl = c & 7;
        *(uint4*)&u.sc.ub[row][sl * 8] =
            *(const uint4*)(A + (size_t)(m0 + row) * 1024 + dg * 64 + sl * 8);
    }
    __syncthreads();

    // 4-lane-parallel scan (R12/R13, verified)
    {
        const int d_l = tid >> 2;
        const int ns = (tid & 3) << 2;
        const int d = dg * 64 + d_l;
        float a[4], s[4];
#pragma unroll
        for (int n = 0; n < 4; n++) {
            a[n] = -__expf(Alog[(size_t)d * 16 + ns + n]);
            s[n] = 0.f;
        }
        const float dv = Dp[d];
        for (int l = 0; l < SEQ; l++) {
            const float dlt = u.sc.dlt[l][d_l];
            const float uu = b2f(u.sc.ub[l][d_l]);
            const float dbu = dlt * uu;
            float part = 0.f;
#pragma unroll
            for (int n = 0; n < 4; n++) {
                s[n] = __expf(dlt * a[n]) * s[n] + dbu * u.sc.BC[l][ns + n];
                part = fmaf(s[n], u.sc.BC[l][16 + ns + n], part);
            }
            part += __shfl_xor(part, 1, 64);
            part += __shfl_xor(part, 2, 64);
            if ((tid & 3) == 0) u.sc.yt[l][d_l] = part + uu * dv;
        }
    }
    __syncthreads();
#pragma unroll
    for (int k = 0; k < 2; k++) {
        const int c = tid + k * 256;
        const int row = c >> 3, sl = c & 7;
        const short8 rv = *(const short8*)(srb + (size_t)(m0 + row) * 1024 + dg * 64 + sl * 8);
        short8 out;
#pragma unroll
        for (int j = 0; j < 8; j++)
            out[j] = f2b(u.sc.yt[row][sl * 8 + j] * b2f(rv[j]));
        *(short8*)(yb + (size_t)(m0 + row) * 1024 + dg * 64 + sl * 8) = out;
    }
}

// ================= out_proj: 32x64 tile, BK=64 swizzled (R14, verified) =================
template <int FIRST>
__global__ __launch_bounds__(256) void outproj_k(
    const short* __restrict__ A, const short* __restrict__ W,
    float* __restrict__ h, short* __restrict__ hb, float* __restrict__ ss_out,
    const float* __restrict__ xsrc, const float* __restrict__ gsp,
    const float* __restrict__ ssS1)
{
    __shared__ short As[2 * 32 * 64];   // 8 KB dbuf
    __shared__ short Bs[2 * 64 * 64];   // 16 KB dbuf
    constexpr int SZA = 32 * 64, SZB = 64 * 64;
    const int m0 = blockIdx.y * 32, n0 = blockIdx.x * 64;
    const int tid = threadIdx.x, wave = tid >> 6, lane = tid & 63;
    const int l15 = lane & 15, kg = lane >> 4;

    const int ra = tid >> 3, sa = tid & 7;
    const short* srcA = A + (size_t)(m0 + ra) * 1024 + ((sa ^ (ra & 7)) * 8);
    const int rb1 = 32 + (tid >> 3);
    const short* srcB0 = W + (size_t)(n0 + ra) * 1024 + ((sa ^ (ra & 7)) * 8);
    const short* srcB1 = W + (size_t)(n0 + rb1) * 1024 + ((sa ^ (rb1 & 7)) * 8);
    const int obA = wave * 512;
    const int obB0 = wave * 512, obB1 = 2048 + wave * 512;

    f32x4 acc[2] = {};
    __builtin_amdgcn_global_load_lds((const glb_u32_t*)srcA,  (lds_u32_t*)(As + obA), 16, 0, 0);
    __builtin_amdgcn_global_load_lds((const glb_u32_t*)srcB0, (lds_u32_t*)(Bs + obB0), 16, 0, 0);
    __builtin_amdgcn_global_load_lds((const glb_u32_t*)srcB1, (lds_u32_t*)(Bs + obB1), 16, 0, 0);

    for (int t = 0; t < 16; t++) {
        __syncthreads();
        if (t + 1 < 16) {
            const int k0 = (t + 1) * 64;
            const int sA = ((t + 1) & 1) * SZA, sB = ((t + 1) & 1) * SZB;
            __builtin_amdgcn_global_load_lds((const glb_u32_t*)(srcA + k0),  (lds_u32_t*)(As + sA + obA), 16, 0, 0);
            __builtin_amdgcn_global_load_lds((const glb_u32_t*)(srcB0 + k0), (lds_u32_t*)(Bs + sB + obB0), 16, 0, 0);
            __builtin_amdgcn_global_load_lds((const glb_u32_t*)(srcB1 + k0), (lds_u32_t*)(Bs + sB + obB1), 16, 0, 0);
        }
        const short* Ab = As + (t & 1) * SZA;
        const short* Bb = Bs + (t & 1) * SZB;
        short8 af[2][2], bf[2];
#pragma unroll
        for (int hk = 0; hk < 2; hk++) {
#pragma unroll
            for (int mi = 0; mi < 2; mi++) {
                const int row = mi * 16 + l15;
                af[hk][mi] = *(const short8*)(Ab + row * 64 + (((hk * 4 + kg) ^ (row & 7)) * 8));
            }
            const int rowb = wave * 16 + l15;
            bf[hk] = *(const short8*)(Bb + rowb * 64 + (((hk * 4 + kg) ^ (rowb & 7)) * 8));
        }
#pragma unroll
        for (int hk = 0; hk < 2; hk++)
#pragma unroll
            for (int mi = 0; mi < 2; mi++)
                acc[mi] = __builtin_amdgcn_mfma_f32_16x16x32_bf16(af[hk][mi], bf[hk], acc[mi], 0, 0, 0);
    }

    const int col = n0 + wave * 16 + l15;
    const float gc = FIRST ? gsp[col] : 0.f;
    float vsq[2][4] = {};
#pragma unroll
    for (int mi = 0; mi < 2; mi++)
#pragma unroll
        for (int j = 0; j < 4; j++) {
            const int row = m0 + mi * 16 + kg * 4 + j;
            float hold;
            if constexpr (FIRST) {
                const float rx = rsqrtf(ssS1[row] * (1.f / 512.f) + 1e-5f);
                hold = xsrc[(size_t)row * 512 + col] * rx * gc;
            } else {
                hold = h[(size_t)row * 512 + col];
            }
            const float v = acc[mi][j] + hold;
            h[(size_t)row * 512 + col] = v;
            hb[(size_t)row * 512 + col] = f2b(v);
            vsq[mi][j] = v * v;
        }
#pragma unroll
    for (int mi = 0; mi < 2; mi++)
#pragma unroll
        for (int j = 0; j < 4; j++) {
            float t = vsq[mi][j];
            t += __shfl_xor(t, 1, 64);
            t += __shfl_xor(t, 2, 64);
            t += __shfl_xor(t, 4, 64);
            t += __shfl_xor(t, 8, 64);
            if (l15 == 0) {
                const int row = m0 + mi * 16 + kg * 4 + j;
                atomicAdd(ss_out + row, t);
            }
        }
}

// ================= final proj (R13, verified) =================
__global__ __launch_bounds__(256) void projf_k(
    const short* __restrict__ A, const short* __restrict__ W,
    const float* __restrict__ ss_in, float* __restrict__ xr)
{
    __shared__ short As[2 * 64 * 64];
    __shared__ short Bs[2 * 64 * 64];
    f32x4 acc[2][2] = {};
    const int m0 = blockIdx.y * 64, n0 = blockIdx.x * 64;
    gemm_core64(acc, A, 512, W, 512, 512, As, Bs, m0, n0);
    const int lane = threadIdx.x & 63, wave = threadIdx.x >> 6;
    const int wm = wave >> 1, wn = wave & 1, l15 = lane & 15, kg = lane >> 4;
#pragma unroll
    for (int mi = 0; mi < 2; mi++)
#pragma unroll
        for (int j = 0; j < 4; j++) {
            const int row = m0 + wm * 32 + mi * 16 + kg * 4 + j;
            const float r = rsqrtf(ss_in[row] * (1.f / 512.f) + 1e-5f);
#pragma unroll
            for (int ni = 0; ni < 2; ni++) {
                const int col = n0 + wn * 32 + ni * 16 + l15;
                xr[(size_t)row * 2048 + col] = acc[mi][ni][j] * r;
            }
        }
}

// ================= coeffs + preds (R2, verified) =================
__global__ __launch_bounds__(256) void coeffs_k(
    const float* __restrict__ outp, const float* __restrict__ inp,
    float* __restrict__ coeffs, float* __restrict__ preds)
{
    const int m = blockIdx.x;
    const int b = m >> 6;
    const int tid = threadIdx.x, wave = tid >> 6, lane = tid & 63;
    __shared__ float4 Us[256], Vs[256];
    __shared__ float ins[256];
    __shared__ float4 tpart[4];
    Us[tid] = *(const float4*)(outp + (size_t)m * 2048 + tid * 4);
    Vs[tid] = *(const float4*)(outp + (size_t)m * 2048 + 1024 + tid * 4);
    ins[tid] = inp[(size_t)m * 256 + tid];
    __syncthreads();
    const float4 vq0 = Vs[lane * 4 + 0], vq1 = Vs[lane * 4 + 1];
    const float4 vq2 = Vs[lane * 4 + 2], vq3 = Vs[lane * 4 + 3];
    float* cbase = coeffs + (size_t)m * 65536 + lane * 4;
#pragma unroll 4
    for (int i = 0; i < 64; i++) {
        const int pp = (wave << 6) + i;
        const float4 up = Us[pp];
        float4 c;
        c.x = up.x * vq0.x + up.y * vq0.y + up.z * vq0.z + up.w * vq0.w;
        c.y = up.x * vq1.x + up.y * vq1.y + up.z * vq1.z + up.w * vq1.w;
        c.z = up.x * vq2.x + up.y * vq2.y + up.z * vq2.z + up.w * vq2.w;
        c.w = up.x * vq3.x + up.y * vq3.y + up.z * vq3.z + up.w * vq3.w;
        *(float4*)(cbase + (size_t)pp * 256) = c;
    }
    const float iv = ins[tid];
    const float4 vm = Vs[tid];
    float4 t = make_float4(vm.x * iv, vm.y * iv, vm.z * iv, vm.w * iv);
#pragma unroll
    for (int off = 32; off > 0; off >>= 1) {
        t.x += __shfl_xor(t.x, off, 64);
        t.y += __shfl_xor(t.y, off, 64);
        t.z += __shfl_xor(t.z, off, 64);
        t.w += __shfl_xor(t.w, off, 64);
    }
    if (lane == 0) tpart[wave] = t;
    __syncthreads();
    const float4 t0 = tpart[0], t1 = tpart[1], t2 = tpart[2], t3 = tpart[3];
    const float4 tt = make_float4(t0.x + t1.x + t2.x + t3.x, t0.y + t1.y + t2.y + t3.y,
                                  t0.z + t1.z + t2.z + t3.z, t0.w + t1.w + t2.w + t3.w);
    const float4 up = Us[tid];
    const float pv = up.x * tt.x + up.y * tt.y + up.z * tt.z + up.w * tt.w;
    atomicAdd(preds + (size_t)b * 256 + tid, pv);
}

} // namespace

extern "C" void kernel_launch(void* const* d_in, const int* in_sizes, int n_in,
                              void* d_out, int out_size, void* d_ws, size_t ws_size,
                              hipStream_t stream)
{
    const float* inputs     = (const float*)d_in[0];
    const float* lin1_w     = (const float*)d_in[1];
    const float* lin1_b     = (const float*)d_in[2];
    const float* lin2_w     = (const float*)d_in[3];
    const float* lin2_b     = (const float*)d_in[4];
    const float* gate_w     = (const float*)d_in[5];
    const float* gate_b     = (const float*)d_in[6];
    const float* sp_norm_w  = (const float*)d_in[7];
    const float* in_proj_w  = (const float*)d_in[8];
    const float* conv_w     = (const float*)d_in[9];
    const float* conv_b     = (const float*)d_in[10];
    const float* x_proj_w   = (const float*)d_in[11];
    const float* dt_proj_w  = (const float*)d_in[12];
    const float* dt_proj_b  = (const float*)d_in[13];
    const float* A_log      = (const float*)d_in[14];
    const float* Dvec       = (const float*)d_in[15];
    const float* out_proj_w = (const float*)d_in[16];
    const float* blk_norm_w = (const float*)d_in[17];
    const float* post_norm_w= (const float*)d_in[18];
    const float* proj_w     = (const float*)d_in[19];

    float* ws = (float*)d_ws;
    // fp32 region
    float* h     = ws;                 // 1024 x 512
    float* xr    = ws + 524288;        // 1024 x 2048 (final proj out)
    float* x     = ws + 2621440;       // 1024 x 512 (lin2 out)
    float* g     = ws + 3145728;       // 1024 x 512
    float* ss    = ws + 3670016;       // slots: 0=S1, 1..4=sum h^2, 5=S2
    // bf16 region
    short* bfb     = (short*)(ws + 3676160);
    short* inputsb = bfb;               // 1024 x 256
    short* h1b     = bfb + 262144;      // 1024 x 512
    short* hb      = bfb + 786432;      // 1024 x 512
    short* xcb     = bfb + 1310720;     // 1024 x 1024
    short* yb      = bfb + 2359296;     // 1024 x 1024
    short* xb      = yb;                // 1024 x 512 ALIAS (dead until xpdscan l0)
    short* srb     = bfb + 3407872;     // 1024 x 1024 silu(res)
    short* wlin1gb = bfb + 4456448;     // 1024 x 256
    short* wlin2b  = bfb + 4718592;     // 512 x 512
    short* winpb   = bfb + 4980736;     // 4 x 2048 x 512 (gamma-folded; l0 also gamma_sp)
    short* woutpb  = bfb + 9175040;     // 4 x 512 x 1024
    short* wprojb  = bfb + 11272192;    // 2048 x 512 (gamma-folded)
    short* wxpdb   = bfb + 12320768;    // 4 x 1056 x 1024 ([BC; W_delta])
    float* preds  = (float*)d_out;
    float* coeffs = (float*)d_out + 4096;

    const dim3 blk(256);

    prep_early_k<<<dim3(808), blk, 0, stream>>>(
        lin1_w, gate_w, lin2_w, inputs, wlin1gb, wlin2b, inputsb, preds, ss);

    lin1gate_k<<<dim3(1760), blk, 0, stream>>>(
        inputsb, wlin1gb, lin1_b, gate_b, h1b, g,
        x_proj_w, dt_proj_w, in_proj_w, out_proj_w, proj_w,
        blk_norm_w, post_norm_w, sp_norm_w,
        winpb, woutpb, wprojb, wxpdb);

    lin2_k<<<dim3(8, 16), blk, 0, stream>>>(h1b, wlin2b, lin2_b, g, sp_norm_w,
                                            x, xb, ss, ss + 5120);

    for (int l = 0; l < 4; l++) {
        if (l == 0)
            inprojconv_k<1><<<dim3(32, 16), blk, 0, stream>>>(
                xb, winpb, ss, ss + 5120,
                conv_w, conv_b, xcb, srb);
        else
            inprojconv_k<0><<<dim3(32, 16), blk, 0, stream>>>(
                hb, winpb + (size_t)l * 1048576, ss + l * 1024, nullptr,
                conv_w + (size_t)l * 4096, conv_b + l * 1024, xcb, srb);
        xpdscan_k<<<dim3(16, 16), blk, 0, stream>>>(
            xcb, wxpdb + (size_t)l * WXPD_STRIDE, dt_proj_b + l * 1024,
            A_log + (size_t)l * 16384, Dvec + l * 1024, srb, yb);
        if (l == 0)
            outproj_k<1><<<dim3(8, 32), blk, 0, stream>>>(yb, woutpb,
                h, hb, ss + 1024, x, sp_norm_w, ss);
        else
            outproj_k<0><<<dim3(8, 32), blk, 0, stream>>>(yb, woutpb + (size_t)l * 524288,
                h, hb, ss + (l + 1) * 1024, nullptr, nullptr, nullptr);
    }

    projf_k<<<dim3(32, 16), blk, 0, stream>>>(hb, wprojb, ss + 4096, xr);
    coeffs_k<<<dim3(1024), blk, 0, stream>>>(xr, inputs, coeffs, preds);
}